// Round 1
// baseline (1390.060 us; speedup 1.0000x reference)
//
#include <hip/hip_runtime.h>

// HeteroGNN: 2-layer hetero SAGE (gene/disease/compound), H=128.
// Strategy:
//  - Build per-dst linked lists once (atomicExch, int) for the 4 relations.
//  - Per layer: per-dst-wave list walk computes neighbor MEAN directly (no f32 atomics).
//  - Per node type: fused f32 GEMM over K-slabs (mean@Wl terms + x@Wr term), bias, relu.
//  - d_out holds features between layers (in-place safe: block reads only its own rows,
//    __syncthreads() before stores).

constexpr int HD = 128;

// ---------------- linked-list build ----------------
__global__ __launch_bounds__(256) void k_build(const int* __restrict__ dst,
                                               int* __restrict__ head,
                                               int* __restrict__ nxt, int E) {
  int e = blockIdx.x * 256 + threadIdx.x;
  if (e < E) nxt[e] = atomicExch(&head[dst[e]], e);
}

// ---------------- neighbor mean via list walk ----------------
// one wave (64 lanes) per dst node; lane covers 2 floats of the 128-dim row.
__global__ __launch_bounds__(256) void k_aggregate(const float* __restrict__ xsrc,
                                                   const int* __restrict__ src,
                                                   const int* __restrict__ head,
                                                   const int* __restrict__ nxt,
                                                   float* __restrict__ mean, int n_dst) {
  int d = blockIdx.x * 4 + (threadIdx.x >> 6);
  int lane = threadIdx.x & 63;
  if (d >= n_dst) return;
  float ax = 0.f, ay = 0.f;
  int cnt = 0;
  int e = head[d];
  while (e >= 0) {
    int s = src[e];
    float2 v = *(const float2*)(xsrc + (size_t)s * HD + lane * 2);
    ax += v.x;
    ay += v.y;
    ++cnt;
    e = nxt[e];
  }
  float inv = 1.0f / (float)(cnt > 0 ? cnt : 1);
  *(float2*)(mean + (size_t)d * HD + lane * 2) = make_float2(ax * inv, ay * inv);
}

// ---------------- small elementwise add (Wr0 + Wr2) ----------------
__global__ __launch_bounds__(256) void k_add(const float* __restrict__ a,
                                             const float* __restrict__ b,
                                             float* __restrict__ o, int n) {
  int i = blockIdx.x * 256 + threadIdx.x;
  if (i < n) o[i] = a[i] + b[i];
}

// ---------------- fused GEMM ----------------
// out[M,128] = sum_s x_s[M,128] @ W_s[128,128] + b0 (+b1), optional relu.
// block: 256 threads, 64-row tile; thread (tx=tid&31, ty=tid>>5) computes
// rows rbase..rbase+7 (ty*8) x cols tx*4..tx*4+3. W slab staged in LDS (64KB).
__device__ __forceinline__ void gemm_slab(const float* __restrict__ xp,
                                          const float* __restrict__ wp,
                                          float* __restrict__ lds,
                                          float4 (&acc)[8],
                                          const int (&rr)[8], int tx, int tid) {
  __syncthreads();  // protect LDS from previous slab's readers
  {
    const float4* s4 = (const float4*)wp;
    float4* l4 = (float4*)lds;
#pragma unroll
    for (int j = 0; j < 16; ++j) l4[tid + j * 256] = s4[tid + j * 256];
  }
  __syncthreads();
#pragma unroll 2
  for (int k0 = 0; k0 < HD; k0 += 4) {
    float4 w0 = *(const float4*)(lds + (k0 + 0) * HD + tx * 4);
    float4 w1 = *(const float4*)(lds + (k0 + 1) * HD + tx * 4);
    float4 w2 = *(const float4*)(lds + (k0 + 2) * HD + tx * 4);
    float4 w3 = *(const float4*)(lds + (k0 + 3) * HD + tx * 4);
#pragma unroll
    for (int i = 0; i < 8; ++i) {
      float4 xv = *(const float4*)(xp + (size_t)rr[i] * HD + k0);
      acc[i].x = fmaf(xv.x, w0.x, acc[i].x);
      acc[i].y = fmaf(xv.x, w0.y, acc[i].y);
      acc[i].z = fmaf(xv.x, w0.z, acc[i].z);
      acc[i].w = fmaf(xv.x, w0.w, acc[i].w);
      acc[i].x = fmaf(xv.y, w1.x, acc[i].x);
      acc[i].y = fmaf(xv.y, w1.y, acc[i].y);
      acc[i].z = fmaf(xv.y, w1.z, acc[i].z);
      acc[i].w = fmaf(xv.y, w1.w, acc[i].w);
      acc[i].x = fmaf(xv.z, w2.x, acc[i].x);
      acc[i].y = fmaf(xv.z, w2.y, acc[i].y);
      acc[i].z = fmaf(xv.z, w2.z, acc[i].z);
      acc[i].w = fmaf(xv.z, w2.w, acc[i].w);
      acc[i].x = fmaf(xv.w, w3.x, acc[i].x);
      acc[i].y = fmaf(xv.w, w3.y, acc[i].y);
      acc[i].z = fmaf(xv.w, w3.z, acc[i].z);
      acc[i].w = fmaf(xv.w, w3.w, acc[i].w);
    }
  }
}

__global__ __launch_bounds__(256) void k_gemm(const float* __restrict__ x0, const float* __restrict__ w0,
                                              const float* __restrict__ x1, const float* __restrict__ w1,
                                              const float* __restrict__ x2, const float* __restrict__ w2,
                                              int nslab,
                                              const float* __restrict__ b0, const float* __restrict__ b1,
                                              float* __restrict__ outp, int M, int relu) {
  __shared__ float lds[HD * HD];
  int tid = threadIdx.x;
  int tx = tid & 31;
  int rbase = blockIdx.x * 64 + ((tid >> 5) << 3);
  int rr[8];
#pragma unroll
  for (int i = 0; i < 8; ++i) {
    int r = rbase + i;
    rr[i] = r < M ? r : M - 1;  // clamp stays within the last block's own tile
  }
  float4 acc[8];
#pragma unroll
  for (int i = 0; i < 8; ++i) acc[i] = make_float4(0.f, 0.f, 0.f, 0.f);

  gemm_slab(x0, w0, lds, acc, rr, tx, tid);
  if (nslab > 1) gemm_slab(x1, w1, lds, acc, rr, tx, tid);
  if (nslab > 2) gemm_slab(x2, w2, lds, acc, rr, tx, tid);

  float4 bias = *(const float4*)(b0 + tx * 4);
  if (b1) {
    float4 t = *(const float4*)(b1 + tx * 4);
    bias.x += t.x; bias.y += t.y; bias.z += t.z; bias.w += t.w;
  }

  __syncthreads();  // all x reads done before in-place stores (x may alias outp)

#pragma unroll
  for (int i = 0; i < 8; ++i) {
    int r = rbase + i;
    if (r < M) {
      float4 v;
      v.x = acc[i].x + bias.x;
      v.y = acc[i].y + bias.y;
      v.z = acc[i].z + bias.z;
      v.w = acc[i].w + bias.w;
      if (relu) {
        v.x = fmaxf(v.x, 0.f); v.y = fmaxf(v.y, 0.f);
        v.z = fmaxf(v.z, 0.f); v.w = fmaxf(v.w, 0.f);
      }
      *(float4*)(outp + (size_t)r * HD + tx * 4) = v;
    }
  }
}

extern "C" void kernel_launch(void* const* d_in, const int* in_sizes, int n_in,
                              void* d_out, int out_size, void* d_ws, size_t ws_size,
                              hipStream_t stream) {
  const float* emb_g = (const float*)d_in[0];
  const float* emb_d = (const float*)d_in[1];
  const float* emb_c = (const float*)d_in[2];
  const float* Wl = (const float*)d_in[3];   // [2,4,128,128]
  const float* bl = (const float*)d_in[4];   // [2,4,128]
  const float* Wr = (const float*)d_in[5];   // [2,4,128,128]
  const int* eg_s  = (const int*)d_in[6];
  const int* eg_d  = (const int*)d_in[7];
  const int* ecd_s = (const int*)d_in[8];
  const int* ecd_d = (const int*)d_in[9];
  const int* ecg_s = (const int*)d_in[10];
  const int* ecg_d = (const int*)d_in[11];
  const int* egc_s = (const int*)d_in[12];
  const int* egc_d = (const int*)d_in[13];

  const int NG = in_sizes[0] / HD;
  const int ND = in_sizes[1] / HD;
  const int NC = in_sizes[2] / HD;
  const int E0 = in_sizes[6];   // g->g
  const int E1 = in_sizes[8];   // c->d
  const int E2 = in_sizes[10];  // c->g
  const int E3 = in_sizes[12];  // g->c

  // ---- workspace carve (all chunks 16B-aligned by construction) ----
  char* w = (char*)d_ws;
  float* mean_gg = (float*)w; w += (size_t)NG * HD * 4;
  float* mean_cg = (float*)w; w += (size_t)NG * HD * 4;
  float* mean_cd = (float*)w; w += (size_t)ND * HD * 4;
  float* mean_gc = (float*)w; w += (size_t)NC * HD * 4;
  float* wsum = (float*)w;    w += (size_t)HD * HD * 4;
  int* head_gg = (int*)w;     w += (size_t)NG * 4;
  int* head_cd = (int*)w;     w += (size_t)ND * 4;
  int* head_cg = (int*)w;     w += (size_t)NG * 4;
  int* head_gc = (int*)w;     w += (size_t)NC * 4;
  int* nxt0 = (int*)w;        w += (size_t)E0 * 4;
  int* nxt1 = (int*)w;        w += (size_t)E1 * 4;
  int* nxt2 = (int*)w;        w += (size_t)E2 * 4;
  int* nxt3 = (int*)w;        w += (size_t)E3 * 4;

  // heads = -1 (contiguous region: head_gg..head_gc)
  hipMemsetAsync(head_gg, 0xFF, (size_t)(NG + ND + NG + NC) * 4, stream);

  k_build<<<(E0 + 255) / 256, 256, 0, stream>>>(eg_d,  head_gg, nxt0, E0);
  k_build<<<(E1 + 255) / 256, 256, 0, stream>>>(ecd_d, head_cd, nxt1, E1);
  k_build<<<(E2 + 255) / 256, 256, 0, stream>>>(ecg_d, head_cg, nxt2, E2);
  k_build<<<(E3 + 255) / 256, 256, 0, stream>>>(egc_d, head_gc, nxt3, E3);

  float* out = (float*)d_out;
  float* xg_out = out;
  float* xd_out = out + (size_t)NG * HD;
  float* xc_out = out + (size_t)(NG + ND) * HD;

  for (int L = 0; L < 2; ++L) {
    const float* xg = L ? (const float*)xg_out : emb_g;
    const float* xd = L ? (const float*)xd_out : emb_d;
    const float* xc = L ? (const float*)xc_out : emb_c;

    // neighbor means (all reads of xg/xc complete before GEMMs overwrite d_out)
    k_aggregate<<<(NG + 3) / 4, 256, 0, stream>>>(xg, eg_s,  head_gg, nxt0, mean_gg, NG);
    k_aggregate<<<(ND + 3) / 4, 256, 0, stream>>>(xc, ecd_s, head_cd, nxt1, mean_cd, ND);
    k_aggregate<<<(NG + 3) / 4, 256, 0, stream>>>(xc, ecg_s, head_cg, nxt2, mean_cg, NG);
    k_aggregate<<<(NC + 3) / 4, 256, 0, stream>>>(xg, egc_s, head_gc, nxt3, mean_gc, NC);

    const float* Wl_L = Wl + (size_t)L * 4 * HD * HD;
    const float* Wr_L = Wr + (size_t)L * 4 * HD * HD;
    const float* bl_L = bl + (size_t)L * 4 * HD;

    // WrSum = Wr[L,0] + Wr[L,2] (gene dst gets two relations)
    k_add<<<(HD * HD + 255) / 256, 256, 0, stream>>>(Wr_L + 0 * HD * HD, Wr_L + 2 * HD * HD,
                                                     wsum, HD * HD);
    int relu = (L == 0) ? 1 : 0;

    // genes: mean_gg@Wl0 + mean_cg@Wl2 + xg@(Wr0+Wr2) + bl0 + bl2
    k_gemm<<<(NG + 63) / 64, 256, 0, stream>>>(mean_gg, Wl_L + 0 * HD * HD,
                                               mean_cg, Wl_L + 2 * HD * HD,
                                               xg, wsum, 3,
                                               bl_L + 0 * HD, bl_L + 2 * HD,
                                               xg_out, NG, relu);
    // disease: mean_cd@Wl1 + xd@Wr1 + bl1
    k_gemm<<<(ND + 63) / 64, 256, 0, stream>>>(mean_cd, Wl_L + 1 * HD * HD,
                                               xd, Wr_L + 1 * HD * HD,
                                               nullptr, nullptr, 2,
                                               bl_L + 1 * HD, nullptr,
                                               xd_out, ND, relu);
    // compound: mean_gc@Wl3 + xc@Wr3 + bl3
    k_gemm<<<(NC + 63) / 64, 256, 0, stream>>>(mean_gc, Wl_L + 3 * HD * HD,
                                               xc, Wr_L + 3 * HD * HD,
                                               nullptr, nullptr, 2,
                                               bl_L + 3 * HD, nullptr,
                                               xc_out, NC, relu);
  }
}

// Round 2
// 892.499 us; speedup vs baseline: 1.5575x; 1.5575x over previous
//
#include <hip/hip_runtime.h>

// HeteroGNN: 2-layer hetero SAGE (gene/disease/compound), H=128.
// R2: GEMMs moved to MFMA (32x32x16 bf16) with split-bf16 3-MFMA precision.
//  - k_prepw: once per launch, builds 14 W-slabs as transposed [n][k], hi/lo bf16,
//    XOR-swizzled (k ^ ((n&15)<<3)) so GEMM LDS staging is a linear copy and
//    B-fragment ds_read_b128 is bank-conflict-free.
//  - k_gemm_mfma: 256 thr = 4 waves; block M-tile 256 (wave owns 64 rows), N=128.
//    A: global f32 -> reg -> hi/lo bf16 (RNE). B: LDS. acc[2][4] f32x16.
//  - Aggregation unchanged (linked-list walk) — next round's target.

constexpr int HD = 128;

typedef __attribute__((ext_vector_type(8))) short bf16x8;
typedef __attribute__((ext_vector_type(16))) float f32x16;

__device__ __forceinline__ unsigned short f2bf(float x) {
  unsigned u = __builtin_bit_cast(unsigned, x);
  u += 0x7FFF + ((u >> 16) & 1);  // RNE
  return (unsigned short)(u >> 16);
}
__device__ __forceinline__ float bf2f(unsigned short h) {
  return __builtin_bit_cast(float, (unsigned)h << 16);
}

// ---------------- linked-list build ----------------
__global__ __launch_bounds__(256) void k_build(const int* __restrict__ dst,
                                               int* __restrict__ head,
                                               int* __restrict__ nxt, int E) {
  int e = blockIdx.x * 256 + threadIdx.x;
  if (e < E) nxt[e] = atomicExch(&head[dst[e]], e);
}

// ---------------- neighbor mean via list walk ----------------
__global__ __launch_bounds__(256) void k_aggregate(const float* __restrict__ xsrc,
                                                   const int* __restrict__ src,
                                                   const int* __restrict__ head,
                                                   const int* __restrict__ nxt,
                                                   float* __restrict__ mean, int n_dst) {
  int d = blockIdx.x * 4 + (threadIdx.x >> 6);
  int lane = threadIdx.x & 63;
  if (d >= n_dst) return;
  float ax = 0.f, ay = 0.f;
  int cnt = 0;
  int e = head[d];
  while (e >= 0) {
    int s = src[e];
    float2 v = *(const float2*)(xsrc + (size_t)s * HD + lane * 2);
    ax += v.x;
    ay += v.y;
    ++cnt;
    e = nxt[e];
  }
  float inv = 1.0f / (float)(cnt > 0 ? cnt : 1);
  *(float2*)(mean + (size_t)d * HD + lane * 2) = make_float2(ax * inv, ay * inv);
}

// ---------------- W preprocessing ----------------
// For each slab: W (or Wa+Wb) [k][n] f32 -> transposed [n][k], split hi/lo bf16,
// k swizzled: idx = n*128 + (k ^ ((n&15)<<3)). hi at [0,16384), lo at [16384,32768).
struct PrepArgs {
  const float* a[14];
  const float* b[14];
};

__global__ __launch_bounds__(256) void k_prepw(PrepArgs pa, unsigned short* __restrict__ out) {
  int s = blockIdx.x;
  const float* A = pa.a[s];
  const float* B = pa.b[s];
  unsigned short* oh = out + (size_t)s * 32768;
  int e0 = blockIdx.y * 1024 + threadIdx.x * 4;
#pragma unroll
  for (int j = 0; j < 4; ++j) {
    int e = e0 + j;
    int k = e >> 7, n = e & 127;
    float v = A[e] + (B ? B[e] : 0.f);
    unsigned short h = f2bf(v);
    unsigned short l = f2bf(v - bf2f(h));
    int idx = n * 128 + (k ^ ((n & 15) << 3));
    oh[idx] = h;
    oh[16384 + idx] = l;
  }
}

// ---------------- MFMA GEMM ----------------
// out[M,128] = sum_s x_s[M,128] @ W_s + b0 (+b1), optional relu.
// Split-bf16: x@W ~= xh@wh + xh@wl + xl@wh (lo*lo dropped, ~2^-18 relative).
__global__ __launch_bounds__(256, 2) void k_gemm_mfma(
    const float* __restrict__ x0, const float* __restrict__ x1, const float* __restrict__ x2,
    const unsigned short* __restrict__ w0p, const unsigned short* __restrict__ w1p,
    const unsigned short* __restrict__ w2p, int nslab,
    const float* __restrict__ b0, const float* __restrict__ b1,
    float* __restrict__ outp, int M, int relu) {
  __shared__ unsigned short ldsb[32768];  // 64KB: hi [0,16384), lo [16384,32768)
  const int tid = threadIdx.x;
  const int wave = tid >> 6;
  const int lane = tid & 63;
  const int l31 = lane & 31;
  const int lhalf = lane >> 5;

  const int mbase = blockIdx.x * 256 + wave * 64;
  int r0 = mbase + l31;
  int r1 = mbase + 32 + l31;
  if (r0 > M - 1) r0 = M - 1;
  if (r1 > M - 1) r1 = M - 1;

  f32x16 acc[2][4];
#pragma unroll
  for (int a = 0; a < 2; ++a)
#pragma unroll
    for (int n = 0; n < 4; ++n)
#pragma unroll
      for (int r = 0; r < 16; ++r) acc[a][n][r] = 0.f;

  const float* xs[3] = {x0, x1, x2};
  const unsigned short* ws[3] = {w0p, w1p, w2p};

#pragma unroll
  for (int s = 0; s < 3; ++s) {
    if (s < nslab) {
      const float* xp = xs[s];
      __syncthreads();  // protect LDS from previous slab's readers
      {
        const float4* src = (const float4*)ws[s];
        float4* dst = (float4*)ldsb;
#pragma unroll
        for (int j = 0; j < 16; ++j) dst[tid + j * 256] = src[tid + j * 256];
      }
      __syncthreads();

#pragma unroll
      for (int ks = 0; ks < 8; ++ks) {
        const int k0 = ks * 16 + lhalf * 8;
        // A: global f32 -> hi/lo bf16 fragments
        bf16x8 ahi[2], alo[2];
#pragma unroll
        for (int as = 0; as < 2; ++as) {
          const float* ap = xp + (size_t)(as ? r1 : r0) * HD + k0;
          float4 va = *(const float4*)ap;
          float4 vb = *(const float4*)(ap + 4);
          float v[8] = {va.x, va.y, va.z, va.w, vb.x, vb.y, vb.z, vb.w};
#pragma unroll
          for (int j = 0; j < 8; ++j) {
            unsigned short h = f2bf(v[j]);
            unsigned short l = f2bf(v[j] - bf2f(h));
            ahi[as][j] = (short)h;
            alo[as][j] = (short)l;
          }
        }
        // B frags from LDS + MFMA
#pragma unroll
        for (int nt = 0; nt < 4; ++nt) {
          const int rown = nt * 32 + l31;
          const int kidx = k0 ^ ((rown & 15) << 3);
          const bf16x8 bhi = *(const bf16x8*)&ldsb[rown * HD + kidx];
          const bf16x8 blo = *(const bf16x8*)&ldsb[16384 + rown * HD + kidx];
#pragma unroll
          for (int as = 0; as < 2; ++as) {
            acc[as][nt] = __builtin_amdgcn_mfma_f32_32x32x16_bf16(ahi[as], bhi, acc[as][nt], 0, 0, 0);
            acc[as][nt] = __builtin_amdgcn_mfma_f32_32x32x16_bf16(ahi[as], blo, acc[as][nt], 0, 0, 0);
            acc[as][nt] = __builtin_amdgcn_mfma_f32_32x32x16_bf16(alo[as], bhi, acc[as][nt], 0, 0, 0);
          }
        }
      }
    }
  }

  // epilogue: bias (+b1), relu, store. All A reads done -> in-place safe.
#pragma unroll
  for (int nt = 0; nt < 4; ++nt) {
    const int col = nt * 32 + l31;
    float bias = b0[col] + (b1 ? b1[col] : 0.f);
#pragma unroll
    for (int as = 0; as < 2; ++as) {
#pragma unroll
      for (int rg = 0; rg < 16; ++rg) {
        int row = mbase + as * 32 + (rg & 3) + 8 * (rg >> 2) + 4 * lhalf;
        float v = acc[as][nt][rg] + bias;
        if (relu) v = fmaxf(v, 0.f);
        if (row < M) outp[(size_t)row * HD + col] = v;
      }
    }
  }
}

extern "C" void kernel_launch(void* const* d_in, const int* in_sizes, int n_in,
                              void* d_out, int out_size, void* d_ws, size_t ws_size,
                              hipStream_t stream) {
  const float* emb_g = (const float*)d_in[0];
  const float* emb_d = (const float*)d_in[1];
  const float* emb_c = (const float*)d_in[2];
  const float* Wl = (const float*)d_in[3];   // [2,4,128,128]
  const float* bl = (const float*)d_in[4];   // [2,4,128]
  const float* Wr = (const float*)d_in[5];   // [2,4,128,128]
  const int* eg_s  = (const int*)d_in[6];
  const int* eg_d  = (const int*)d_in[7];
  const int* ecd_s = (const int*)d_in[8];
  const int* ecd_d = (const int*)d_in[9];
  const int* ecg_s = (const int*)d_in[10];
  const int* ecg_d = (const int*)d_in[11];
  const int* egc_s = (const int*)d_in[12];
  const int* egc_d = (const int*)d_in[13];

  const int NG = in_sizes[0] / HD;
  const int ND = in_sizes[1] / HD;
  const int NC = in_sizes[2] / HD;
  const int E0 = in_sizes[6];   // g->g
  const int E1 = in_sizes[8];   // c->d
  const int E2 = in_sizes[10];  // c->g
  const int E3 = in_sizes[12];  // g->c
  const int HH = HD * HD;

  // ---- workspace carve ----
  char* w = (char*)d_ws;
  unsigned short* wprep = (unsigned short*)w; w += (size_t)14 * 65536;
  float* mean_gg = (float*)w; w += (size_t)NG * HD * 4;
  float* mean_cg = (float*)w; w += (size_t)NG * HD * 4;
  float* mean_cd = (float*)w; w += (size_t)ND * HD * 4;
  float* mean_gc = (float*)w; w += (size_t)NC * HD * 4;
  int* head_gg = (int*)w;     w += (size_t)NG * 4;
  int* head_cd = (int*)w;     w += (size_t)ND * 4;
  int* head_cg = (int*)w;     w += (size_t)NG * 4;
  int* head_gc = (int*)w;     w += (size_t)NC * 4;
  int* nxt0 = (int*)w;        w += (size_t)E0 * 4;
  int* nxt1 = (int*)w;        w += (size_t)E1 * 4;
  int* nxt2 = (int*)w;        w += (size_t)E2 * 4;
  int* nxt3 = (int*)w;        w += (size_t)E3 * 4;

  hipMemsetAsync(head_gg, 0xFF, (size_t)(NG + ND + NG + NC) * 4, stream);

  // W preprocessing: 7 slabs per layer:
  // 0:Wl0 1:Wl2 2:Wr0+Wr2 3:Wl1 4:Wr1 5:Wl3 6:Wr3
  PrepArgs pa;
  for (int L = 0; L < 2; ++L) {
    int b = L * 7;
    pa.a[b + 0] = Wl + (size_t)(L * 4 + 0) * HH; pa.b[b + 0] = nullptr;
    pa.a[b + 1] = Wl + (size_t)(L * 4 + 2) * HH; pa.b[b + 1] = nullptr;
    pa.a[b + 2] = Wr + (size_t)(L * 4 + 0) * HH; pa.b[b + 2] = Wr + (size_t)(L * 4 + 2) * HH;
    pa.a[b + 3] = Wl + (size_t)(L * 4 + 1) * HH; pa.b[b + 3] = nullptr;
    pa.a[b + 4] = Wr + (size_t)(L * 4 + 1) * HH; pa.b[b + 4] = nullptr;
    pa.a[b + 5] = Wl + (size_t)(L * 4 + 3) * HH; pa.b[b + 5] = nullptr;
    pa.a[b + 6] = Wr + (size_t)(L * 4 + 3) * HH; pa.b[b + 6] = nullptr;
  }
  k_prepw<<<dim3(14, 16), 256, 0, stream>>>(pa, wprep);

  k_build<<<(E0 + 255) / 256, 256, 0, stream>>>(eg_d,  head_gg, nxt0, E0);
  k_build<<<(E1 + 255) / 256, 256, 0, stream>>>(ecd_d, head_cd, nxt1, E1);
  k_build<<<(E2 + 255) / 256, 256, 0, stream>>>(ecg_d, head_cg, nxt2, E2);
  k_build<<<(E3 + 255) / 256, 256, 0, stream>>>(egc_d, head_gc, nxt3, E3);

  float* out = (float*)d_out;
  float* xg_out = out;
  float* xd_out = out + (size_t)NG * HD;
  float* xc_out = out + (size_t)(NG + ND) * HD;

  for (int L = 0; L < 2; ++L) {
    const float* xg = L ? (const float*)xg_out : emb_g;
    const float* xd = L ? (const float*)xd_out : emb_d;
    const float* xc = L ? (const float*)xc_out : emb_c;

    k_aggregate<<<(NG + 3) / 4, 256, 0, stream>>>(xg, eg_s,  head_gg, nxt0, mean_gg, NG);
    k_aggregate<<<(ND + 3) / 4, 256, 0, stream>>>(xc, ecd_s, head_cd, nxt1, mean_cd, ND);
    k_aggregate<<<(NG + 3) / 4, 256, 0, stream>>>(xc, ecg_s, head_cg, nxt2, mean_cg, NG);
    k_aggregate<<<(NC + 3) / 4, 256, 0, stream>>>(xg, egc_s, head_gc, nxt3, mean_gc, NC);

    const float* bl_L = bl + (size_t)L * 4 * HD;
    const unsigned short* wp = wprep + (size_t)L * 7 * 32768;
    int relu = (L == 0) ? 1 : 0;

    // genes: mean_gg@Wl0 + mean_cg@Wl2 + xg@(Wr0+Wr2) + bl0 + bl2
    k_gemm_mfma<<<(NG + 255) / 256, 256, 0, stream>>>(
        mean_gg, mean_cg, xg,
        wp + 0 * 32768, wp + 1 * 32768, wp + 2 * 32768, 3,
        bl_L + 0 * HD, bl_L + 2 * HD, xg_out, NG, relu);
    // disease: mean_cd@Wl1 + xd@Wr1 + bl1
    k_gemm_mfma<<<(ND + 255) / 256, 256, 0, stream>>>(
        mean_cd, xd, nullptr,
        wp + 3 * 32768, wp + 4 * 32768, nullptr, 2,
        bl_L + 1 * HD, nullptr, xd_out, ND, relu);
    // compound: mean_gc@Wl3 + xc@Wr3 + bl3
    k_gemm_mfma<<<(NC + 255) / 256, 256, 0, stream>>>(
        mean_gc, xc, nullptr,
        wp + 5 * 32768, wp + 6 * 32768, nullptr, 2,
        bl_L + 3 * HD, nullptr, xc_out, NC, relu);
  }
}

// Round 3
// 784.429 us; speedup vs baseline: 1.7721x; 1.1378x over previous
//
#include <hip/hip_runtime.h>

// HeteroGNN: 2-layer hetero SAGE (gene/disease/compound), H=128.
// R3: aggregation reworked from linked-list walk to on-device CSR:
//  - k_hist: per-dst degree histogram (int atomics).
//  - k_offsets: per-block LDS scan + one cursor atomic -> contiguous segments
//    (segment ORDER across blocks is arbitrary; irrelevant for correctness).
//  - k_scatter: srcs_sorted[atomicAdd(wp[dst])] = src  (stores src VALUE, so
//    aggregation needs no second indirection).
//  - k_aggregate: half-wave (32 lanes, float4/lane) per dst; 32 indices loaded
//    coalesced, shfl-broadcast, row gathers issued 4-wide (MLP).
// GEMM path unchanged from R2 (MFMA 32x32x16 bf16, split-bf16 3-MFMA).

constexpr int HD = 128;

typedef __attribute__((ext_vector_type(8))) short bf16x8;
typedef __attribute__((ext_vector_type(16))) float f32x16;

__device__ __forceinline__ unsigned short f2bf(float x) {
  unsigned u = __builtin_bit_cast(unsigned, x);
  u += 0x7FFF + ((u >> 16) & 1);  // RNE
  return (unsigned short)(u >> 16);
}
__device__ __forceinline__ float bf2f(unsigned short h) {
  return __builtin_bit_cast(float, (unsigned)h << 16);
}

// ---------------- CSR build ----------------
__global__ __launch_bounds__(256) void k_hist(const int* __restrict__ dst,
                                              int* __restrict__ cnt, int E) {
  int e = blockIdx.x * 256 + threadIdx.x;
  if (e < E) atomicAdd(&cnt[dst[e]], 1);
}

// per-block scan of 1024 counts + one cursor atomic for the block base.
__global__ __launch_bounds__(256) void k_offsets(const int* __restrict__ cnt, int n,
                                                 int* __restrict__ ptr, int* __restrict__ wp,
                                                 int* __restrict__ cursor) {
  int tid = threadIdx.x;
  int i0 = blockIdx.x * 1024 + tid * 4;
  int c[4];
  int s = 0;
#pragma unroll
  for (int j = 0; j < 4; ++j) {
    c[j] = (i0 + j < n) ? cnt[i0 + j] : 0;
    s += c[j];
  }
  int lane = tid & 63, wid = tid >> 6;
  int incl = s;
#pragma unroll
  for (int off = 1; off < 64; off <<= 1) {
    int t = __shfl_up(incl, off);
    if (lane >= off) incl += t;
  }
  __shared__ int wsum[4], wbase[5];
  if (lane == 63) wsum[wid] = incl;
  __syncthreads();
  if (tid == 0) {
    int b = 0;
#pragma unroll
    for (int w2 = 0; w2 < 4; ++w2) { wbase[w2] = b; b += wsum[w2]; }
    wbase[4] = atomicAdd(cursor, b);
  }
  __syncthreads();
  int run = wbase[4] + wbase[wid] + (incl - s);
#pragma unroll
  for (int j = 0; j < 4; ++j) {
    int i = i0 + j;
    if (i < n) { ptr[i] = run; wp[i] = run; }
    run += c[j];
  }
}

__global__ __launch_bounds__(256) void k_scatter(const int* __restrict__ src,
                                                 const int* __restrict__ dst,
                                                 int* __restrict__ wp,
                                                 int* __restrict__ srcs_sorted, int E) {
  int e = blockIdx.x * 256 + threadIdx.x;
  if (e < E) {
    int pos = atomicAdd(&wp[dst[e]], 1);
    srcs_sorted[pos] = src[e];
  }
}

// ---------------- neighbor mean via CSR ----------------
// half-wave (32 lanes) per dst; lane covers 4 floats (float4) of the 128-dim row.
__global__ __launch_bounds__(256) void k_aggregate(const float* __restrict__ xsrc,
                                                   const int* __restrict__ srcs,
                                                   const int* __restrict__ ptr,
                                                   const int* __restrict__ cnt,
                                                   float* __restrict__ mean, int n_dst) {
  int d = blockIdx.x * 8 + (threadIdx.x >> 5);
  if (d >= n_dst) return;
  int l = threadIdx.x & 31;
  int p = ptr[d];
  int deg = cnt[d];
  float4 acc = make_float4(0.f, 0.f, 0.f, 0.f);
  for (int j0 = 0; j0 < deg; j0 += 32) {
    int m = deg - j0;
    if (m > 32) m = 32;
    int idx = srcs[p + j0 + (l < m ? l : 0)];
    int j = 0;
    for (; j + 4 <= m; j += 4) {
      int s0 = __shfl(idx, j + 0, 32);
      int s1 = __shfl(idx, j + 1, 32);
      int s2 = __shfl(idx, j + 2, 32);
      int s3 = __shfl(idx, j + 3, 32);
      float4 v0 = *(const float4*)(xsrc + (size_t)s0 * HD + l * 4);
      float4 v1 = *(const float4*)(xsrc + (size_t)s1 * HD + l * 4);
      float4 v2 = *(const float4*)(xsrc + (size_t)s2 * HD + l * 4);
      float4 v3 = *(const float4*)(xsrc + (size_t)s3 * HD + l * 4);
      acc.x += v0.x + v1.x + v2.x + v3.x;
      acc.y += v0.y + v1.y + v2.y + v3.y;
      acc.z += v0.z + v1.z + v2.z + v3.z;
      acc.w += v0.w + v1.w + v2.w + v3.w;
    }
    for (; j < m; ++j) {
      int s = __shfl(idx, j, 32);
      float4 v = *(const float4*)(xsrc + (size_t)s * HD + l * 4);
      acc.x += v.x; acc.y += v.y; acc.z += v.z; acc.w += v.w;
    }
  }
  float inv = 1.0f / (float)(deg > 0 ? deg : 1);
  float4 r = make_float4(acc.x * inv, acc.y * inv, acc.z * inv, acc.w * inv);
  *(float4*)(mean + (size_t)d * HD + l * 4) = r;
}

// ---------------- W preprocessing ----------------
struct PrepArgs {
  const float* a[14];
  const float* b[14];
};

__global__ __launch_bounds__(256) void k_prepw(PrepArgs pa, unsigned short* __restrict__ out) {
  int s = blockIdx.x;
  const float* A = pa.a[s];
  const float* B = pa.b[s];
  unsigned short* oh = out + (size_t)s * 32768;
  int e0 = blockIdx.y * 1024 + threadIdx.x * 4;
#pragma unroll
  for (int j = 0; j < 4; ++j) {
    int e = e0 + j;
    int k = e >> 7, n = e & 127;
    float v = A[e] + (B ? B[e] : 0.f);
    unsigned short h = f2bf(v);
    unsigned short l = f2bf(v - bf2f(h));
    int idx = n * 128 + (k ^ ((n & 15) << 3));
    oh[idx] = h;
    oh[16384 + idx] = l;
  }
}

// ---------------- MFMA GEMM ----------------
__global__ __launch_bounds__(256, 2) void k_gemm_mfma(
    const float* __restrict__ x0, const float* __restrict__ x1, const float* __restrict__ x2,
    const unsigned short* __restrict__ w0p, const unsigned short* __restrict__ w1p,
    const unsigned short* __restrict__ w2p, int nslab,
    const float* __restrict__ b0, const float* __restrict__ b1,
    float* __restrict__ outp, int M, int relu) {
  __shared__ unsigned short ldsb[32768];  // 64KB: hi [0,16384), lo [16384,32768)
  const int tid = threadIdx.x;
  const int wave = tid >> 6;
  const int lane = tid & 63;
  const int l31 = lane & 31;
  const int lhalf = lane >> 5;

  const int mbase = blockIdx.x * 256 + wave * 64;
  int r0 = mbase + l31;
  int r1 = mbase + 32 + l31;
  if (r0 > M - 1) r0 = M - 1;
  if (r1 > M - 1) r1 = M - 1;

  f32x16 acc[2][4];
#pragma unroll
  for (int a = 0; a < 2; ++a)
#pragma unroll
    for (int n = 0; n < 4; ++n)
#pragma unroll
      for (int r = 0; r < 16; ++r) acc[a][n][r] = 0.f;

  const float* xs[3] = {x0, x1, x2};
  const unsigned short* ws[3] = {w0p, w1p, w2p};

#pragma unroll
  for (int s = 0; s < 3; ++s) {
    if (s < nslab) {
      const float* xp = xs[s];
      __syncthreads();  // protect LDS from previous slab's readers
      {
        const float4* src = (const float4*)ws[s];
        float4* dst = (float4*)ldsb;
#pragma unroll
        for (int j = 0; j < 16; ++j) dst[tid + j * 256] = src[tid + j * 256];
      }
      __syncthreads();

#pragma unroll
      for (int ks = 0; ks < 8; ++ks) {
        const int k0 = ks * 16 + lhalf * 8;
        bf16x8 ahi[2], alo[2];
#pragma unroll
        for (int as = 0; as < 2; ++as) {
          const float* ap = xp + (size_t)(as ? r1 : r0) * HD + k0;
          float4 va = *(const float4*)ap;
          float4 vb = *(const float4*)(ap + 4);
          float v[8] = {va.x, va.y, va.z, va.w, vb.x, vb.y, vb.z, vb.w};
#pragma unroll
          for (int j = 0; j < 8; ++j) {
            unsigned short h = f2bf(v[j]);
            unsigned short l = f2bf(v[j] - bf2f(h));
            ahi[as][j] = (short)h;
            alo[as][j] = (short)l;
          }
        }
#pragma unroll
        for (int nt = 0; nt < 4; ++nt) {
          const int rown = nt * 32 + l31;
          const int kidx = k0 ^ ((rown & 15) << 3);
          const bf16x8 bhi = *(const bf16x8*)&ldsb[rown * HD + kidx];
          const bf16x8 blo = *(const bf16x8*)&ldsb[16384 + rown * HD + kidx];
#pragma unroll
          for (int as = 0; as < 2; ++as) {
            acc[as][nt] = __builtin_amdgcn_mfma_f32_32x32x16_bf16(ahi[as], bhi, acc[as][nt], 0, 0, 0);
            acc[as][nt] = __builtin_amdgcn_mfma_f32_32x32x16_bf16(ahi[as], blo, acc[as][nt], 0, 0, 0);
            acc[as][nt] = __builtin_amdgcn_mfma_f32_32x32x16_bf16(alo[as], bhi, acc[as][nt], 0, 0, 0);
          }
        }
      }
    }
  }

#pragma unroll
  for (int nt = 0; nt < 4; ++nt) {
    const int col = nt * 32 + l31;
    float bias = b0[col] + (b1 ? b1[col] : 0.f);
#pragma unroll
    for (int as = 0; as < 2; ++as) {
#pragma unroll
      for (int rg = 0; rg < 16; ++rg) {
        int row = mbase + as * 32 + (rg & 3) + 8 * (rg >> 2) + 4 * lhalf;
        float v = acc[as][nt][rg] + bias;
        if (relu) v = fmaxf(v, 0.f);
        if (row < M) outp[(size_t)row * HD + col] = v;
      }
    }
  }
}

extern "C" void kernel_launch(void* const* d_in, const int* in_sizes, int n_in,
                              void* d_out, int out_size, void* d_ws, size_t ws_size,
                              hipStream_t stream) {
  const float* emb_g = (const float*)d_in[0];
  const float* emb_d = (const float*)d_in[1];
  const float* emb_c = (const float*)d_in[2];
  const float* Wl = (const float*)d_in[3];   // [2,4,128,128]
  const float* bl = (const float*)d_in[4];   // [2,4,128]
  const float* Wr = (const float*)d_in[5];   // [2,4,128,128]
  const int* eg_s  = (const int*)d_in[6];
  const int* eg_d  = (const int*)d_in[7];
  const int* ecd_s = (const int*)d_in[8];
  const int* ecd_d = (const int*)d_in[9];
  const int* ecg_s = (const int*)d_in[10];
  const int* ecg_d = (const int*)d_in[11];
  const int* egc_s = (const int*)d_in[12];
  const int* egc_d = (const int*)d_in[13];

  const int NG = in_sizes[0] / HD;
  const int ND = in_sizes[1] / HD;
  const int NC = in_sizes[2] / HD;
  const int E0 = in_sizes[6];   // g->g
  const int E1 = in_sizes[8];   // c->d
  const int E2 = in_sizes[10];  // c->g
  const int E3 = in_sizes[12];  // g->c
  const int HH = HD * HD;

  // ---- workspace carve (all 16B-aligned by construction) ----
  char* w = (char*)d_ws;
  unsigned short* wprep = (unsigned short*)w; w += (size_t)14 * 65536;
  float* mean_gg = (float*)w; w += (size_t)NG * HD * 4;
  float* mean_cg = (float*)w; w += (size_t)NG * HD * 4;
  float* mean_cd = (float*)w; w += (size_t)ND * HD * 4;
  float* mean_gc = (float*)w; w += (size_t)NC * HD * 4;
  int* ss0 = (int*)w;         w += (size_t)E0 * 4;
  int* ss1 = (int*)w;         w += (size_t)E1 * 4;
  int* ss2 = (int*)w;         w += (size_t)E2 * 4;
  int* ss3 = (int*)w;         w += (size_t)E3 * 4;
  int* ptr0 = (int*)w;        w += (size_t)NG * 4;
  int* ptr1 = (int*)w;        w += (size_t)ND * 4;
  int* ptr2 = (int*)w;        w += (size_t)NG * 4;
  int* ptr3 = (int*)w;        w += (size_t)NC * 4;
  int* wp0 = (int*)w;         w += (size_t)NG * 4;
  int* wp1 = (int*)w;         w += (size_t)ND * 4;
  int* wp2 = (int*)w;         w += (size_t)NG * 4;
  int* wp3 = (int*)w;         w += (size_t)NC * 4;
  // zeroed region: cnt x4 + cursors(4)
  int* cnt0 = (int*)w;        w += (size_t)NG * 4;
  int* cnt1 = (int*)w;        w += (size_t)ND * 4;
  int* cnt2 = (int*)w;        w += (size_t)NG * 4;
  int* cnt3 = (int*)w;        w += (size_t)NC * 4;
  int* cur = (int*)w;         w += 16;

  hipMemsetAsync(cnt0, 0, (size_t)(NG + ND + NG + NC + 4) * 4, stream);

  // CSR build (once; reused by both layers)
  k_hist<<<(E0 + 255) / 256, 256, 0, stream>>>(eg_d,  cnt0, E0);
  k_hist<<<(E1 + 255) / 256, 256, 0, stream>>>(ecd_d, cnt1, E1);
  k_hist<<<(E2 + 255) / 256, 256, 0, stream>>>(ecg_d, cnt2, E2);
  k_hist<<<(E3 + 255) / 256, 256, 0, stream>>>(egc_d, cnt3, E3);
  k_offsets<<<(NG + 1023) / 1024, 256, 0, stream>>>(cnt0, NG, ptr0, wp0, cur + 0);
  k_offsets<<<(ND + 1023) / 1024, 256, 0, stream>>>(cnt1, ND, ptr1, wp1, cur + 1);
  k_offsets<<<(NG + 1023) / 1024, 256, 0, stream>>>(cnt2, NG, ptr2, wp2, cur + 2);
  k_offsets<<<(NC + 1023) / 1024, 256, 0, stream>>>(cnt3, NC, ptr3, wp3, cur + 3);
  k_scatter<<<(E0 + 255) / 256, 256, 0, stream>>>(eg_s,  eg_d,  wp0, ss0, E0);
  k_scatter<<<(E1 + 255) / 256, 256, 0, stream>>>(ecd_s, ecd_d, wp1, ss1, E1);
  k_scatter<<<(E2 + 255) / 256, 256, 0, stream>>>(ecg_s, ecg_d, wp2, ss2, E2);
  k_scatter<<<(E3 + 255) / 256, 256, 0, stream>>>(egc_s, egc_d, wp3, ss3, E3);

  // W preprocessing: 7 slabs/layer: 0:Wl0 1:Wl2 2:Wr0+Wr2 3:Wl1 4:Wr1 5:Wl3 6:Wr3
  PrepArgs pa;
  for (int L = 0; L < 2; ++L) {
    int b = L * 7;
    pa.a[b + 0] = Wl + (size_t)(L * 4 + 0) * HH; pa.b[b + 0] = nullptr;
    pa.a[b + 1] = Wl + (size_t)(L * 4 + 2) * HH; pa.b[b + 1] = nullptr;
    pa.a[b + 2] = Wr + (size_t)(L * 4 + 0) * HH; pa.b[b + 2] = Wr + (size_t)(L * 4 + 2) * HH;
    pa.a[b + 3] = Wl + (size_t)(L * 4 + 1) * HH; pa.b[b + 3] = nullptr;
    pa.a[b + 4] = Wr + (size_t)(L * 4 + 1) * HH; pa.b[b + 4] = nullptr;
    pa.a[b + 5] = Wl + (size_t)(L * 4 + 3) * HH; pa.b[b + 5] = nullptr;
    pa.a[b + 6] = Wr + (size_t)(L * 4 + 3) * HH; pa.b[b + 6] = nullptr;
  }
  k_prepw<<<dim3(14, 16), 256, 0, stream>>>(pa, wprep);

  float* out = (float*)d_out;
  float* xg_out = out;
  float* xd_out = out + (size_t)NG * HD;
  float* xc_out = out + (size_t)(NG + ND) * HD;

  for (int L = 0; L < 2; ++L) {
    const float* xg = L ? (const float*)xg_out : emb_g;
    const float* xd = L ? (const float*)xd_out : emb_d;
    const float* xc = L ? (const float*)xc_out : emb_c;

    k_aggregate<<<(NG + 7) / 8, 256, 0, stream>>>(xg, ss0, ptr0, cnt0, mean_gg, NG);
    k_aggregate<<<(ND + 7) / 8, 256, 0, stream>>>(xc, ss1, ptr1, cnt1, mean_cd, ND);
    k_aggregate<<<(NG + 7) / 8, 256, 0, stream>>>(xc, ss2, ptr2, cnt2, mean_cg, NG);
    k_aggregate<<<(NC + 7) / 8, 256, 0, stream>>>(xg, ss3, ptr3, cnt3, mean_gc, NC);

    const float* bl_L = bl + (size_t)L * 4 * HD;
    const unsigned short* wp = wprep + (size_t)L * 7 * 32768;
    int relu = (L == 0) ? 1 : 0;

    // genes: mean_gg@Wl0 + mean_cg@Wl2 + xg@(Wr0+Wr2) + bl0 + bl2
    k_gemm_mfma<<<(NG + 255) / 256, 256, 0, stream>>>(
        mean_gg, mean_cg, xg,
        wp + 0 * 32768, wp + 1 * 32768, wp + 2 * 32768, 3,
        bl_L + 0 * HD, bl_L + 2 * HD, xg_out, NG, relu);
    // disease: mean_cd@Wl1 + xd@Wr1 + bl1
    k_gemm_mfma<<<(ND + 255) / 256, 256, 0, stream>>>(
        mean_cd, xd, nullptr,
        wp + 3 * 32768, wp + 4 * 32768, nullptr, 2,
        bl_L + 1 * HD, nullptr, xd_out, ND, relu);
    // compound: mean_gc@Wl3 + xc@Wr3 + bl3
    k_gemm_mfma<<<(NC + 255) / 256, 256, 0, stream>>>(
        mean_gc, xc, nullptr,
        wp + 5 * 32768, wp + 6 * 32768, nullptr, 2,
        bl_L + 3 * HD, nullptr, xc_out, NC, relu);
  }
}

// Round 4
// 669.223 us; speedup vs baseline: 2.0771x; 1.1721x over previous
//
#include <hip/hip_runtime.h>

// HeteroGNN: 2-layer hetero SAGE (gene/disease/compound), H=128.
// R4: bf16 data plane end-to-end.
//  - k_convert: emb f32 -> bf16 tables (once).
//  - CSR build fused: 1 hist + 1 offsets (single cursor, concat node space) + 1 scatter.
//  - k_aggregate_all: fused 4 relations; half-wave/dst; bf16 gathers (256B/row),
//    8-wide issue for MLP; f32 accumulate; bf16 mean out.
//  - k_gemm_mfma: A = bf16 tables (direct MFMA feed), B = bf16 swizzled LDS slab
//    (32KB), 1 MFMA per pair; layer-0 writes bf16 hidden tables (+relu),
//    layer-1 writes f32 d_out. f32 accumulation throughout.
// Error budget: each bf16 rounding source ~1e-4 RMS; expected absmax ~2e-3 vs
// threshold 5.586e-3.

constexpr int HD = 128;

typedef __attribute__((ext_vector_type(8))) short bf16x8;
typedef __attribute__((ext_vector_type(16))) float f32x16;

__device__ __forceinline__ unsigned short f2bf(float x) {
  unsigned u = __builtin_bit_cast(unsigned, x);
  u += 0x7FFF + ((u >> 16) & 1);  // RNE
  return (unsigned short)(u >> 16);
}
__device__ __forceinline__ float bf2f(unsigned short h) {
  return __builtin_bit_cast(float, (unsigned)h << 16);
}

// ---------------- f32 -> bf16 table convert (3 tables, fused) ----------------
__global__ __launch_bounds__(256) void k_convert(const float* __restrict__ s0,
                                                 const float* __restrict__ s1,
                                                 const float* __restrict__ s2,
                                                 unsigned short* __restrict__ d0,
                                                 unsigned short* __restrict__ d1,
                                                 unsigned short* __restrict__ d2,
                                                 long long n0, long long n1, long long n2) {
  long long i = ((long long)blockIdx.x * 256 + threadIdx.x) * 8;
  const float* s;
  unsigned short* d;
  if (i < n0) { s = s0 + i; d = d0 + i; }
  else if (i < n0 + n1) { s = s1 + (i - n0); d = d1 + (i - n0); }
  else if (i < n0 + n1 + n2) { s = s2 + (i - n0 - n1); d = d2 + (i - n0 - n1); }
  else return;
  float4 a = *(const float4*)s;
  float4 b = *(const float4*)(s + 4);
  uint4 o;
  o.x = (unsigned)f2bf(a.x) | ((unsigned)f2bf(a.y) << 16);
  o.y = (unsigned)f2bf(a.z) | ((unsigned)f2bf(a.w) << 16);
  o.z = (unsigned)f2bf(b.x) | ((unsigned)f2bf(b.y) << 16);
  o.w = (unsigned)f2bf(b.z) | ((unsigned)f2bf(b.w) << 16);
  *(uint4*)d = o;
}

// ---------------- CSR build (concatenated node/edge spaces) ----------------
struct GArgs {
  const int* esrc[4];
  const int* edst[4];
  int ebase[5];  // edge prefix
  int nbase[4];  // dst-node prefix per relation
};

__global__ __launch_bounds__(256) void k_hist_all(GArgs ga, int* __restrict__ cnt) {
  int e = blockIdx.x * 256 + threadIdx.x;
  if (e >= ga.ebase[4]) return;
  int r = (e >= ga.ebase[1]) + (e >= ga.ebase[2]) + (e >= ga.ebase[3]);
  int el = e - ga.ebase[r];
  atomicAdd(&cnt[ga.nbase[r] + ga.edst[r][el]], 1);
}

// per-block scan of 1024 counts + one cursor atomic for the block base.
__global__ __launch_bounds__(256) void k_offsets(const int* __restrict__ cnt, int n,
                                                 int* __restrict__ ptr, int* __restrict__ wp,
                                                 int* __restrict__ cursor) {
  int tid = threadIdx.x;
  int i0 = blockIdx.x * 1024 + tid * 4;
  int c[4];
  int s = 0;
#pragma unroll
  for (int j = 0; j < 4; ++j) {
    c[j] = (i0 + j < n) ? cnt[i0 + j] : 0;
    s += c[j];
  }
  int lane = tid & 63, wid = tid >> 6;
  int incl = s;
#pragma unroll
  for (int off = 1; off < 64; off <<= 1) {
    int t = __shfl_up(incl, off);
    if (lane >= off) incl += t;
  }
  __shared__ int wsum[4], wbase[5];
  if (lane == 63) wsum[wid] = incl;
  __syncthreads();
  if (tid == 0) {
    int b = 0;
#pragma unroll
    for (int w2 = 0; w2 < 4; ++w2) { wbase[w2] = b; b += wsum[w2]; }
    wbase[4] = atomicAdd(cursor, b);
  }
  __syncthreads();
  int run = wbase[4] + wbase[wid] + (incl - s);
#pragma unroll
  for (int j = 0; j < 4; ++j) {
    int i = i0 + j;
    if (i < n) { ptr[i] = run; wp[i] = run; }
    run += c[j];
  }
}

__global__ __launch_bounds__(256) void k_scatter_all(GArgs ga, int* __restrict__ wp,
                                                     int* __restrict__ ss) {
  int e = blockIdx.x * 256 + threadIdx.x;
  if (e >= ga.ebase[4]) return;
  int r = (e >= ga.ebase[1]) + (e >= ga.ebase[2]) + (e >= ga.ebase[3]);
  int el = e - ga.ebase[r];
  int pos = atomicAdd(&wp[ga.nbase[r] + ga.edst[r][el]], 1);
  ss[pos] = ga.esrc[r][el];
}

// ---------------- fused neighbor mean (4 relations) ----------------
struct AArgs {
  const unsigned short* xs[4];
  unsigned short* mean[4];
  int nbase[4];
  int bbase[5];  // block prefix
  int n[4];
};

__global__ __launch_bounds__(256) void k_aggregate_all(AArgs A, const int* __restrict__ ptr,
                                                       const int* __restrict__ cnt,
                                                       const int* __restrict__ ss) {
  int b = blockIdx.x;
  int r = (b >= A.bbase[1]) + (b >= A.bbase[2]) + (b >= A.bbase[3]);
  int d = (b - A.bbase[r]) * 8 + (threadIdx.x >> 5);
  if (d >= A.n[r]) return;
  const unsigned short* xs = A.xs[r];
  int l = threadIdx.x & 31;
  int g = A.nbase[r] + d;
  int p = ptr[g];
  int deg = cnt[g];
  float ax = 0.f, ay = 0.f, az = 0.f, aw = 0.f;
  for (int j0 = 0; j0 < deg; j0 += 32) {
    int m = deg - j0;
    if (m > 32) m = 32;
    int idx = ss[p + j0 + (l < m ? l : m - 1)];
    for (int j = 0; j < m; j += 8) {
      int mm = m - j;
      if (mm > 8) mm = 8;
      float4 vv[8];
#pragma unroll
      for (int k = 0; k < 8; ++k) {
        if (k < mm) {
          int s = __shfl(idx, j + k, 32);
          ushort4 u = *(const ushort4*)(xs + (size_t)s * HD + l * 4);
          vv[k] = make_float4(bf2f(u.x), bf2f(u.y), bf2f(u.z), bf2f(u.w));
        }
      }
#pragma unroll
      for (int k = 0; k < 8; ++k) {
        if (k < mm) { ax += vv[k].x; ay += vv[k].y; az += vv[k].z; aw += vv[k].w; }
      }
    }
  }
  float inv = 1.0f / (float)(deg > 0 ? deg : 1);
  ushort4 o;
  o.x = f2bf(ax * inv); o.y = f2bf(ay * inv);
  o.z = f2bf(az * inv); o.w = f2bf(aw * inv);
  *(ushort4*)(A.mean[r] + (size_t)d * HD + l * 4) = o;
}

// ---------------- W preprocessing ----------------
// W (or Wa+Wb) [k][n] f32 -> transposed [n][k] bf16, k swizzled:
// idx = n*128 + (k ^ ((n&15)<<3))  -> conflict-free ds_read_b128 in GEMM.
struct PrepArgs {
  const float* a[14];
  const float* b[14];
};

__global__ __launch_bounds__(256) void k_prepw(PrepArgs pa, unsigned short* __restrict__ out) {
  int s = blockIdx.x;
  const float* A = pa.a[s];
  const float* B = pa.b[s];
  unsigned short* oh = out + (size_t)s * 16384;
  int e0 = blockIdx.y * 1024 + threadIdx.x * 4;
#pragma unroll
  for (int j = 0; j < 4; ++j) {
    int e = e0 + j;
    int k = e >> 7, n = e & 127;
    float v = A[e] + (B ? B[e] : 0.f);
    oh[n * 128 + (k ^ ((n & 15) << 3))] = f2bf(v);
  }
}

// ---------------- MFMA GEMM (bf16 x bf16, f32 acc) ----------------
// out[M,128] = sum_s x_s[M,128] @ W_s + b0 (+b1); relu opt;
// layer0: outb (bf16 hidden table); layer1: outf (f32 d_out).
__global__ __launch_bounds__(256, 2) void k_gemm_mfma(
    const unsigned short* __restrict__ x0, const unsigned short* __restrict__ x1,
    const unsigned short* __restrict__ x2,
    const unsigned short* __restrict__ w0p, const unsigned short* __restrict__ w1p,
    const unsigned short* __restrict__ w2p, int nslab,
    const float* __restrict__ b0, const float* __restrict__ b1,
    float* __restrict__ outf, unsigned short* __restrict__ outb, int M, int relu) {
  __shared__ unsigned short ldsb[16384];  // 32KB
  const int tid = threadIdx.x;
  const int wave = tid >> 6;
  const int lane = tid & 63;
  const int l31 = lane & 31;
  const int lhalf = lane >> 5;

  const int mbase = blockIdx.x * 256 + wave * 64;
  int r0 = mbase + l31;
  int r1 = mbase + 32 + l31;
  if (r0 > M - 1) r0 = M - 1;
  if (r1 > M - 1) r1 = M - 1;

  f32x16 acc[2][4];
#pragma unroll
  for (int a = 0; a < 2; ++a)
#pragma unroll
    for (int n = 0; n < 4; ++n)
#pragma unroll
      for (int q = 0; q < 16; ++q) acc[a][n][q] = 0.f;

  const unsigned short* xs[3] = {x0, x1, x2};
  const unsigned short* ws[3] = {w0p, w1p, w2p};

#pragma unroll
  for (int s = 0; s < 3; ++s) {
    if (s < nslab) {
      const unsigned short* xp = xs[s];
      __syncthreads();  // protect LDS from previous slab's readers
      {
        const float4* src = (const float4*)ws[s];
        float4* dst = (float4*)ldsb;
#pragma unroll
        for (int j = 0; j < 8; ++j) dst[tid + j * 256] = src[tid + j * 256];
      }
      __syncthreads();

#pragma unroll
      for (int ks = 0; ks < 8; ++ks) {
        const int k0 = ks * 16 + lhalf * 8;
        bf16x8 a0 = *(const bf16x8*)(xp + (size_t)r0 * HD + k0);
        bf16x8 a1 = *(const bf16x8*)(xp + (size_t)r1 * HD + k0);
#pragma unroll
        for (int nt = 0; nt < 4; ++nt) {
          const int rown = nt * 32 + l31;
          const int kidx = k0 ^ ((rown & 15) << 3);
          const bf16x8 bb = *(const bf16x8*)&ldsb[rown * HD + kidx];
          acc[0][nt] = __builtin_amdgcn_mfma_f32_32x32x16_bf16(a0, bb, acc[0][nt], 0, 0, 0);
          acc[1][nt] = __builtin_amdgcn_mfma_f32_32x32x16_bf16(a1, bb, acc[1][nt], 0, 0, 0);
        }
      }
    }
  }

#pragma unroll
  for (int nt = 0; nt < 4; ++nt) {
    const int col = nt * 32 + l31;
    float bias = b0[col] + (b1 ? b1[col] : 0.f);
#pragma unroll
    for (int as = 0; as < 2; ++as) {
#pragma unroll
      for (int rg = 0; rg < 16; ++rg) {
        int row = mbase + as * 32 + (rg & 3) + 8 * (rg >> 2) + 4 * lhalf;
        float v = acc[as][nt][rg] + bias;
        if (relu) v = fmaxf(v, 0.f);
        if (row < M) {
          if (outf) outf[(size_t)row * HD + col] = v;
          else outb[(size_t)row * HD + col] = f2bf(v);
        }
      }
    }
  }
}

extern "C" void kernel_launch(void* const* d_in, const int* in_sizes, int n_in,
                              void* d_out, int out_size, void* d_ws, size_t ws_size,
                              hipStream_t stream) {
  const float* emb_g = (const float*)d_in[0];
  const float* emb_d = (const float*)d_in[1];
  const float* emb_c = (const float*)d_in[2];
  const float* Wl = (const float*)d_in[3];   // [2,4,128,128]
  const float* bl = (const float*)d_in[4];   // [2,4,128]
  const float* Wr = (const float*)d_in[5];   // [2,4,128,128]

  const int NG = in_sizes[0] / HD;
  const int ND = in_sizes[1] / HD;
  const int NC = in_sizes[2] / HD;
  const int E0 = in_sizes[6];   // g->g
  const int E1 = in_sizes[8];   // c->d
  const int E2 = in_sizes[10];  // c->g
  const int E3 = in_sizes[12];  // g->c
  const int HH = HD * HD;
  const int Etot = E0 + E1 + E2 + E3;
  const int Ntot = NG + ND + NG + NC;

  // ---- workspace carve (all 16B-aligned by construction) ----
  char* w = (char*)d_ws;
  unsigned short* wprep = (unsigned short*)w; w += (size_t)14 * 32768;
  unsigned short* xbf_g0 = (unsigned short*)w; w += (size_t)NG * HD * 2;
  unsigned short* xbf_d0 = (unsigned short*)w; w += (size_t)ND * HD * 2;
  unsigned short* xbf_c0 = (unsigned short*)w; w += (size_t)NC * HD * 2;
  unsigned short* xbf_g1 = (unsigned short*)w; w += (size_t)NG * HD * 2;
  unsigned short* xbf_d1 = (unsigned short*)w; w += (size_t)ND * HD * 2;
  unsigned short* xbf_c1 = (unsigned short*)w; w += (size_t)NC * HD * 2;
  unsigned short* mean_gg = (unsigned short*)w; w += (size_t)NG * HD * 2;
  unsigned short* mean_cd = (unsigned short*)w; w += (size_t)ND * HD * 2;
  unsigned short* mean_cg = (unsigned short*)w; w += (size_t)NG * HD * 2;
  unsigned short* mean_gc = (unsigned short*)w; w += (size_t)NC * HD * 2;
  int* ss = (int*)w;   w += (size_t)Etot * 4;
  int* ptr = (int*)w;  w += (size_t)Ntot * 4;
  int* wpp = (int*)w;  w += (size_t)Ntot * 4;
  int* cnt = (int*)w;  w += (size_t)Ntot * 4;  // zeroed (with cursor)
  int* cur = (int*)w;  w += 16;

  hipMemsetAsync(cnt, 0, ((size_t)Ntot + 4) * 4, stream);

  // bf16 feature tables for layer 0
  {
    long long n0 = (long long)NG * HD, n1 = (long long)ND * HD, n2 = (long long)NC * HD;
    long long tot8 = (n0 + n1 + n2) / 8;
    k_convert<<<(int)((tot8 + 255) / 256), 256, 0, stream>>>(emb_g, emb_d, emb_c,
                                                             xbf_g0, xbf_d0, xbf_c0, n0, n1, n2);
  }

  // CSR build over concatenated spaces
  GArgs ga;
  ga.esrc[0] = (const int*)d_in[6];  ga.edst[0] = (const int*)d_in[7];
  ga.esrc[1] = (const int*)d_in[8];  ga.edst[1] = (const int*)d_in[9];
  ga.esrc[2] = (const int*)d_in[10]; ga.edst[2] = (const int*)d_in[11];
  ga.esrc[3] = (const int*)d_in[12]; ga.edst[3] = (const int*)d_in[13];
  ga.ebase[0] = 0; ga.ebase[1] = E0; ga.ebase[2] = E0 + E1;
  ga.ebase[3] = E0 + E1 + E2; ga.ebase[4] = Etot;
  ga.nbase[0] = 0; ga.nbase[1] = NG; ga.nbase[2] = NG + ND; ga.nbase[3] = NG + ND + NG;

  k_hist_all<<<(Etot + 255) / 256, 256, 0, stream>>>(ga, cnt);
  k_offsets<<<(Ntot + 1023) / 1024, 256, 0, stream>>>(cnt, Ntot, ptr, wpp, cur);
  k_scatter_all<<<(Etot + 255) / 256, 256, 0, stream>>>(ga, wpp, ss);

  // W preprocessing: 7 slabs/layer: 0:Wl0 1:Wl2 2:Wr0+Wr2 3:Wl1 4:Wr1 5:Wl3 6:Wr3
  PrepArgs pa;
  for (int L = 0; L < 2; ++L) {
    int b = L * 7;
    pa.a[b + 0] = Wl + (size_t)(L * 4 + 0) * HH; pa.b[b + 0] = nullptr;
    pa.a[b + 1] = Wl + (size_t)(L * 4 + 2) * HH; pa.b[b + 1] = nullptr;
    pa.a[b + 2] = Wr + (size_t)(L * 4 + 0) * HH; pa.b[b + 2] = Wr + (size_t)(L * 4 + 2) * HH;
    pa.a[b + 3] = Wl + (size_t)(L * 4 + 1) * HH; pa.b[b + 3] = nullptr;
    pa.a[b + 4] = Wr + (size_t)(L * 4 + 1) * HH; pa.b[b + 4] = nullptr;
    pa.a[b + 5] = Wl + (size_t)(L * 4 + 3) * HH; pa.b[b + 5] = nullptr;
    pa.a[b + 6] = Wr + (size_t)(L * 4 + 3) * HH; pa.b[b + 6] = nullptr;
  }
  k_prepw<<<dim3(14, 16), 256, 0, stream>>>(pa, wprep);

  float* out = (float*)d_out;
  float* xg_out = out;
  float* xd_out = out + (size_t)NG * HD;
  float* xc_out = out + (size_t)(NG + ND) * HD;

  for (int L = 0; L < 2; ++L) {
    const unsigned short* xg = L ? xbf_g1 : xbf_g0;
    const unsigned short* xd = L ? xbf_d1 : xbf_d0;
    const unsigned short* xc = L ? xbf_c1 : xbf_c0;

    // fused aggregates (reln order: gg(src xg), cd(src xc), cg(src xc), gc(src xg))
    AArgs aa;
    aa.xs[0] = xg; aa.xs[1] = xc; aa.xs[2] = xc; aa.xs[3] = xg;
    aa.mean[0] = mean_gg; aa.mean[1] = mean_cd; aa.mean[2] = mean_cg; aa.mean[3] = mean_gc;
    aa.nbase[0] = 0; aa.nbase[1] = NG; aa.nbase[2] = NG + ND; aa.nbase[3] = NG + ND + NG;
    aa.n[0] = NG; aa.n[1] = ND; aa.n[2] = NG; aa.n[3] = NC;
    int bb = 0;
    for (int r = 0; r < 4; ++r) { aa.bbase[r] = bb; bb += (aa.n[r] + 7) / 8; }
    aa.bbase[4] = bb;
    k_aggregate_all<<<bb, 256, 0, stream>>>(aa, ptr, cnt, ss);

    const float* bl_L = bl + (size_t)L * 4 * HD;
    const unsigned short* wp = wprep + (size_t)L * 7 * 16384;
    int relu = (L == 0) ? 1 : 0;
    float* of_g = L ? xg_out : nullptr;
    float* of_d = L ? xd_out : nullptr;
    float* of_c = L ? xc_out : nullptr;

    // genes: mean_gg@Wl0 + mean_cg@Wl2 + xg@(Wr0+Wr2) + bl0 + bl2
    k_gemm_mfma<<<(NG + 255) / 256, 256, 0, stream>>>(
        mean_gg, mean_cg, xg,
        wp + 0 * 16384, wp + 1 * 16384, wp + 2 * 16384, 3,
        bl_L + 0 * HD, bl_L + 2 * HD, of_g, xbf_g1, NG, relu);
    // disease: mean_cd@Wl1 + xd@Wr1 + bl1
    k_gemm_mfma<<<(ND + 255) / 256, 256, 0, stream>>>(
        mean_cd, xd, nullptr,
        wp + 3 * 16384, wp + 4 * 16384, nullptr, 2,
        bl_L + 1 * HD, nullptr, of_d, xbf_d1, ND, relu);
    // compound: mean_gc@Wl3 + xc@Wr3 + bl3
    k_gemm_mfma<<<(NC + 255) / 256, 256, 0, stream>>>(
        mean_gc, xc, nullptr,
        wp + 5 * 16384, wp + 6 * 16384, nullptr, 2,
        bl_L + 3 * HD, nullptr, of_c, xbf_c1, NC, relu);
  }
}

// Round 5
// 503.170 us; speedup vs baseline: 2.7626x; 1.3300x over previous
//
#include <hip/hip_runtime.h>

// HeteroGNN: 2-layer hetero SAGE (gene/disease/compound), H=128.
// R5: CSR build reworked as two-pass LDS-binned counting sort (kills the
// 165us random-scatter + random-atomic k_scatter/k_hist):
//  - k_binA: 4096 edges/block, LDS bucket histogram (buckets = 1024-node
//    ranges of concat dst space), 1 global atomic per (block,bucket), packed
//    (dstLocal<<20|src) records written in per-bucket runs (line-efficient).
//  - k_binB: 1 block/bucket: LDS per-node hist + scan -> ptr/cnt written
//    directly; LDS-cursor scatter of ss within the bucket's contiguous output
//    (single-CU locality -> no write amplification). No global hist/offsets.
// Aggregation + GEMM unchanged from R4 (bf16 plane, MFMA 32x32x16, f32 acc).

constexpr int HD = 128;
constexpr int NBMAX = 512;    // max buckets (Ntot/1024 = 293 here)
constexpr int BSTRIDE = 32768; // per-bucket record capacity (expected max ~13K)

typedef __attribute__((ext_vector_type(8))) short bf16x8;
typedef __attribute__((ext_vector_type(16))) float f32x16;

__device__ __forceinline__ unsigned short f2bf(float x) {
  unsigned u = __builtin_bit_cast(unsigned, x);
  u += 0x7FFF + ((u >> 16) & 1);  // RNE
  return (unsigned short)(u >> 16);
}
__device__ __forceinline__ float bf2f(unsigned short h) {
  return __builtin_bit_cast(float, (unsigned)h << 16);
}

// ---------------- f32 -> bf16 table convert (3 tables, fused) ----------------
__global__ __launch_bounds__(256) void k_convert(const float* __restrict__ s0,
                                                 const float* __restrict__ s1,
                                                 const float* __restrict__ s2,
                                                 unsigned short* __restrict__ d0,
                                                 unsigned short* __restrict__ d1,
                                                 unsigned short* __restrict__ d2,
                                                 long long n0, long long n1, long long n2) {
  long long i = ((long long)blockIdx.x * 256 + threadIdx.x) * 8;
  const float* s;
  unsigned short* d;
  if (i < n0) { s = s0 + i; d = d0 + i; }
  else if (i < n0 + n1) { s = s1 + (i - n0); d = d1 + (i - n0); }
  else if (i < n0 + n1 + n2) { s = s2 + (i - n0 - n1); d = d2 + (i - n0 - n1); }
  else return;
  float4 a = *(const float4*)s;
  float4 b = *(const float4*)(s + 4);
  uint4 o;
  o.x = (unsigned)f2bf(a.x) | ((unsigned)f2bf(a.y) << 16);
  o.y = (unsigned)f2bf(a.z) | ((unsigned)f2bf(a.w) << 16);
  o.z = (unsigned)f2bf(b.x) | ((unsigned)f2bf(b.y) << 16);
  o.w = (unsigned)f2bf(b.z) | ((unsigned)f2bf(b.w) << 16);
  *(uint4*)d = o;
}

// ---------------- CSR build: two-pass binned sort ----------------
struct GArgs {
  const int* esrc[4];
  const int* edst[4];
  int ebase[5];  // edge prefix over concatenated edge space
  int nbase[4];  // dst-node prefix per relation (concat node space)
};

// Pass A: bin edges into 1024-node buckets; packed rec = (g&1023)<<20 | src.
__global__ __launch_bounds__(256) void k_binA(GArgs ga, int Etot, int NB,
                                              int* __restrict__ bucketCur,
                                              unsigned* __restrict__ binned) {
  __shared__ int hist[NBMAX];
  __shared__ int base[NBMAX];
  const int tid = threadIdx.x;
  for (int b = tid; b < NB; b += 256) hist[b] = 0;
  __syncthreads();
  const int e0 = blockIdx.x * 4096;
  for (int i = tid; i < 4096; i += 256) {
    int e = e0 + i;
    if (e < Etot) {
      int r = (e >= ga.ebase[1]) + (e >= ga.ebase[2]) + (e >= ga.ebase[3]);
      int g = ga.nbase[r] + ga.edst[r][e - ga.ebase[r]];
      atomicAdd(&hist[g >> 10], 1);
    }
  }
  __syncthreads();
  for (int b = tid; b < NB; b += 256) {
    int h = hist[b];
    base[b] = h ? atomicAdd(&bucketCur[b], h) : 0;
    hist[b] = 0;  // same thread owns b in both statements -> ordered
  }
  __syncthreads();
  for (int i = tid; i < 4096; i += 256) {
    int e = e0 + i;
    if (e < Etot) {
      int r = (e >= ga.ebase[1]) + (e >= ga.ebase[2]) + (e >= ga.ebase[3]);
      int el = e - ga.ebase[r];
      int g = ga.nbase[r] + ga.edst[r][el];
      int b = g >> 10;
      int pos = base[b] + atomicAdd(&hist[b], 1);
      binned[(size_t)b * BSTRIDE + pos] =
          ((unsigned)(g & 1023) << 20) | (unsigned)ga.esrc[r][el];
    }
  }
}

// Pass B: one block per bucket; per-node LDS hist + scan -> ptr/cnt; LDS-cursor
// scatter -> ss (bucket output is contiguous, single-CU -> L2-friendly).
__global__ __launch_bounds__(256) void k_binB(const int* __restrict__ bucketCur,
                                              const unsigned* __restrict__ binned,
                                              int* __restrict__ ptr, int* __restrict__ cnt,
                                              int* __restrict__ ss, int Ntot) {
  const int b = blockIdx.x;
  const int tid = threadIdx.x;
  __shared__ int ncnt[1024];
  __shared__ int noff[1024];
  __shared__ int red[256];
  __shared__ int sbase_s;
  __shared__ int wsum[4], wbase[4];

  // bucket output base = sum of bucketCur[0..b)
  int part = 0;
  for (int i = tid; i < b; i += 256) part += bucketCur[i];
  red[tid] = part;
  __syncthreads();
  for (int s = 128; s > 0; s >>= 1) {
    if (tid < s) red[tid] += red[tid + s];
    __syncthreads();
  }
  if (tid == 0) sbase_s = red[0];

  for (int j = tid; j < 1024; j += 256) ncnt[j] = 0;
  __syncthreads();

  const int ecount = bucketCur[b];
  const unsigned* bp = binned + (size_t)b * BSTRIDE;
  for (int i = tid; i < ecount; i += 256) atomicAdd(&ncnt[bp[i] >> 20], 1);
  __syncthreads();

  // exclusive scan over 1024 counts (4/thread + wave scan + wave bases)
  const int j0 = tid * 4;
  int c0 = ncnt[j0], c1 = ncnt[j0 + 1], c2 = ncnt[j0 + 2], c3 = ncnt[j0 + 3];
  int s4 = c0 + c1 + c2 + c3;
  int lane = tid & 63, wid = tid >> 6;
  int incl = s4;
#pragma unroll
  for (int off = 1; off < 64; off <<= 1) {
    int t = __shfl_up(incl, off);
    if (lane >= off) incl += t;
  }
  if (lane == 63) wsum[wid] = incl;
  __syncthreads();
  if (tid == 0) {
    int acc = 0;
#pragma unroll
    for (int w2 = 0; w2 < 4; ++w2) { wbase[w2] = acc; acc += wsum[w2]; }
  }
  __syncthreads();
  int excl = wbase[wid] + incl - s4;
  const int sbase = sbase_s;
  int o0 = excl, o1 = excl + c0, o2 = o1 + c1, o3 = o2 + c2;
  noff[j0] = o0; noff[j0 + 1] = o1; noff[j0 + 2] = o2; noff[j0 + 3] = o3;
  int g0 = b * 1024 + j0;
  if (g0 + 0 < Ntot) { ptr[g0 + 0] = sbase + o0; cnt[g0 + 0] = c0; }
  if (g0 + 1 < Ntot) { ptr[g0 + 1] = sbase + o1; cnt[g0 + 1] = c1; }
  if (g0 + 2 < Ntot) { ptr[g0 + 2] = sbase + o2; cnt[g0 + 2] = c2; }
  if (g0 + 3 < Ntot) { ptr[g0 + 3] = sbase + o3; cnt[g0 + 3] = c3; }
  __syncthreads();

  // scatter srcs using noff as per-node cursors
  for (int i = tid; i < ecount; i += 256) {
    unsigned rec = bp[i];
    int j = rec >> 20;
    int p = sbase + atomicAdd(&noff[j], 1);
    ss[p] = (int)(rec & 0xFFFFF);
  }
}

// ---------------- fused neighbor mean (4 relations) ----------------
struct AArgs {
  const unsigned short* xs[4];
  unsigned short* mean[4];
  int nbase[4];
  int bbase[5];  // block prefix
  int n[4];
};

__global__ __launch_bounds__(256) void k_aggregate_all(AArgs A, const int* __restrict__ ptr,
                                                       const int* __restrict__ cnt,
                                                       const int* __restrict__ ss) {
  int b = blockIdx.x;
  int r = (b >= A.bbase[1]) + (b >= A.bbase[2]) + (b >= A.bbase[3]);
  int d = (b - A.bbase[r]) * 8 + (threadIdx.x >> 5);
  if (d >= A.n[r]) return;
  const unsigned short* xs = A.xs[r];
  int l = threadIdx.x & 31;
  int g = A.nbase[r] + d;
  int p = ptr[g];
  int deg = cnt[g];
  float ax = 0.f, ay = 0.f, az = 0.f, aw = 0.f;
  for (int j0 = 0; j0 < deg; j0 += 32) {
    int m = deg - j0;
    if (m > 32) m = 32;
    int idx = ss[p + j0 + (l < m ? l : m - 1)];
    for (int j = 0; j < m; j += 8) {
      int mm = m - j;
      if (mm > 8) mm = 8;
      float4 vv[8];
#pragma unroll
      for (int k = 0; k < 8; ++k) {
        if (k < mm) {
          int s = __shfl(idx, j + k, 32);
          ushort4 u = *(const ushort4*)(xs + (size_t)s * HD + l * 4);
          vv[k] = make_float4(bf2f(u.x), bf2f(u.y), bf2f(u.z), bf2f(u.w));
        }
      }
#pragma unroll
      for (int k = 0; k < 8; ++k) {
        if (k < mm) { ax += vv[k].x; ay += vv[k].y; az += vv[k].z; aw += vv[k].w; }
      }
    }
  }
  float inv = 1.0f / (float)(deg > 0 ? deg : 1);
  ushort4 o;
  o.x = f2bf(ax * inv); o.y = f2bf(ay * inv);
  o.z = f2bf(az * inv); o.w = f2bf(aw * inv);
  *(ushort4*)(A.mean[r] + (size_t)d * HD + l * 4) = o;
}

// ---------------- W preprocessing ----------------
// W (or Wa+Wb) [k][n] f32 -> transposed [n][k] bf16, k swizzled:
// idx = n*128 + (k ^ ((n&15)<<3))  -> conflict-free ds_read_b128 in GEMM.
struct PrepArgs {
  const float* a[14];
  const float* b[14];
};

__global__ __launch_bounds__(256) void k_prepw(PrepArgs pa, unsigned short* __restrict__ out) {
  int s = blockIdx.x;
  const float* A = pa.a[s];
  const float* B = pa.b[s];
  unsigned short* oh = out + (size_t)s * 16384;
  int e0 = blockIdx.y * 1024 + threadIdx.x * 4;
#pragma unroll
  for (int j = 0; j < 4; ++j) {
    int e = e0 + j;
    int k = e >> 7, n = e & 127;
    float v = A[e] + (B ? B[e] : 0.f);
    oh[n * 128 + (k ^ ((n & 15) << 3))] = f2bf(v);
  }
}

// ---------------- MFMA GEMM (bf16 x bf16, f32 acc) ----------------
__global__ __launch_bounds__(256, 2) void k_gemm_mfma(
    const unsigned short* __restrict__ x0, const unsigned short* __restrict__ x1,
    const unsigned short* __restrict__ x2,
    const unsigned short* __restrict__ w0p, const unsigned short* __restrict__ w1p,
    const unsigned short* __restrict__ w2p, int nslab,
    const float* __restrict__ b0, const float* __restrict__ b1,
    float* __restrict__ outf, unsigned short* __restrict__ outb, int M, int relu) {
  __shared__ unsigned short ldsb[16384];  // 32KB
  const int tid = threadIdx.x;
  const int wave = tid >> 6;
  const int lane = tid & 63;
  const int l31 = lane & 31;
  const int lhalf = lane >> 5;

  const int mbase = blockIdx.x * 256 + wave * 64;
  int r0 = mbase + l31;
  int r1 = mbase + 32 + l31;
  if (r0 > M - 1) r0 = M - 1;
  if (r1 > M - 1) r1 = M - 1;

  f32x16 acc[2][4];
#pragma unroll
  for (int a = 0; a < 2; ++a)
#pragma unroll
    for (int n = 0; n < 4; ++n)
#pragma unroll
      for (int q = 0; q < 16; ++q) acc[a][n][q] = 0.f;

  const unsigned short* xs[3] = {x0, x1, x2};
  const unsigned short* ws[3] = {w0p, w1p, w2p};

#pragma unroll
  for (int s = 0; s < 3; ++s) {
    if (s < nslab) {
      const unsigned short* xp = xs[s];
      __syncthreads();  // protect LDS from previous slab's readers
      {
        const float4* src = (const float4*)ws[s];
        float4* dst = (float4*)ldsb;
#pragma unroll
        for (int j = 0; j < 8; ++j) dst[tid + j * 256] = src[tid + j * 256];
      }
      __syncthreads();

#pragma unroll
      for (int ks = 0; ks < 8; ++ks) {
        const int k0 = ks * 16 + lhalf * 8;
        bf16x8 a0 = *(const bf16x8*)(xp + (size_t)r0 * HD + k0);
        bf16x8 a1 = *(const bf16x8*)(xp + (size_t)r1 * HD + k0);
#pragma unroll
        for (int nt = 0; nt < 4; ++nt) {
          const int rown = nt * 32 + l31;
          const int kidx = k0 ^ ((rown & 15) << 3);
          const bf16x8 bb = *(const bf16x8*)&ldsb[rown * HD + kidx];
          acc[0][nt] = __builtin_amdgcn_mfma_f32_32x32x16_bf16(a0, bb, acc[0][nt], 0, 0, 0);
          acc[1][nt] = __builtin_amdgcn_mfma_f32_32x32x16_bf16(a1, bb, acc[1][nt], 0, 0, 0);
        }
      }
    }
  }

#pragma unroll
  for (int nt = 0; nt < 4; ++nt) {
    const int col = nt * 32 + l31;
    float bias = b0[col] + (b1 ? b1[col] : 0.f);
#pragma unroll
    for (int as = 0; as < 2; ++as) {
#pragma unroll
      for (int rg = 0; rg < 16; ++rg) {
        int row = mbase + as * 32 + (rg & 3) + 8 * (rg >> 2) + 4 * lhalf;
        float v = acc[as][nt][rg] + bias;
        if (relu) v = fmaxf(v, 0.f);
        if (row < M) {
          if (outf) outf[(size_t)row * HD + col] = v;
          else outb[(size_t)row * HD + col] = f2bf(v);
        }
      }
    }
  }
}

extern "C" void kernel_launch(void* const* d_in, const int* in_sizes, int n_in,
                              void* d_out, int out_size, void* d_ws, size_t ws_size,
                              hipStream_t stream) {
  const float* emb_g = (const float*)d_in[0];
  const float* emb_d = (const float*)d_in[1];
  const float* emb_c = (const float*)d_in[2];
  const float* Wl = (const float*)d_in[3];   // [2,4,128,128]
  const float* bl = (const float*)d_in[4];   // [2,4,128]
  const float* Wr = (const float*)d_in[5];   // [2,4,128,128]

  const int NG = in_sizes[0] / HD;
  const int ND = in_sizes[1] / HD;
  const int NC = in_sizes[2] / HD;
  const int E0 = in_sizes[6];   // g->g
  const int E1 = in_sizes[8];   // c->d
  const int E2 = in_sizes[10];  // c->g
  const int E3 = in_sizes[12];  // g->c
  const int HH = HD * HD;
  const int Etot = E0 + E1 + E2 + E3;
  const int Ntot = NG + ND + NG + NC;
  const int NB = (Ntot + 1023) >> 10;  // 1024-node buckets

  // ---- workspace carve (all 16B-aligned by construction) ----
  char* w = (char*)d_ws;
  unsigned short* wprep = (unsigned short*)w; w += (size_t)14 * 32768;
  unsigned short* xbf_g0 = (unsigned short*)w; w += (size_t)NG * HD * 2;
  unsigned short* xbf_d0 = (unsigned short*)w; w += (size_t)ND * HD * 2;
  unsigned short* xbf_c0 = (unsigned short*)w; w += (size_t)NC * HD * 2;
  unsigned short* xbf_g1 = (unsigned short*)w; w += (size_t)NG * HD * 2;
  unsigned short* xbf_d1 = (unsigned short*)w; w += (size_t)ND * HD * 2;
  unsigned short* xbf_c1 = (unsigned short*)w; w += (size_t)NC * HD * 2;
  unsigned short* mean_gg = (unsigned short*)w; w += (size_t)NG * HD * 2;
  unsigned short* mean_cd = (unsigned short*)w; w += (size_t)ND * HD * 2;
  unsigned short* mean_cg = (unsigned short*)w; w += (size_t)NG * HD * 2;
  unsigned short* mean_gc = (unsigned short*)w; w += (size_t)NC * HD * 2;
  int* ss = (int*)w;        w += (size_t)Etot * 4;
  int* ptr = (int*)w;       w += (size_t)Ntot * 4;
  int* cnt = (int*)w;       w += (size_t)Ntot * 4;
  unsigned* binned = (unsigned*)w; w += (size_t)NB * BSTRIDE * 4;
  int* bucketCur = (int*)w; w += (size_t)NBMAX * 4;  // zeroed

  hipMemsetAsync(bucketCur, 0, (size_t)NBMAX * 4, stream);

  // bf16 feature tables for layer 0
  {
    long long n0 = (long long)NG * HD, n1 = (long long)ND * HD, n2 = (long long)NC * HD;
    long long tot8 = (n0 + n1 + n2) / 8;
    k_convert<<<(int)((tot8 + 255) / 256), 256, 0, stream>>>(emb_g, emb_d, emb_c,
                                                             xbf_g0, xbf_d0, xbf_c0, n0, n1, n2);
  }

  // CSR build over concatenated spaces (two-pass binned sort)
  GArgs ga;
  ga.esrc[0] = (const int*)d_in[6];  ga.edst[0] = (const int*)d_in[7];
  ga.esrc[1] = (const int*)d_in[8];  ga.edst[1] = (const int*)d_in[9];
  ga.esrc[2] = (const int*)d_in[10]; ga.edst[2] = (const int*)d_in[11];
  ga.esrc[3] = (const int*)d_in[12]; ga.edst[3] = (const int*)d_in[13];
  ga.ebase[0] = 0; ga.ebase[1] = E0; ga.ebase[2] = E0 + E1;
  ga.ebase[3] = E0 + E1 + E2; ga.ebase[4] = Etot;
  ga.nbase[0] = 0; ga.nbase[1] = NG; ga.nbase[2] = NG + ND; ga.nbase[3] = NG + ND + NG;

  k_binA<<<(Etot + 4095) / 4096, 256, 0, stream>>>(ga, Etot, NB, bucketCur, binned);
  k_binB<<<NB, 256, 0, stream>>>(bucketCur, binned, ptr, cnt, ss, Ntot);

  // W preprocessing: 7 slabs/layer: 0:Wl0 1:Wl2 2:Wr0+Wr2 3:Wl1 4:Wr1 5:Wl3 6:Wr3
  PrepArgs pa;
  for (int L = 0; L < 2; ++L) {
    int b = L * 7;
    pa.a[b + 0] = Wl + (size_t)(L * 4 + 0) * HH; pa.b[b + 0] = nullptr;
    pa.a[b + 1] = Wl + (size_t)(L * 4 + 2) * HH; pa.b[b + 1] = nullptr;
    pa.a[b + 2] = Wr + (size_t)(L * 4 + 0) * HH; pa.b[b + 2] = Wr + (size_t)(L * 4 + 2) * HH;
    pa.a[b + 3] = Wl + (size_t)(L * 4 + 1) * HH; pa.b[b + 3] = nullptr;
    pa.a[b + 4] = Wr + (size_t)(L * 4 + 1) * HH; pa.b[b + 4] = nullptr;
    pa.a[b + 5] = Wl + (size_t)(L * 4 + 3) * HH; pa.b[b + 5] = nullptr;
    pa.a[b + 6] = Wr + (size_t)(L * 4 + 3) * HH; pa.b[b + 6] = nullptr;
  }
  k_prepw<<<dim3(14, 16), 256, 0, stream>>>(pa, wprep);

  float* out = (float*)d_out;
  float* xg_out = out;
  float* xd_out = out + (size_t)NG * HD;
  float* xc_out = out + (size_t)(NG + ND) * HD;

  for (int L = 0; L < 2; ++L) {
    const unsigned short* xg = L ? xbf_g1 : xbf_g0;
    const unsigned short* xd = L ? xbf_d1 : xbf_d0;
    const unsigned short* xc = L ? xbf_c1 : xbf_c0;

    // fused aggregates (reln order: gg(src xg), cd(src xc), cg(src xc), gc(src xg))
    AArgs aa;
    aa.xs[0] = xg; aa.xs[1] = xc; aa.xs[2] = xc; aa.xs[3] = xg;
    aa.mean[0] = mean_gg; aa.mean[1] = mean_cd; aa.mean[2] = mean_cg; aa.mean[3] = mean_gc;
    aa.nbase[0] = 0; aa.nbase[1] = NG; aa.nbase[2] = NG + ND; aa.nbase[3] = NG + ND + NG;
    aa.n[0] = NG; aa.n[1] = ND; aa.n[2] = NG; aa.n[3] = NC;
    int bb = 0;
    for (int r = 0; r < 4; ++r) { aa.bbase[r] = bb; bb += (aa.n[r] + 7) / 8; }
    aa.bbase[4] = bb;
    k_aggregate_all<<<bb, 256, 0, stream>>>(aa, ptr, cnt, ss);

    const float* bl_L = bl + (size_t)L * 4 * HD;
    const unsigned short* wp = wprep + (size_t)L * 7 * 16384;
    int relu = (L == 0) ? 1 : 0;
    float* of_g = L ? xg_out : nullptr;
    float* of_d = L ? xd_out : nullptr;
    float* of_c = L ? xc_out : nullptr;

    // genes: mean_gg@Wl0 + mean_cg@Wl2 + xg@(Wr0+Wr2) + bl0 + bl2
    k_gemm_mfma<<<(NG + 255) / 256, 256, 0, stream>>>(
        mean_gg, mean_cg, xg,
        wp + 0 * 16384, wp + 1 * 16384, wp + 2 * 16384, 3,
        bl_L + 0 * HD, bl_L + 2 * HD, of_g, xbf_g1, NG, relu);
    // disease: mean_cd@Wl1 + xd@Wr1 + bl1
    k_gemm_mfma<<<(ND + 255) / 256, 256, 0, stream>>>(
        mean_cd, xd, nullptr,
        wp + 3 * 16384, wp + 4 * 16384, nullptr, 2,
        bl_L + 1 * HD, nullptr, of_d, xbf_d1, ND, relu);
    // compound: mean_gc@Wl3 + xc@Wr3 + bl3
    k_gemm_mfma<<<(NC + 255) / 256, 256, 0, stream>>>(
        mean_gc, xc, nullptr,
        wp + 5 * 16384, wp + 6 * 16384, nullptr, 2,
        bl_L + 3 * HD, nullptr, of_c, xbf_c1, NC, relu);
  }
}

// Round 6
// 493.655 us; speedup vs baseline: 2.8159x; 1.0193x over previous
//
#include <hip/hip_runtime.h>

// HeteroGNN: 2-layer hetero SAGE (gene/disease/compound), H=128.
// R6: fp8(e4m3, x16 scale) gather tables for aggregation (halves gather bytes:
// 256B -> 128B/row). Only the neighbor-mean path sees fp8; GEMM A-operands
// (means + x_dst) remain bf16, f32 accumulate. Scale x16 avoids the fp8
// subnormal floor and folds out exactly via inv = 1/(16*deg).
//  - k_convert: emb f32 -> bf16 tables AND fp8 tables (once).
//  - k_cvt8: hidden bf16 (contiguous g1|d1|c1) -> fp8 hidden tables (~6us).
//  - k_aggregate_all: gathers fp8 rows (1 dword/lane), v_cvt_pk_f32_fp8 decode.
// CSR build (binned sort) + MFMA GEMM unchanged from R5.

constexpr int HD = 128;
constexpr int NBMAX = 512;     // max buckets (Ntot/1024 = 293 here)
constexpr int BSTRIDE = 32768; // per-bucket record capacity (expected max ~13K)

typedef __attribute__((ext_vector_type(8))) short bf16x8;
typedef __attribute__((ext_vector_type(16))) float f32x16;
typedef __attribute__((ext_vector_type(2))) float f32x2;

__device__ __forceinline__ unsigned short f2bf(float x) {
  unsigned u = __builtin_bit_cast(unsigned, x);
  u += 0x7FFF + ((u >> 16) & 1);  // RNE
  return (unsigned short)(u >> 16);
}
__device__ __forceinline__ float bf2f(unsigned short h) {
  return __builtin_bit_cast(float, (unsigned)h << 16);
}

// pack 8 f32 (x16 scale) -> 8 fp8 bytes (uint2)
__device__ __forceinline__ uint2 pack_fp8x8(const float* v) {
  uint2 o;
  unsigned t;
  t = (unsigned)__builtin_amdgcn_cvt_pk_fp8_f32(v[0] * 16.f, v[1] * 16.f, 0, false);
  t = (unsigned)__builtin_amdgcn_cvt_pk_fp8_f32(v[2] * 16.f, v[3] * 16.f, (int)t, true);
  o.x = t;
  t = (unsigned)__builtin_amdgcn_cvt_pk_fp8_f32(v[4] * 16.f, v[5] * 16.f, 0, false);
  t = (unsigned)__builtin_amdgcn_cvt_pk_fp8_f32(v[6] * 16.f, v[7] * 16.f, (int)t, true);
  o.y = t;
  return o;
}

// ---------------- f32 -> bf16 + fp8 table convert (3 tables, fused) ----------------
__global__ __launch_bounds__(256) void k_convert(const float* __restrict__ s0,
                                                 const float* __restrict__ s1,
                                                 const float* __restrict__ s2,
                                                 unsigned short* __restrict__ d0,
                                                 unsigned short* __restrict__ d1,
                                                 unsigned short* __restrict__ d2,
                                                 unsigned char* __restrict__ e0,
                                                 unsigned char* __restrict__ e1,
                                                 unsigned char* __restrict__ e2,
                                                 long long n0, long long n1, long long n2) {
  long long i = ((long long)blockIdx.x * 256 + threadIdx.x) * 8;
  const float* s;
  unsigned short* d;
  unsigned char* e;
  if (i < n0) { s = s0 + i; d = d0 + i; e = e0 + i; }
  else if (i < n0 + n1) { s = s1 + (i - n0); d = d1 + (i - n0); e = e1 + (i - n0); }
  else if (i < n0 + n1 + n2) { s = s2 + (i - n0 - n1); d = d2 + (i - n0 - n1); e = e2 + (i - n0 - n1); }
  else return;
  float4 a = *(const float4*)s;
  float4 b = *(const float4*)(s + 4);
  float v[8] = {a.x, a.y, a.z, a.w, b.x, b.y, b.z, b.w};
  uint4 o;
  o.x = (unsigned)f2bf(v[0]) | ((unsigned)f2bf(v[1]) << 16);
  o.y = (unsigned)f2bf(v[2]) | ((unsigned)f2bf(v[3]) << 16);
  o.z = (unsigned)f2bf(v[4]) | ((unsigned)f2bf(v[5]) << 16);
  o.w = (unsigned)f2bf(v[6]) | ((unsigned)f2bf(v[7]) << 16);
  *(uint4*)d = o;
  *(uint2*)e = pack_fp8x8(v);
}

// ---------------- bf16 -> fp8 (hidden tables, contiguous region) ----------------
__global__ __launch_bounds__(256) void k_cvt8(const unsigned short* __restrict__ in,
                                              unsigned char* __restrict__ out8, long long n8) {
  long long i = (long long)blockIdx.x * 256 + threadIdx.x;  // group of 8 elems
  if (i >= n8) return;
  uint4 u = *(const uint4*)(in + i * 8);
  float v[8];
  v[0] = bf2f((unsigned short)(u.x & 0xFFFF)); v[1] = bf2f((unsigned short)(u.x >> 16));
  v[2] = bf2f((unsigned short)(u.y & 0xFFFF)); v[3] = bf2f((unsigned short)(u.y >> 16));
  v[4] = bf2f((unsigned short)(u.z & 0xFFFF)); v[5] = bf2f((unsigned short)(u.z >> 16));
  v[6] = bf2f((unsigned short)(u.w & 0xFFFF)); v[7] = bf2f((unsigned short)(u.w >> 16));
  *(uint2*)(out8 + i * 8) = pack_fp8x8(v);
}

// ---------------- CSR build: two-pass binned sort ----------------
struct GArgs {
  const int* esrc[4];
  const int* edst[4];
  int ebase[5];  // edge prefix over concatenated edge space
  int nbase[4];  // dst-node prefix per relation (concat node space)
};

// Pass A: bin edges into 1024-node buckets; packed rec = (g&1023)<<20 | src.
__global__ __launch_bounds__(256) void k_binA(GArgs ga, int Etot, int NB,
                                              int* __restrict__ bucketCur,
                                              unsigned* __restrict__ binned) {
  __shared__ int hist[NBMAX];
  __shared__ int base[NBMAX];
  const int tid = threadIdx.x;
  for (int b = tid; b < NB; b += 256) hist[b] = 0;
  __syncthreads();
  const int e0 = blockIdx.x * 4096;
  for (int i = tid; i < 4096; i += 256) {
    int e = e0 + i;
    if (e < Etot) {
      int r = (e >= ga.ebase[1]) + (e >= ga.ebase[2]) + (e >= ga.ebase[3]);
      int g = ga.nbase[r] + ga.edst[r][e - ga.ebase[r]];
      atomicAdd(&hist[g >> 10], 1);
    }
  }
  __syncthreads();
  for (int b = tid; b < NB; b += 256) {
    int h = hist[b];
    base[b] = h ? atomicAdd(&bucketCur[b], h) : 0;
    hist[b] = 0;  // same thread owns b in both statements -> ordered
  }
  __syncthreads();
  for (int i = tid; i < 4096; i += 256) {
    int e = e0 + i;
    if (e < Etot) {
      int r = (e >= ga.ebase[1]) + (e >= ga.ebase[2]) + (e >= ga.ebase[3]);
      int el = e - ga.ebase[r];
      int g = ga.nbase[r] + ga.edst[r][el];
      int b = g >> 10;
      int pos = base[b] + atomicAdd(&hist[b], 1);
      binned[(size_t)b * BSTRIDE + pos] =
          ((unsigned)(g & 1023) << 20) | (unsigned)ga.esrc[r][el];
    }
  }
}

// Pass B: one block per bucket; per-node LDS hist + scan -> ptr/cnt; LDS-cursor
// scatter -> ss (bucket output contiguous, single-CU -> L2-friendly).
__global__ __launch_bounds__(256) void k_binB(const int* __restrict__ bucketCur,
                                              const unsigned* __restrict__ binned,
                                              int* __restrict__ ptr, int* __restrict__ cnt,
                                              int* __restrict__ ss, int Ntot) {
  const int b = blockIdx.x;
  const int tid = threadIdx.x;
  __shared__ int ncnt[1024];
  __shared__ int noff[1024];
  __shared__ int red[256];
  __shared__ int sbase_s;
  __shared__ int wsum[4], wbase[4];

  int part = 0;
  for (int i = tid; i < b; i += 256) part += bucketCur[i];
  red[tid] = part;
  __syncthreads();
  for (int s = 128; s > 0; s >>= 1) {
    if (tid < s) red[tid] += red[tid + s];
    __syncthreads();
  }
  if (tid == 0) sbase_s = red[0];

  for (int j = tid; j < 1024; j += 256) ncnt[j] = 0;
  __syncthreads();

  const int ecount = bucketCur[b];
  const unsigned* bp = binned + (size_t)b * BSTRIDE;
  for (int i = tid; i < ecount; i += 256) atomicAdd(&ncnt[bp[i] >> 20], 1);
  __syncthreads();

  const int j0 = tid * 4;
  int c0 = ncnt[j0], c1 = ncnt[j0 + 1], c2 = ncnt[j0 + 2], c3 = ncnt[j0 + 3];
  int s4 = c0 + c1 + c2 + c3;
  int lane = tid & 63, wid = tid >> 6;
  int incl = s4;
#pragma unroll
  for (int off = 1; off < 64; off <<= 1) {
    int t = __shfl_up(incl, off);
    if (lane >= off) incl += t;
  }
  if (lane == 63) wsum[wid] = incl;
  __syncthreads();
  if (tid == 0) {
    int acc = 0;
#pragma unroll
    for (int w2 = 0; w2 < 4; ++w2) { wbase[w2] = acc; acc += wsum[w2]; }
  }
  __syncthreads();
  int excl = wbase[wid] + incl - s4;
  const int sbase = sbase_s;
  int o0 = excl, o1 = excl + c0, o2 = o1 + c1, o3 = o2 + c2;
  noff[j0] = o0; noff[j0 + 1] = o1; noff[j0 + 2] = o2; noff[j0 + 3] = o3;
  int g0 = b * 1024 + j0;
  if (g0 + 0 < Ntot) { ptr[g0 + 0] = sbase + o0; cnt[g0 + 0] = c0; }
  if (g0 + 1 < Ntot) { ptr[g0 + 1] = sbase + o1; cnt[g0 + 1] = c1; }
  if (g0 + 2 < Ntot) { ptr[g0 + 2] = sbase + o2; cnt[g0 + 2] = c2; }
  if (g0 + 3 < Ntot) { ptr[g0 + 3] = sbase + o3; cnt[g0 + 3] = c3; }
  __syncthreads();

  for (int i = tid; i < ecount; i += 256) {
    unsigned rec = bp[i];
    int j = rec >> 20;
    int p = sbase + atomicAdd(&noff[j], 1);
    ss[p] = (int)(rec & 0xFFFFF);
  }
}

// ---------------- fused neighbor mean (4 relations, fp8 gather) ----------------
struct AArgs {
  const unsigned char* xs[4];   // fp8 tables (x16 scale)
  unsigned short* mean[4];      // bf16 out
  int nbase[4];
  int bbase[5];  // block prefix
  int n[4];
};

__global__ __launch_bounds__(256) void k_aggregate_all(AArgs A, const int* __restrict__ ptr,
                                                       const int* __restrict__ cnt,
                                                       const int* __restrict__ ss) {
  int b = blockIdx.x;
  int r = (b >= A.bbase[1]) + (b >= A.bbase[2]) + (b >= A.bbase[3]);
  int d = (b - A.bbase[r]) * 8 + (threadIdx.x >> 5);
  if (d >= A.n[r]) return;
  const unsigned char* xs = A.xs[r];
  int l = threadIdx.x & 31;
  int g = A.nbase[r] + d;
  int p = ptr[g];
  int deg = cnt[g];
  float ax = 0.f, ay = 0.f, az = 0.f, aw = 0.f;
  for (int j0 = 0; j0 < deg; j0 += 32) {
    int m = deg - j0;
    if (m > 32) m = 32;
    int idx = ss[p + j0 + (l < m ? l : m - 1)];
    for (int j = 0; j < m; j += 8) {
      int mm = m - j;
      if (mm > 8) mm = 8;
      unsigned uu[8];
#pragma unroll
      for (int k = 0; k < 8; ++k) {
        if (k < mm) {
          int s = __shfl(idx, j + k, 32);
          uu[k] = *(const unsigned*)(xs + (size_t)s * HD + l * 4);
        }
      }
#pragma unroll
      for (int k = 0; k < 8; ++k) {
        if (k < mm) {
          f32x2 lo = __builtin_amdgcn_cvt_pk_f32_fp8(uu[k], false);
          f32x2 hi = __builtin_amdgcn_cvt_pk_f32_fp8(uu[k], true);
          ax += lo.x; ay += lo.y; az += hi.x; aw += hi.y;
        }
      }
    }
  }
  float inv = 1.0f / (16.0f * (float)(deg > 0 ? deg : 1));  // fold out x16 scale
  ushort4 o;
  o.x = f2bf(ax * inv); o.y = f2bf(ay * inv);
  o.z = f2bf(az * inv); o.w = f2bf(aw * inv);
  *(ushort4*)(A.mean[r] + (size_t)d * HD + l * 4) = o;
}

// ---------------- W preprocessing ----------------
// W (or Wa+Wb) [k][n] f32 -> transposed [n][k] bf16, k swizzled:
// idx = n*128 + (k ^ ((n&15)<<3))  -> conflict-free ds_read_b128 in GEMM.
struct PrepArgs {
  const float* a[14];
  const float* b[14];
};

__global__ __launch_bounds__(256) void k_prepw(PrepArgs pa, unsigned short* __restrict__ out) {
  int s = blockIdx.x;
  const float* A = pa.a[s];
  const float* B = pa.b[s];
  unsigned short* oh = out + (size_t)s * 16384;
  int e0 = blockIdx.y * 1024 + threadIdx.x * 4;
#pragma unroll
  for (int j = 0; j < 4; ++j) {
    int e = e0 + j;
    int k = e >> 7, n = e & 127;
    float v = A[e] + (B ? B[e] : 0.f);
    oh[n * 128 + (k ^ ((n & 15) << 3))] = f2bf(v);
  }
}

// ---------------- MFMA GEMM (bf16 x bf16, f32 acc) ----------------
__global__ __launch_bounds__(256, 2) void k_gemm_mfma(
    const unsigned short* __restrict__ x0, const unsigned short* __restrict__ x1,
    const unsigned short* __restrict__ x2,
    const unsigned short* __restrict__ w0p, const unsigned short* __restrict__ w1p,
    const unsigned short* __restrict__ w2p, int nslab,
    const float* __restrict__ b0, const float* __restrict__ b1,
    float* __restrict__ outf, unsigned short* __restrict__ outb, int M, int relu) {
  __shared__ unsigned short ldsb[16384];  // 32KB
  const int tid = threadIdx.x;
  const int wave = tid >> 6;
  const int lane = tid & 63;
  const int l31 = lane & 31;
  const int lhalf = lane >> 5;

  const int mbase = blockIdx.x * 256 + wave * 64;
  int r0 = mbase + l31;
  int r1 = mbase + 32 + l31;
  if (r0 > M - 1) r0 = M - 1;
  if (r1 > M - 1) r1 = M - 1;

  f32x16 acc[2][4];
#pragma unroll
  for (int a = 0; a < 2; ++a)
#pragma unroll
    for (int n = 0; n < 4; ++n)
#pragma unroll
      for (int q = 0; q < 16; ++q) acc[a][n][q] = 0.f;

  const unsigned short* xs[3] = {x0, x1, x2};
  const unsigned short* ws[3] = {w0p, w1p, w2p};

#pragma unroll
  for (int s = 0; s < 3; ++s) {
    if (s < nslab) {
      const unsigned short* xp = xs[s];
      __syncthreads();  // protect LDS from previous slab's readers
      {
        const float4* src = (const float4*)ws[s];
        float4* dst = (float4*)ldsb;
#pragma unroll
        for (int j = 0; j < 8; ++j) dst[tid + j * 256] = src[tid + j * 256];
      }
      __syncthreads();

#pragma unroll
      for (int ks = 0; ks < 8; ++ks) {
        const int k0 = ks * 16 + lhalf * 8;
        bf16x8 a0 = *(const bf16x8*)(xp + (size_t)r0 * HD + k0);
        bf16x8 a1 = *(const bf16x8*)(xp + (size_t)r1 * HD + k0);
#pragma unroll
        for (int nt = 0; nt < 4; ++nt) {
          const int rown = nt * 32 + l31;
          const int kidx = k0 ^ ((rown & 15) << 3);
          const bf16x8 bb = *(const bf16x8*)&ldsb[rown * HD + kidx];
          acc[0][nt] = __builtin_amdgcn_mfma_f32_32x32x16_bf16(a0, bb, acc[0][nt], 0, 0, 0);
          acc[1][nt] = __builtin_amdgcn_mfma_f32_32x32x16_bf16(a1, bb, acc[1][nt], 0, 0, 0);
        }
      }
    }
  }

#pragma unroll
  for (int nt = 0; nt < 4; ++nt) {
    const int col = nt * 32 + l31;
    float bias = b0[col] + (b1 ? b1[col] : 0.f);
#pragma unroll
    for (int as = 0; as < 2; ++as) {
#pragma unroll
      for (int rg = 0; rg < 16; ++rg) {
        int row = mbase + as * 32 + (rg & 3) + 8 * (rg >> 2) + 4 * lhalf;
        float v = acc[as][nt][rg] + bias;
        if (relu) v = fmaxf(v, 0.f);
        if (row < M) {
          if (outf) outf[(size_t)row * HD + col] = v;
          else outb[(size_t)row * HD + col] = f2bf(v);
        }
      }
    }
  }
}

extern "C" void kernel_launch(void* const* d_in, const int* in_sizes, int n_in,
                              void* d_out, int out_size, void* d_ws, size_t ws_size,
                              hipStream_t stream) {
  const float* emb_g = (const float*)d_in[0];
  const float* emb_d = (const float*)d_in[1];
  const float* emb_c = (const float*)d_in[2];
  const float* Wl = (const float*)d_in[3];   // [2,4,128,128]
  const float* bl = (const float*)d_in[4];   // [2,4,128]
  const float* Wr = (const float*)d_in[5];   // [2,4,128,128]

  const int NG = in_sizes[0] / HD;
  const int ND = in_sizes[1] / HD;
  const int NC = in_sizes[2] / HD;
  const int E0 = in_sizes[6];   // g->g
  const int E1 = in_sizes[8];   // c->d
  const int E2 = in_sizes[10];  // c->g
  const int E3 = in_sizes[12];  // g->c
  const int HH = HD * HD;
  const int Etot = E0 + E1 + E2 + E3;
  const int Ntot = NG + ND + NG + NC;
  const int NB = (Ntot + 1023) >> 10;  // 1024-node buckets

  // ---- workspace carve (all 16B-aligned by construction) ----
  char* w = (char*)d_ws;
  unsigned short* wprep = (unsigned short*)w; w += (size_t)14 * 32768;
  unsigned short* xbf_g0 = (unsigned short*)w; w += (size_t)NG * HD * 2;
  unsigned short* xbf_d0 = (unsigned short*)w; w += (size_t)ND * HD * 2;
  unsigned short* xbf_c0 = (unsigned short*)w; w += (size_t)NC * HD * 2;
  unsigned short* xbf_g1 = (unsigned short*)w; w += (size_t)NG * HD * 2;
  unsigned short* xbf_d1 = (unsigned short*)w; w += (size_t)ND * HD * 2;
  unsigned short* xbf_c1 = (unsigned short*)w; w += (size_t)NC * HD * 2;
  unsigned short* mean_gg = (unsigned short*)w; w += (size_t)NG * HD * 2;
  unsigned short* mean_cd = (unsigned short*)w; w += (size_t)ND * HD * 2;
  unsigned short* mean_cg = (unsigned short*)w; w += (size_t)NG * HD * 2;
  unsigned short* mean_gc = (unsigned short*)w; w += (size_t)NC * HD * 2;
  unsigned char* x8_g0 = (unsigned char*)w; w += (size_t)NG * HD;
  unsigned char* x8_d0 = (unsigned char*)w; w += (size_t)ND * HD;
  unsigned char* x8_c0 = (unsigned char*)w; w += (size_t)NC * HD;
  unsigned char* x8_g1 = (unsigned char*)w; w += (size_t)NG * HD;
  unsigned char* x8_d1 = (unsigned char*)w; w += (size_t)ND * HD;
  unsigned char* x8_c1 = (unsigned char*)w; w += (size_t)NC * HD;
  int* ss = (int*)w;        w += (size_t)Etot * 4;
  int* ptr = (int*)w;       w += (size_t)Ntot * 4;
  int* cnt = (int*)w;       w += (size_t)Ntot * 4;
  unsigned* binned = (unsigned*)w; w += (size_t)NB * BSTRIDE * 4;
  int* bucketCur = (int*)w; w += (size_t)NBMAX * 4;  // zeroed

  hipMemsetAsync(bucketCur, 0, (size_t)NBMAX * 4, stream);

  // bf16 + fp8 feature tables for layer 0
  {
    long long n0 = (long long)NG * HD, n1 = (long long)ND * HD, n2 = (long long)NC * HD;
    long long tot8 = (n0 + n1 + n2) / 8;
    k_convert<<<(int)((tot8 + 255) / 256), 256, 0, stream>>>(
        emb_g, emb_d, emb_c, xbf_g0, xbf_d0, xbf_c0, x8_g0, x8_d0, x8_c0, n0, n1, n2);
  }

  // CSR build over concatenated spaces (two-pass binned sort)
  GArgs ga;
  ga.esrc[0] = (const int*)d_in[6];  ga.edst[0] = (const int*)d_in[7];
  ga.esrc[1] = (const int*)d_in[8];  ga.edst[1] = (const int*)d_in[9];
  ga.esrc[2] = (const int*)d_in[10]; ga.edst[2] = (const int*)d_in[11];
  ga.esrc[3] = (const int*)d_in[12]; ga.edst[3] = (const int*)d_in[13];
  ga.ebase[0] = 0; ga.ebase[1] = E0; ga.ebase[2] = E0 + E1;
  ga.ebase[3] = E0 + E1 + E2; ga.ebase[4] = Etot;
  ga.nbase[0] = 0; ga.nbase[1] = NG; ga.nbase[2] = NG + ND; ga.nbase[3] = NG + ND + NG;

  k_binA<<<(Etot + 4095) / 4096, 256, 0, stream>>>(ga, Etot, NB, bucketCur, binned);
  k_binB<<<NB, 256, 0, stream>>>(bucketCur, binned, ptr, cnt, ss, Ntot);

  // W preprocessing: 7 slabs/layer: 0:Wl0 1:Wl2 2:Wr0+Wr2 3:Wl1 4:Wr1 5:Wl3 6:Wr3
  PrepArgs pa;
  for (int L = 0; L < 2; ++L) {
    int b = L * 7;
    pa.a[b + 0] = Wl + (size_t)(L * 4 + 0) * HH; pa.b[b + 0] = nullptr;
    pa.a[b + 1] = Wl + (size_t)(L * 4 + 2) * HH; pa.b[b + 1] = nullptr;
    pa.a[b + 2] = Wr + (size_t)(L * 4 + 0) * HH; pa.b[b + 2] = Wr + (size_t)(L * 4 + 2) * HH;
    pa.a[b + 3] = Wl + (size_t)(L * 4 + 1) * HH; pa.b[b + 3] = nullptr;
    pa.a[b + 4] = Wr + (size_t)(L * 4 + 1) * HH; pa.b[b + 4] = nullptr;
    pa.a[b + 5] = Wl + (size_t)(L * 4 + 3) * HH; pa.b[b + 5] = nullptr;
    pa.a[b + 6] = Wr + (size_t)(L * 4 + 3) * HH; pa.b[b + 6] = nullptr;
  }
  k_prepw<<<dim3(14, 16), 256, 0, stream>>>(pa, wprep);

  float* out = (float*)d_out;
  float* xg_out = out;
  float* xd_out = out + (size_t)NG * HD;
  float* xc_out = out + (size_t)(NG + ND) * HD;

  for (int L = 0; L < 2; ++L) {
    const unsigned short* xg = L ? xbf_g1 : xbf_g0;
    const unsigned short* xd = L ? xbf_d1 : xbf_d0;
    const unsigned short* xc = L ? xbf_c1 : xbf_c0;
    const unsigned char* x8g = L ? x8_g1 : x8_g0;
    const unsigned char* x8c = L ? x8_c1 : x8_c0;

    if (L == 1) {
      // hidden bf16 (contiguous g1|d1|c1) -> fp8 hidden tables
      long long n8 = ((long long)(NG + ND + NC) * HD) / 8;
      k_cvt8<<<(int)((n8 + 255) / 256), 256, 0, stream>>>(xbf_g1, x8_g1, n8);
    }

    // fused aggregates (reln order: gg(src xg), cd(src xc), cg(src xc), gc(src xg))
    AArgs aa;
    aa.xs[0] = x8g; aa.xs[1] = x8c; aa.xs[2] = x8c; aa.xs[3] = x8g;
    aa.mean[0] = mean_gg; aa.mean[1] = mean_cd; aa.mean[2] = mean_cg; aa.mean[3] = mean_gc;
    aa.nbase[0] = 0; aa.nbase[1] = NG; aa.nbase[2] = NG + ND; aa.nbase[3] = NG + ND + NG;
    aa.n[0] = NG; aa.n[1] = ND; aa.n[2] = NG; aa.n[3] = NC;
    int bb = 0;
    for (int r = 0; r < 4; ++r) { aa.bbase[r] = bb; bb += (aa.n[r] + 7) / 8; }
    aa.bbase[4] = bb;
    k_aggregate_all<<<bb, 256, 0, stream>>>(aa, ptr, cnt, ss);

    const float* bl_L = bl + (size_t)L * 4 * HD;
    const unsigned short* wp = wprep + (size_t)L * 7 * 16384;
    int relu = (L == 0) ? 1 : 0;
    float* of_g = L ? xg_out : nullptr;
    float* of_d = L ? xd_out : nullptr;
    float* of_c = L ? xc_out : nullptr;

    // genes: mean_gg@Wl0 + mean_cg@Wl2 + xg@(Wr0+Wr2) + bl0 + bl2
    k_gemm_mfma<<<(NG + 255) / 256, 256, 0, stream>>>(
        mean_gg, mean_cg, xg,
        wp + 0 * 16384, wp + 1 * 16384, wp + 2 * 16384, 3,
        bl_L + 0 * HD, bl_L + 2 * HD, of_g, xbf_g1, NG, relu);
    // disease: mean_cd@Wl1 + xd@Wr1 + bl1
    k_gemm_mfma<<<(ND + 255) / 256, 256, 0, stream>>>(
        mean_cd, xd, nullptr,
        wp + 3 * 16384, wp + 4 * 16384, nullptr, 2,
        bl_L + 1 * HD, nullptr, of_d, xbf_d1, ND, relu);
    // compound: mean_gc@Wl3 + xc@Wr3 + bl3
    k_gemm_mfma<<<(NC + 255) / 256, 256, 0, stream>>>(
        mean_gc, xc, nullptr,
        wp + 5 * 16384, wp + 6 * 16384, nullptr, 2,
        bl_L + 3 * HD, nullptr, of_c, xbf_c1, NC, relu);
  }
}

// Round 7
// 382.939 us; speedup vs baseline: 3.6300x; 1.2891x over previous
//
#include <hip/hip_runtime.h>

// HeteroGNN: 2-layer hetero SAGE (gene/disease/compound), H=128.
// R7 (no numeric changes vs R6 — bit-identical math):
//  - k_aggregate_all: 16-lane row-groups, uint2 (8B)/lane -> one gather instr
//    serves 4 edges (512B) instead of 2; vmem instruction count halves.
//  - k_gemm_all: the 3 per-layer GEMMs merged into ONE dispatch (block-prefix
//    decode) -> better CU packing, fewer launch gaps.
// Pipeline: memset, convert(f32->bf16+fp8), binA, binB, prepw,
//           L0{agg, gemm_all}, cvt8, L1{agg, gemm_all} = 10 launches.

constexpr int HD = 128;
constexpr int NBMAX = 512;     // max buckets (Ntot/1024 = 293 here)
constexpr int BSTRIDE = 32768; // per-bucket record capacity (expected max ~13K)

typedef __attribute__((ext_vector_type(8))) short bf16x8;
typedef __attribute__((ext_vector_type(16))) float f32x16;
typedef __attribute__((ext_vector_type(2))) float f32x2;

__device__ __forceinline__ unsigned short f2bf(float x) {
  unsigned u = __builtin_bit_cast(unsigned, x);
  u += 0x7FFF + ((u >> 16) & 1);  // RNE
  return (unsigned short)(u >> 16);
}
__device__ __forceinline__ float bf2f(unsigned short h) {
  return __builtin_bit_cast(float, (unsigned)h << 16);
}

// pack 8 f32 (x16 scale) -> 8 fp8 bytes (uint2)
__device__ __forceinline__ uint2 pack_fp8x8(const float* v) {
  uint2 o;
  unsigned t;
  t = (unsigned)__builtin_amdgcn_cvt_pk_fp8_f32(v[0] * 16.f, v[1] * 16.f, 0, false);
  t = (unsigned)__builtin_amdgcn_cvt_pk_fp8_f32(v[2] * 16.f, v[3] * 16.f, (int)t, true);
  o.x = t;
  t = (unsigned)__builtin_amdgcn_cvt_pk_fp8_f32(v[4] * 16.f, v[5] * 16.f, 0, false);
  t = (unsigned)__builtin_amdgcn_cvt_pk_fp8_f32(v[6] * 16.f, v[7] * 16.f, (int)t, true);
  o.y = t;
  return o;
}

// ---------------- f32 -> bf16 + fp8 table convert (3 tables, fused) ----------------
__global__ __launch_bounds__(256) void k_convert(const float* __restrict__ s0,
                                                 const float* __restrict__ s1,
                                                 const float* __restrict__ s2,
                                                 unsigned short* __restrict__ d0,
                                                 unsigned short* __restrict__ d1,
                                                 unsigned short* __restrict__ d2,
                                                 unsigned char* __restrict__ e0,
                                                 unsigned char* __restrict__ e1,
                                                 unsigned char* __restrict__ e2,
                                                 long long n0, long long n1, long long n2) {
  long long i = ((long long)blockIdx.x * 256 + threadIdx.x) * 8;
  const float* s;
  unsigned short* d;
  unsigned char* e;
  if (i < n0) { s = s0 + i; d = d0 + i; e = e0 + i; }
  else if (i < n0 + n1) { s = s1 + (i - n0); d = d1 + (i - n0); e = e1 + (i - n0); }
  else if (i < n0 + n1 + n2) { s = s2 + (i - n0 - n1); d = d2 + (i - n0 - n1); e = e2 + (i - n0 - n1); }
  else return;
  float4 a = *(const float4*)s;
  float4 b = *(const float4*)(s + 4);
  float v[8] = {a.x, a.y, a.z, a.w, b.x, b.y, b.z, b.w};
  uint4 o;
  o.x = (unsigned)f2bf(v[0]) | ((unsigned)f2bf(v[1]) << 16);
  o.y = (unsigned)f2bf(v[2]) | ((unsigned)f2bf(v[3]) << 16);
  o.z = (unsigned)f2bf(v[4]) | ((unsigned)f2bf(v[5]) << 16);
  o.w = (unsigned)f2bf(v[6]) | ((unsigned)f2bf(v[7]) << 16);
  *(uint4*)d = o;
  *(uint2*)e = pack_fp8x8(v);
}

// ---------------- bf16 -> fp8 (hidden tables, contiguous region) ----------------
__global__ __launch_bounds__(256) void k_cvt8(const unsigned short* __restrict__ in,
                                              unsigned char* __restrict__ out8, long long n8) {
  long long i = (long long)blockIdx.x * 256 + threadIdx.x;  // group of 8 elems
  if (i >= n8) return;
  uint4 u = *(const uint4*)(in + i * 8);
  float v[8];
  v[0] = bf2f((unsigned short)(u.x & 0xFFFF)); v[1] = bf2f((unsigned short)(u.x >> 16));
  v[2] = bf2f((unsigned short)(u.y & 0xFFFF)); v[3] = bf2f((unsigned short)(u.y >> 16));
  v[4] = bf2f((unsigned short)(u.z & 0xFFFF)); v[5] = bf2f((unsigned short)(u.z >> 16));
  v[6] = bf2f((unsigned short)(u.w & 0xFFFF)); v[7] = bf2f((unsigned short)(u.w >> 16));
  *(uint2*)(out8 + i * 8) = pack_fp8x8(v);
}

// ---------------- CSR build: two-pass binned sort ----------------
struct GArgs {
  const int* esrc[4];
  const int* edst[4];
  int ebase[5];  // edge prefix over concatenated edge space
  int nbase[4];  // dst-node prefix per relation (concat node space)
};

// Pass A: bin edges into 1024-node buckets; packed rec = (g&1023)<<20 | src.
__global__ __launch_bounds__(256) void k_binA(GArgs ga, int Etot, int NB,
                                              int* __restrict__ bucketCur,
                                              unsigned* __restrict__ binned) {
  __shared__ int hist[NBMAX];
  __shared__ int base[NBMAX];
  const int tid = threadIdx.x;
  for (int b = tid; b < NB; b += 256) hist[b] = 0;
  __syncthreads();
  const int e0 = blockIdx.x * 4096;
  for (int i = tid; i < 4096; i += 256) {
    int e = e0 + i;
    if (e < Etot) {
      int r = (e >= ga.ebase[1]) + (e >= ga.ebase[2]) + (e >= ga.ebase[3]);
      int g = ga.nbase[r] + ga.edst[r][e - ga.ebase[r]];
      atomicAdd(&hist[g >> 10], 1);
    }
  }
  __syncthreads();
  for (int b = tid; b < NB; b += 256) {
    int h = hist[b];
    base[b] = h ? atomicAdd(&bucketCur[b], h) : 0;
    hist[b] = 0;  // same thread owns b in both statements -> ordered
  }
  __syncthreads();
  for (int i = tid; i < 4096; i += 256) {
    int e = e0 + i;
    if (e < Etot) {
      int r = (e >= ga.ebase[1]) + (e >= ga.ebase[2]) + (e >= ga.ebase[3]);
      int el = e - ga.ebase[r];
      int g = ga.nbase[r] + ga.edst[r][el];
      int b = g >> 10;
      int pos = base[b] + atomicAdd(&hist[b], 1);
      binned[(size_t)b * BSTRIDE + pos] =
          ((unsigned)(g & 1023) << 20) | (unsigned)ga.esrc[r][el];
    }
  }
}

// Pass B: one block per bucket; per-node LDS hist + scan -> ptr/cnt; LDS-cursor
// scatter -> ss (bucket output contiguous, single-CU -> L2-friendly).
__global__ __launch_bounds__(256) void k_binB(const int* __restrict__ bucketCur,
                                              const unsigned* __restrict__ binned,
                                              int* __restrict__ ptr, int* __restrict__ cnt,
                                              int* __restrict__ ss, int Ntot) {
  const int b = blockIdx.x;
  const int tid = threadIdx.x;
  __shared__ int ncnt[1024];
  __shared__ int noff[1024];
  __shared__ int red[256];
  __shared__ int sbase_s;
  __shared__ int wsum[4], wbase[4];

  int part = 0;
  for (int i = tid; i < b; i += 256) part += bucketCur[i];
  red[tid] = part;
  __syncthreads();
  for (int s = 128; s > 0; s >>= 1) {
    if (tid < s) red[tid] += red[tid + s];
    __syncthreads();
  }
  if (tid == 0) sbase_s = red[0];

  for (int j = tid; j < 1024; j += 256) ncnt[j] = 0;
  __syncthreads();

  const int ecount = bucketCur[b];
  const unsigned* bp = binned + (size_t)b * BSTRIDE;
  for (int i = tid; i < ecount; i += 256) atomicAdd(&ncnt[bp[i] >> 20], 1);
  __syncthreads();

  const int j0 = tid * 4;
  int c0 = ncnt[j0], c1 = ncnt[j0 + 1], c2 = ncnt[j0 + 2], c3 = ncnt[j0 + 3];
  int s4 = c0 + c1 + c2 + c3;
  int lane = tid & 63, wid = tid >> 6;
  int incl = s4;
#pragma unroll
  for (int off = 1; off < 64; off <<= 1) {
    int t = __shfl_up(incl, off);
    if (lane >= off) incl += t;
  }
  if (lane == 63) wsum[wid] = incl;
  __syncthreads();
  if (tid == 0) {
    int acc = 0;
#pragma unroll
    for (int w2 = 0; w2 < 4; ++w2) { wbase[w2] = acc; acc += wsum[w2]; }
  }
  __syncthreads();
  int excl = wbase[wid] + incl - s4;
  const int sbase = sbase_s;
  int o0 = excl, o1 = excl + c0, o2 = o1 + c1, o3 = o2 + c2;
  noff[j0] = o0; noff[j0 + 1] = o1; noff[j0 + 2] = o2; noff[j0 + 3] = o3;
  int g0 = b * 1024 + j0;
  if (g0 + 0 < Ntot) { ptr[g0 + 0] = sbase + o0; cnt[g0 + 0] = c0; }
  if (g0 + 1 < Ntot) { ptr[g0 + 1] = sbase + o1; cnt[g0 + 1] = c1; }
  if (g0 + 2 < Ntot) { ptr[g0 + 2] = sbase + o2; cnt[g0 + 2] = c2; }
  if (g0 + 3 < Ntot) { ptr[g0 + 3] = sbase + o3; cnt[g0 + 3] = c3; }
  __syncthreads();

  for (int i = tid; i < ecount; i += 256) {
    unsigned rec = bp[i];
    int j = rec >> 20;
    int p = sbase + atomicAdd(&noff[j], 1);
    ss[p] = (int)(rec & 0xFFFFF);
  }
}

// ---------------- fused neighbor mean (4 relations, fp8 gather) ----------------
// 16-lane groups: lane covers 8 cols (uint2); one wave = 4 dst nodes; one
// gather instr = 4 edges x 128B. Per-element edge order identical to R6.
struct AArgs {
  const unsigned char* xs[4];   // fp8 tables (x16 scale)
  unsigned short* mean[4];      // bf16 out
  int nbase[4];
  int bbase[5];  // block prefix
  int n[4];
};

__global__ __launch_bounds__(256) void k_aggregate_all(AArgs A, const int* __restrict__ ptr,
                                                       const int* __restrict__ cnt,
                                                       const int* __restrict__ ss) {
  int b = blockIdx.x;
  int r = (b >= A.bbase[1]) + (b >= A.bbase[2]) + (b >= A.bbase[3]);
  int d = (b - A.bbase[r]) * 16 + (threadIdx.x >> 4);
  if (d >= A.n[r]) return;
  const unsigned char* xs = A.xs[r];
  int l = threadIdx.x & 15;
  int g = A.nbase[r] + d;
  int p = ptr[g];
  int deg = cnt[g];
  float a0 = 0.f, a1 = 0.f, a2 = 0.f, a3 = 0.f, a4 = 0.f, a5 = 0.f, a6 = 0.f, a7 = 0.f;
  for (int j0 = 0; j0 < deg; j0 += 16) {
    int m = deg - j0;
    if (m > 16) m = 16;
    int idx = ss[p + j0 + (l < m ? l : m - 1)];
    for (int j = 0; j < m; j += 8) {
      int mm = m - j;
      if (mm > 8) mm = 8;
      uint2 uu[8];
#pragma unroll
      for (int k = 0; k < 8; ++k) {
        if (k < mm) {
          int s = __shfl(idx, j + k, 16);
          uu[k] = *(const uint2*)(xs + (size_t)s * HD + l * 8);
        }
      }
#pragma unroll
      for (int k = 0; k < 8; ++k) {
        if (k < mm) {
          f32x2 p0 = __builtin_amdgcn_cvt_pk_f32_fp8(uu[k].x, false);
          f32x2 p1 = __builtin_amdgcn_cvt_pk_f32_fp8(uu[k].x, true);
          f32x2 p2 = __builtin_amdgcn_cvt_pk_f32_fp8(uu[k].y, false);
          f32x2 p3 = __builtin_amdgcn_cvt_pk_f32_fp8(uu[k].y, true);
          a0 += p0.x; a1 += p0.y; a2 += p1.x; a3 += p1.y;
          a4 += p2.x; a5 += p2.y; a6 += p3.x; a7 += p3.y;
        }
      }
    }
  }
  float inv = 1.0f / (16.0f * (float)(deg > 0 ? deg : 1));  // fold out x16 scale
  uint4 o;
  o.x = (unsigned)f2bf(a0 * inv) | ((unsigned)f2bf(a1 * inv) << 16);
  o.y = (unsigned)f2bf(a2 * inv) | ((unsigned)f2bf(a3 * inv) << 16);
  o.z = (unsigned)f2bf(a4 * inv) | ((unsigned)f2bf(a5 * inv) << 16);
  o.w = (unsigned)f2bf(a6 * inv) | ((unsigned)f2bf(a7 * inv) << 16);
  *(uint4*)(A.mean[r] + (size_t)d * HD + l * 8) = o;
}

// ---------------- W preprocessing ----------------
// W (or Wa+Wb) [k][n] f32 -> transposed [n][k] bf16, k swizzled:
// idx = n*128 + (k ^ ((n&15)<<3))  -> conflict-free ds_read_b128 in GEMM.
struct PrepArgs {
  const float* a[14];
  const float* b[14];
};

__global__ __launch_bounds__(256) void k_prepw(PrepArgs pa, unsigned short* __restrict__ out) {
  int s = blockIdx.x;
  const float* A = pa.a[s];
  const float* B = pa.b[s];
  unsigned short* oh = out + (size_t)s * 16384;
  int e0 = blockIdx.y * 1024 + threadIdx.x * 4;
#pragma unroll
  for (int j = 0; j < 4; ++j) {
    int e = e0 + j;
    int k = e >> 7, n = e & 127;
    float v = A[e] + (B ? B[e] : 0.f);
    oh[n * 128 + (k ^ ((n & 15) << 3))] = f2bf(v);
  }
}

// ---------------- merged MFMA GEMM (3 node types, one dispatch) ----------------
struct GemmArgs {
  const unsigned short* x[3][3];   // [type][slab]
  const unsigned short* wp[3][3];
  const float* b0[3];
  const float* b1[3];
  float* outf[3];                  // layer-1: d_out segment; layer-0: null
  unsigned short* outb[3];         // layer-0: bf16 hidden table
  int M[3];
  int nslab[3];
  int gbase[4];                    // block prefix per type
  int relu;
};

__global__ __launch_bounds__(256, 2) void k_gemm_all(GemmArgs ga) {
  __shared__ unsigned short ldsb[16384];  // 32KB
  const int t = (blockIdx.x >= ga.gbase[1]) + (blockIdx.x >= ga.gbase[2]);
  const int blk = blockIdx.x - ga.gbase[t];
  const int M = ga.M[t];
  const int nslab = ga.nslab[t];
  const int tid = threadIdx.x;
  const int wave = tid >> 6;
  const int lane = tid & 63;
  const int l31 = lane & 31;
  const int lhalf = lane >> 5;

  const int mbase = blk * 256 + wave * 64;
  int r0 = mbase + l31;
  int r1 = mbase + 32 + l31;
  if (r0 > M - 1) r0 = M - 1;
  if (r1 > M - 1) r1 = M - 1;

  f32x16 acc[2][4];
#pragma unroll
  for (int a = 0; a < 2; ++a)
#pragma unroll
    for (int n = 0; n < 4; ++n)
#pragma unroll
      for (int q = 0; q < 16; ++q) acc[a][n][q] = 0.f;

#pragma unroll
  for (int s = 0; s < 3; ++s) {
    if (s < nslab) {
      const unsigned short* xp = ga.x[t][s];
      __syncthreads();  // protect LDS from previous slab's readers
      {
        const float4* src = (const float4*)ga.wp[t][s];
        float4* dst = (float4*)ldsb;
#pragma unroll
        for (int j = 0; j < 8; ++j) dst[tid + j * 256] = src[tid + j * 256];
      }
      __syncthreads();

#pragma unroll
      for (int ks = 0; ks < 8; ++ks) {
        const int k0 = ks * 16 + lhalf * 8;
        bf16x8 a0 = *(const bf16x8*)(xp + (size_t)r0 * HD + k0);
        bf16x8 a1 = *(const bf16x8*)(xp + (size_t)r1 * HD + k0);
#pragma unroll
        for (int nt = 0; nt < 4; ++nt) {
          const int rown = nt * 32 + l31;
          const int kidx = k0 ^ ((rown & 15) << 3);
          const bf16x8 bb = *(const bf16x8*)&ldsb[rown * HD + kidx];
          acc[0][nt] = __builtin_amdgcn_mfma_f32_32x32x16_bf16(a0, bb, acc[0][nt], 0, 0, 0);
          acc[1][nt] = __builtin_amdgcn_mfma_f32_32x32x16_bf16(a1, bb, acc[1][nt], 0, 0, 0);
        }
      }
    }
  }

  const float* b0 = ga.b0[t];
  const float* b1 = ga.b1[t];
  float* outf = ga.outf[t];
  unsigned short* outb = ga.outb[t];
#pragma unroll
  for (int nt = 0; nt < 4; ++nt) {
    const int col = nt * 32 + l31;
    float bias = b0[col] + (b1 ? b1[col] : 0.f);
#pragma unroll
    for (int as = 0; as < 2; ++as) {
#pragma unroll
      for (int rg = 0; rg < 16; ++rg) {
        int row = mbase + as * 32 + (rg & 3) + 8 * (rg >> 2) + 4 * lhalf;
        float v = acc[as][nt][rg] + bias;
        if (ga.relu) v = fmaxf(v, 0.f);
        if (row < M) {
          if (outf) outf[(size_t)row * HD + col] = v;
          else outb[(size_t)row * HD + col] = f2bf(v);
        }
      }
    }
  }
}

extern "C" void kernel_launch(void* const* d_in, const int* in_sizes, int n_in,
                              void* d_out, int out_size, void* d_ws, size_t ws_size,
                              hipStream_t stream) {
  const float* emb_g = (const float*)d_in[0];
  const float* emb_d = (const float*)d_in[1];
  const float* emb_c = (const float*)d_in[2];
  const float* Wl = (const float*)d_in[3];   // [2,4,128,128]
  const float* bl = (const float*)d_in[4];   // [2,4,128]
  const float* Wr = (const float*)d_in[5];   // [2,4,128,128]

  const int NG = in_sizes[0] / HD;
  const int ND = in_sizes[1] / HD;
  const int NC = in_sizes[2] / HD;
  const int E0 = in_sizes[6];   // g->g
  const int E1 = in_sizes[8];   // c->d
  const int E2 = in_sizes[10];  // c->g
  const int E3 = in_sizes[12];  // g->c
  const int HH = HD * HD;
  const int Etot = E0 + E1 + E2 + E3;
  const int Ntot = NG + ND + NG + NC;
  const int NB = (Ntot + 1023) >> 10;  // 1024-node buckets

  // ---- workspace carve (all 16B-aligned by construction) ----
  char* w = (char*)d_ws;
  unsigned short* wprep = (unsigned short*)w; w += (size_t)14 * 32768;
  unsigned short* xbf_g0 = (unsigned short*)w; w += (size_t)NG * HD * 2;
  unsigned short* xbf_d0 = (unsigned short*)w; w += (size_t)ND * HD * 2;
  unsigned short* xbf_c0 = (unsigned short*)w; w += (size_t)NC * HD * 2;
  unsigned short* xbf_g1 = (unsigned short*)w; w += (size_t)NG * HD * 2;
  unsigned short* xbf_d1 = (unsigned short*)w; w += (size_t)ND * HD * 2;
  unsigned short* xbf_c1 = (unsigned short*)w; w += (size_t)NC * HD * 2;
  unsigned short* mean_gg = (unsigned short*)w; w += (size_t)NG * HD * 2;
  unsigned short* mean_cd = (unsigned short*)w; w += (size_t)ND * HD * 2;
  unsigned short* mean_cg = (unsigned short*)w; w += (size_t)NG * HD * 2;
  unsigned short* mean_gc = (unsigned short*)w; w += (size_t)NC * HD * 2;
  unsigned char* x8_g0 = (unsigned char*)w; w += (size_t)NG * HD;
  unsigned char* x8_d0 = (unsigned char*)w; w += (size_t)ND * HD;
  unsigned char* x8_c0 = (unsigned char*)w; w += (size_t)NC * HD;
  unsigned char* x8_g1 = (unsigned char*)w; w += (size_t)NG * HD;
  unsigned char* x8_d1 = (unsigned char*)w; w += (size_t)ND * HD;
  unsigned char* x8_c1 = (unsigned char*)w; w += (size_t)NC * HD;
  int* ss = (int*)w;        w += (size_t)Etot * 4;
  int* ptr = (int*)w;       w += (size_t)Ntot * 4;
  int* cnt = (int*)w;       w += (size_t)Ntot * 4;
  unsigned* binned = (unsigned*)w; w += (size_t)NB * BSTRIDE * 4;
  int* bucketCur = (int*)w; w += (size_t)NBMAX * 4;  // zeroed

  hipMemsetAsync(bucketCur, 0, (size_t)NBMAX * 4, stream);

  // bf16 + fp8 feature tables for layer 0
  {
    long long n0 = (long long)NG * HD, n1 = (long long)ND * HD, n2 = (long long)NC * HD;
    long long tot8 = (n0 + n1 + n2) / 8;
    k_convert<<<(int)((tot8 + 255) / 256), 256, 0, stream>>>(
        emb_g, emb_d, emb_c, xbf_g0, xbf_d0, xbf_c0, x8_g0, x8_d0, x8_c0, n0, n1, n2);
  }

  // CSR build over concatenated spaces (two-pass binned sort)
  GArgs ga;
  ga.esrc[0] = (const int*)d_in[6];  ga.edst[0] = (const int*)d_in[7];
  ga.esrc[1] = (const int*)d_in[8];  ga.edst[1] = (const int*)d_in[9];
  ga.esrc[2] = (const int*)d_in[10]; ga.edst[2] = (const int*)d_in[11];
  ga.esrc[3] = (const int*)d_in[12]; ga.edst[3] = (const int*)d_in[13];
  ga.ebase[0] = 0; ga.ebase[1] = E0; ga.ebase[2] = E0 + E1;
  ga.ebase[3] = E0 + E1 + E2; ga.ebase[4] = Etot;
  ga.nbase[0] = 0; ga.nbase[1] = NG; ga.nbase[2] = NG + ND; ga.nbase[3] = NG + ND + NG;

  k_binA<<<(Etot + 4095) / 4096, 256, 0, stream>>>(ga, Etot, NB, bucketCur, binned);
  k_binB<<<NB, 256, 0, stream>>>(bucketCur, binned, ptr, cnt, ss, Ntot);

  // W preprocessing: 7 slabs/layer: 0:Wl0 1:Wl2 2:Wr0+Wr2 3:Wl1 4:Wr1 5:Wl3 6:Wr3
  PrepArgs pa;
  for (int L = 0; L < 2; ++L) {
    int b = L * 7;
    pa.a[b + 0] = Wl + (size_t)(L * 4 + 0) * HH; pa.b[b + 0] = nullptr;
    pa.a[b + 1] = Wl + (size_t)(L * 4 + 2) * HH; pa.b[b + 1] = nullptr;
    pa.a[b + 2] = Wr + (size_t)(L * 4 + 0) * HH; pa.b[b + 2] = Wr + (size_t)(L * 4 + 2) * HH;
    pa.a[b + 3] = Wl + (size_t)(L * 4 + 1) * HH; pa.b[b + 3] = nullptr;
    pa.a[b + 4] = Wr + (size_t)(L * 4 + 1) * HH; pa.b[b + 4] = nullptr;
    pa.a[b + 5] = Wl + (size_t)(L * 4 + 3) * HH; pa.b[b + 5] = nullptr;
    pa.a[b + 6] = Wr + (size_t)(L * 4 + 3) * HH; pa.b[b + 6] = nullptr;
  }
  k_prepw<<<dim3(14, 16), 256, 0, stream>>>(pa, wprep);

  float* out = (float*)d_out;
  float* xg_out = out;
  float* xd_out = out + (size_t)NG * HD;
  float* xc_out = out + (size_t)(NG + ND) * HD;

  for (int L = 0; L < 2; ++L) {
    const unsigned short* xg = L ? xbf_g1 : xbf_g0;
    const unsigned short* xd = L ? xbf_d1 : xbf_d0;
    const unsigned short* xc = L ? xbf_c1 : xbf_c0;
    const unsigned char* x8g = L ? x8_g1 : x8_g0;
    const unsigned char* x8c = L ? x8_c1 : x8_c0;

    if (L == 1) {
      // hidden bf16 (contiguous g1|d1|c1) -> fp8 hidden tables
      long long n8 = ((long long)(NG + ND + NC) * HD) / 8;
      k_cvt8<<<(int)((n8 + 255) / 256), 256, 0, stream>>>(xbf_g1, x8_g1, n8);
    }

    // fused aggregates (reln order: gg(src xg), cd(src xc), cg(src xc), gc(src xg))
    AArgs aa;
    aa.xs[0] = x8g; aa.xs[1] = x8c; aa.xs[2] = x8c; aa.xs[3] = x8g;
    aa.mean[0] = mean_gg; aa.mean[1] = mean_cd; aa.mean[2] = mean_cg; aa.mean[3] = mean_gc;
    aa.nbase[0] = 0; aa.nbase[1] = NG; aa.nbase[2] = NG + ND; aa.nbase[3] = NG + ND + NG;
    aa.n[0] = NG; aa.n[1] = ND; aa.n[2] = NG; aa.n[3] = NC;
    int bb = 0;
    for (int r = 0; r < 4; ++r) { aa.bbase[r] = bb; bb += (aa.n[r] + 15) / 16; }
    aa.bbase[4] = bb;
    k_aggregate_all<<<bb, 256, 0, stream>>>(aa, ptr, cnt, ss);

    const float* bl_L = bl + (size_t)L * 4 * HD;
    const unsigned short* wp = wprep + (size_t)L * 7 * 16384;

    GemmArgs gm;
    // genes: mean_gg@Wl0 + mean_cg@Wl2 + xg@(Wr0+Wr2) + bl0 + bl2
    gm.x[0][0] = mean_gg; gm.x[0][1] = mean_cg; gm.x[0][2] = xg;
    gm.wp[0][0] = wp + 0 * 16384; gm.wp[0][1] = wp + 1 * 16384; gm.wp[0][2] = wp + 2 * 16384;
    gm.b0[0] = bl_L + 0 * HD; gm.b1[0] = bl_L + 2 * HD;
    gm.M[0] = NG; gm.nslab[0] = 3;
    // disease: mean_cd@Wl1 + xd@Wr1 + bl1
    gm.x[1][0] = mean_cd; gm.x[1][1] = xd; gm.x[1][2] = nullptr;
    gm.wp[1][0] = wp + 3 * 16384; gm.wp[1][1] = wp + 4 * 16384; gm.wp[1][2] = nullptr;
    gm.b0[1] = bl_L + 1 * HD; gm.b1[1] = nullptr;
    gm.M[1] = ND; gm.nslab[1] = 2;
    // compound: mean_gc@Wl3 + xc@Wr3 + bl3
    gm.x[2][0] = mean_gc; gm.x[2][1] = xc; gm.x[2][2] = nullptr;
    gm.wp[2][0] = wp + 5 * 16384; gm.wp[2][1] = wp + 6 * 16384; gm.wp[2][2] = nullptr;
    gm.b0[2] = bl_L + 3 * HD; gm.b1[2] = nullptr;
    gm.M[2] = NC; gm.nslab[2] = 2;
    if (L) {
      gm.outf[0] = xg_out; gm.outf[1] = xd_out; gm.outf[2] = xc_out;
      gm.outb[0] = gm.outb[1] = gm.outb[2] = nullptr;
    } else {
      gm.outf[0] = gm.outf[1] = gm.outf[2] = nullptr;
      gm.outb[0] = xbf_g1; gm.outb[1] = xbf_d1; gm.outb[2] = xbf_c1;
    }
    gm.relu = (L == 0) ? 1 : 0;
    int gb = 0;
    for (int t = 0; t < 3; ++t) { gm.gbase[t] = gb; gb += (gm.M[t] + 255) / 256; }
    gm.gbase[3] = gb;
    k_gemm_all<<<gb, 256, 0, stream>>>(gm);
  }
}

// Round 8
// 373.992 us; speedup vs baseline: 3.7168x; 1.0239x over previous
//
#include <hip/hip_runtime.h>

// HeteroGNN: 2-layer hetero SAGE (gene/disease/compound), H=128.
// R8 (bit-identical math vs R7):
//  - k_gemm_all: M-tile 256 -> 128, wave owns 32 rows (acc[4]) -> 2x blocks
//    (1564/layer, ~4 resident blocks/CU) for latency hiding; same k-order.
//  - k_cvt8 fused into L0 GEMM epilogue: fp8 computed from the bf16-ROUNDED
//    value (bit-identical to the old separate pass); disease type skips fp8
//    (no relation gathers from disease).
// Pipeline: memset, convert, binA, binB, prepw, L0{agg, gemm}, L1{agg, gemm}
// = 9 launches.

constexpr int HD = 128;
constexpr int NBMAX = 512;     // max buckets (Ntot/1024 = 293 here)
constexpr int BSTRIDE = 32768; // per-bucket record capacity (expected max ~13K)

typedef __attribute__((ext_vector_type(8))) short bf16x8;
typedef __attribute__((ext_vector_type(16))) float f32x16;
typedef __attribute__((ext_vector_type(2))) float f32x2;

__device__ __forceinline__ unsigned short f2bf(float x) {
  unsigned u = __builtin_bit_cast(unsigned, x);
  u += 0x7FFF + ((u >> 16) & 1);  // RNE
  return (unsigned short)(u >> 16);
}
__device__ __forceinline__ float bf2f(unsigned short h) {
  return __builtin_bit_cast(float, (unsigned)h << 16);
}

// pack 8 f32 (x16 scale) -> 8 fp8 bytes (uint2)
__device__ __forceinline__ uint2 pack_fp8x8(const float* v) {
  uint2 o;
  unsigned t;
  t = (unsigned)__builtin_amdgcn_cvt_pk_fp8_f32(v[0] * 16.f, v[1] * 16.f, 0, false);
  t = (unsigned)__builtin_amdgcn_cvt_pk_fp8_f32(v[2] * 16.f, v[3] * 16.f, (int)t, true);
  o.x = t;
  t = (unsigned)__builtin_amdgcn_cvt_pk_fp8_f32(v[4] * 16.f, v[5] * 16.f, 0, false);
  t = (unsigned)__builtin_amdgcn_cvt_pk_fp8_f32(v[6] * 16.f, v[7] * 16.f, (int)t, true);
  o.y = t;
  return o;
}

// ---------------- f32 -> bf16 + fp8 table convert (3 tables, fused) ----------------
__global__ __launch_bounds__(256) void k_convert(const float* __restrict__ s0,
                                                 const float* __restrict__ s1,
                                                 const float* __restrict__ s2,
                                                 unsigned short* __restrict__ d0,
                                                 unsigned short* __restrict__ d1,
                                                 unsigned short* __restrict__ d2,
                                                 unsigned char* __restrict__ e0,
                                                 unsigned char* __restrict__ e1,
                                                 unsigned char* __restrict__ e2,
                                                 long long n0, long long n1, long long n2) {
  long long i = ((long long)blockIdx.x * 256 + threadIdx.x) * 8;
  const float* s;
  unsigned short* d;
  unsigned char* e;
  if (i < n0) { s = s0 + i; d = d0 + i; e = e0 + i; }
  else if (i < n0 + n1) { s = s1 + (i - n0); d = d1 + (i - n0); e = e1 + (i - n0); }
  else if (i < n0 + n1 + n2) { s = s2 + (i - n0 - n1); d = d2 + (i - n0 - n1); e = e2 + (i - n0 - n1); }
  else return;
  float4 a = *(const float4*)s;
  float4 b = *(const float4*)(s + 4);
  float v[8] = {a.x, a.y, a.z, a.w, b.x, b.y, b.z, b.w};
  uint4 o;
  o.x = (unsigned)f2bf(v[0]) | ((unsigned)f2bf(v[1]) << 16);
  o.y = (unsigned)f2bf(v[2]) | ((unsigned)f2bf(v[3]) << 16);
  o.z = (unsigned)f2bf(v[4]) | ((unsigned)f2bf(v[5]) << 16);
  o.w = (unsigned)f2bf(v[6]) | ((unsigned)f2bf(v[7]) << 16);
  *(uint4*)d = o;
  *(uint2*)e = pack_fp8x8(v);
}

// ---------------- CSR build: two-pass binned sort ----------------
struct GArgs {
  const int* esrc[4];
  const int* edst[4];
  int ebase[5];  // edge prefix over concatenated edge space
  int nbase[4];  // dst-node prefix per relation (concat node space)
};

// Pass A: bin edges into 1024-node buckets; packed rec = (g&1023)<<20 | src.
__global__ __launch_bounds__(256) void k_binA(GArgs ga, int Etot, int NB,
                                              int* __restrict__ bucketCur,
                                              unsigned* __restrict__ binned) {
  __shared__ int hist[NBMAX];
  __shared__ int base[NBMAX];
  const int tid = threadIdx.x;
  for (int b = tid; b < NB; b += 256) hist[b] = 0;
  __syncthreads();
  const int e0 = blockIdx.x * 4096;
  for (int i = tid; i < 4096; i += 256) {
    int e = e0 + i;
    if (e < Etot) {
      int r = (e >= ga.ebase[1]) + (e >= ga.ebase[2]) + (e >= ga.ebase[3]);
      int g = ga.nbase[r] + ga.edst[r][e - ga.ebase[r]];
      atomicAdd(&hist[g >> 10], 1);
    }
  }
  __syncthreads();
  for (int b = tid; b < NB; b += 256) {
    int h = hist[b];
    base[b] = h ? atomicAdd(&bucketCur[b], h) : 0;
    hist[b] = 0;  // same thread owns b in both statements -> ordered
  }
  __syncthreads();
  for (int i = tid; i < 4096; i += 256) {
    int e = e0 + i;
    if (e < Etot) {
      int r = (e >= ga.ebase[1]) + (e >= ga.ebase[2]) + (e >= ga.ebase[3]);
      int el = e - ga.ebase[r];
      int g = ga.nbase[r] + ga.edst[r][el];
      int b = g >> 10;
      int pos = base[b] + atomicAdd(&hist[b], 1);
      binned[(size_t)b * BSTRIDE + pos] =
          ((unsigned)(g & 1023) << 20) | (unsigned)ga.esrc[r][el];
    }
  }
}

// Pass B: one block per bucket; per-node LDS hist + scan -> ptr/cnt; LDS-cursor
// scatter -> ss (bucket output contiguous, single-CU -> L2-friendly).
__global__ __launch_bounds__(256) void k_binB(const int* __restrict__ bucketCur,
                                              const unsigned* __restrict__ binned,
                                              int* __restrict__ ptr, int* __restrict__ cnt,
                                              int* __restrict__ ss, int Ntot) {
  const int b = blockIdx.x;
  const int tid = threadIdx.x;
  __shared__ int ncnt[1024];
  __shared__ int noff[1024];
  __shared__ int red[256];
  __shared__ int sbase_s;
  __shared__ int wsum[4], wbase[4];

  int part = 0;
  for (int i = tid; i < b; i += 256) part += bucketCur[i];
  red[tid] = part;
  __syncthreads();
  for (int s = 128; s > 0; s >>= 1) {
    if (tid < s) red[tid] += red[tid + s];
    __syncthreads();
  }
  if (tid == 0) sbase_s = red[0];

  for (int j = tid; j < 1024; j += 256) ncnt[j] = 0;
  __syncthreads();

  const int ecount = bucketCur[b];
  const unsigned* bp = binned + (size_t)b * BSTRIDE;
  for (int i = tid; i < ecount; i += 256) atomicAdd(&ncnt[bp[i] >> 20], 1);
  __syncthreads();

  const int j0 = tid * 4;
  int c0 = ncnt[j0], c1 = ncnt[j0 + 1], c2 = ncnt[j0 + 2], c3 = ncnt[j0 + 3];
  int s4 = c0 + c1 + c2 + c3;
  int lane = tid & 63, wid = tid >> 6;
  int incl = s4;
#pragma unroll
  for (int off = 1; off < 64; off <<= 1) {
    int t = __shfl_up(incl, off);
    if (lane >= off) incl += t;
  }
  if (lane == 63) wsum[wid] = incl;
  __syncthreads();
  if (tid == 0) {
    int acc = 0;
#pragma unroll
    for (int w2 = 0; w2 < 4; ++w2) { wbase[w2] = acc; acc += wsum[w2]; }
  }
  __syncthreads();
  int excl = wbase[wid] + incl - s4;
  const int sbase = sbase_s;
  int o0 = excl, o1 = excl + c0, o2 = o1 + c1, o3 = o2 + c2;
  noff[j0] = o0; noff[j0 + 1] = o1; noff[j0 + 2] = o2; noff[j0 + 3] = o3;
  int g0 = b * 1024 + j0;
  if (g0 + 0 < Ntot) { ptr[g0 + 0] = sbase + o0; cnt[g0 + 0] = c0; }
  if (g0 + 1 < Ntot) { ptr[g0 + 1] = sbase + o1; cnt[g0 + 1] = c1; }
  if (g0 + 2 < Ntot) { ptr[g0 + 2] = sbase + o2; cnt[g0 + 2] = c2; }
  if (g0 + 3 < Ntot) { ptr[g0 + 3] = sbase + o3; cnt[g0 + 3] = c3; }
  __syncthreads();

  for (int i = tid; i < ecount; i += 256) {
    unsigned rec = bp[i];
    int j = rec >> 20;
    int p = sbase + atomicAdd(&noff[j], 1);
    ss[p] = (int)(rec & 0xFFFFF);
  }
}

// ---------------- fused neighbor mean (4 relations, fp8 gather) ----------------
// 16-lane groups: lane covers 8 cols (uint2); one wave = 4 dst nodes; one
// gather instr = 4 edges x 128B.
struct AArgs {
  const unsigned char* xs[4];   // fp8 tables (x16 scale)
  unsigned short* mean[4];      // bf16 out
  int nbase[4];
  int bbase[5];  // block prefix
  int n[4];
};

__global__ __launch_bounds__(256) void k_aggregate_all(AArgs A, const int* __restrict__ ptr,
                                                       const int* __restrict__ cnt,
                                                       const int* __restrict__ ss) {
  int b = blockIdx.x;
  int r = (b >= A.bbase[1]) + (b >= A.bbase[2]) + (b >= A.bbase[3]);
  int d = (b - A.bbase[r]) * 16 + (threadIdx.x >> 4);
  if (d >= A.n[r]) return;
  const unsigned char* xs = A.xs[r];
  int l = threadIdx.x & 15;
  int g = A.nbase[r] + d;
  int p = ptr[g];
  int deg = cnt[g];
  float a0 = 0.f, a1 = 0.f, a2 = 0.f, a3 = 0.f, a4 = 0.f, a5 = 0.f, a6 = 0.f, a7 = 0.f;
  for (int j0 = 0; j0 < deg; j0 += 16) {
    int m = deg - j0;
    if (m > 16) m = 16;
    int idx = ss[p + j0 + (l < m ? l : m - 1)];
    for (int j = 0; j < m; j += 8) {
      int mm = m - j;
      if (mm > 8) mm = 8;
      uint2 uu[8];
#pragma unroll
      for (int k = 0; k < 8; ++k) {
        if (k < mm) {
          int s = __shfl(idx, j + k, 16);
          uu[k] = *(const uint2*)(xs + (size_t)s * HD + l * 8);
        }
      }
#pragma unroll
      for (int k = 0; k < 8; ++k) {
        if (k < mm) {
          f32x2 p0 = __builtin_amdgcn_cvt_pk_f32_fp8(uu[k].x, false);
          f32x2 p1 = __builtin_amdgcn_cvt_pk_f32_fp8(uu[k].x, true);
          f32x2 p2 = __builtin_amdgcn_cvt_pk_f32_fp8(uu[k].y, false);
          f32x2 p3 = __builtin_amdgcn_cvt_pk_f32_fp8(uu[k].y, true);
          a0 += p0.x; a1 += p0.y; a2 += p1.x; a3 += p1.y;
          a4 += p2.x; a5 += p2.y; a6 += p3.x; a7 += p3.y;
        }
      }
    }
  }
  float inv = 1.0f / (16.0f * (float)(deg > 0 ? deg : 1));  // fold out x16 scale
  uint4 o;
  o.x = (unsigned)f2bf(a0 * inv) | ((unsigned)f2bf(a1 * inv) << 16);
  o.y = (unsigned)f2bf(a2 * inv) | ((unsigned)f2bf(a3 * inv) << 16);
  o.z = (unsigned)f2bf(a4 * inv) | ((unsigned)f2bf(a5 * inv) << 16);
  o.w = (unsigned)f2bf(a6 * inv) | ((unsigned)f2bf(a7 * inv) << 16);
  *(uint4*)(A.mean[r] + (size_t)d * HD + l * 8) = o;
}

// ---------------- W preprocessing ----------------
// W (or Wa+Wb) [k][n] f32 -> transposed [n][k] bf16, k swizzled:
// idx = n*128 + (k ^ ((n&15)<<3))  -> conflict-free ds_read_b128 in GEMM.
struct PrepArgs {
  const float* a[14];
  const float* b[14];
};

__global__ __launch_bounds__(256) void k_prepw(PrepArgs pa, unsigned short* __restrict__ out) {
  int s = blockIdx.x;
  const float* A = pa.a[s];
  const float* B = pa.b[s];
  unsigned short* oh = out + (size_t)s * 16384;
  int e0 = blockIdx.y * 1024 + threadIdx.x * 4;
#pragma unroll
  for (int j = 0; j < 4; ++j) {
    int e = e0 + j;
    int k = e >> 7, n = e & 127;
    float v = A[e] + (B ? B[e] : 0.f);
    oh[n * 128 + (k ^ ((n & 15) << 3))] = f2bf(v);
  }
}

// ---------------- merged MFMA GEMM (3 node types, one dispatch) ----------------
// M-tile 128, 4 waves, wave owns 32 rows (acc[4]). L0 epilogue also emits the
// fp8 gather table from the bf16-ROUNDED value (bit-identical to old k_cvt8).
struct GemmArgs {
  const unsigned short* x[3][3];   // [type][slab]
  const unsigned short* wp[3][3];
  const float* b0[3];
  const float* b1[3];
  float* outf[3];                  // layer-1: d_out segment; layer-0: null
  unsigned short* outb[3];         // layer-0: bf16 hidden table
  unsigned char* out8[3];          // layer-0: fp8 hidden table (null = skip)
  int M[3];
  int nslab[3];
  int gbase[4];                    // block prefix per type
  int relu;
};

__global__ __launch_bounds__(256, 4) void k_gemm_all(GemmArgs ga) {
  __shared__ unsigned short ldsb[16384];  // 32KB
  const int t = (blockIdx.x >= ga.gbase[1]) + (blockIdx.x >= ga.gbase[2]);
  const int blk = blockIdx.x - ga.gbase[t];
  const int M = ga.M[t];
  const int nslab = ga.nslab[t];
  const int tid = threadIdx.x;
  const int wave = tid >> 6;
  const int lane = tid & 63;
  const int l31 = lane & 31;
  const int lhalf = lane >> 5;

  const int mbase = blk * 128 + wave * 32;
  int r0 = mbase + l31;
  if (r0 > M - 1) r0 = M - 1;

  f32x16 acc[4];
#pragma unroll
  for (int n = 0; n < 4; ++n)
#pragma unroll
    for (int q = 0; q < 16; ++q) acc[n][q] = 0.f;

#pragma unroll
  for (int s = 0; s < 3; ++s) {
    if (s < nslab) {
      const unsigned short* xp = ga.x[t][s];
      __syncthreads();  // protect LDS from previous slab's readers
      {
        const float4* src = (const float4*)ga.wp[t][s];
        float4* dst = (float4*)ldsb;
#pragma unroll
        for (int j = 0; j < 8; ++j) dst[tid + j * 256] = src[tid + j * 256];
      }
      __syncthreads();

#pragma unroll
      for (int ks = 0; ks < 8; ++ks) {
        const int k0 = ks * 16 + lhalf * 8;
        bf16x8 a0 = *(const bf16x8*)(xp + (size_t)r0 * HD + k0);
#pragma unroll
        for (int nt = 0; nt < 4; ++nt) {
          const int rown = nt * 32 + l31;
          const int kidx = k0 ^ ((rown & 15) << 3);
          const bf16x8 bb = *(const bf16x8*)&ldsb[rown * HD + kidx];
          acc[nt] = __builtin_amdgcn_mfma_f32_32x32x16_bf16(a0, bb, acc[nt], 0, 0, 0);
        }
      }
    }
  }

  const float* b0 = ga.b0[t];
  const float* b1 = ga.b1[t];
  float* outf = ga.outf[t];
  unsigned short* outb = ga.outb[t];
  unsigned char* out8 = ga.out8[t];
#pragma unroll
  for (int nt = 0; nt < 4; ++nt) {
    const int col = nt * 32 + l31;
    float bias = b0[col] + (b1 ? b1[col] : 0.f);
#pragma unroll
    for (int rg = 0; rg < 16; ++rg) {
      int row = mbase + (rg & 3) + 8 * (rg >> 2) + 4 * lhalf;
      float v = acc[nt][rg] + bias;
      if (ga.relu) v = fmaxf(v, 0.f);
      if (row < M) {
        if (outf) {
          outf[(size_t)row * HD + col] = v;
        } else {
          unsigned short h = f2bf(v);
          outb[(size_t)row * HD + col] = h;
          if (out8) {
            float vb = bf2f(h);  // bf16-rounded value -> identical to old k_cvt8
            unsigned pk = (unsigned)__builtin_amdgcn_cvt_pk_fp8_f32(vb * 16.f, vb * 16.f, 0, false);
            out8[(size_t)row * HD + col] = (unsigned char)(pk & 0xFF);
          }
        }
      }
    }
  }
}

extern "C" void kernel_launch(void* const* d_in, const int* in_sizes, int n_in,
                              void* d_out, int out_size, void* d_ws, size_t ws_size,
                              hipStream_t stream) {
  const float* emb_g = (const float*)d_in[0];
  const float* emb_d = (const float*)d_in[1];
  const float* emb_c = (const float*)d_in[2];
  const float* Wl = (const float*)d_in[3];   // [2,4,128,128]
  const float* bl = (const float*)d_in[4];   // [2,4,128]
  const float* Wr = (const float*)d_in[5];   // [2,4,128,128]

  const int NG = in_sizes[0] / HD;
  const int ND = in_sizes[1] / HD;
  const int NC = in_sizes[2] / HD;
  const int E0 = in_sizes[6];   // g->g
  const int E1 = in_sizes[8];   // c->d
  const int E2 = in_sizes[10];  // c->g
  const int E3 = in_sizes[12];  // g->c
  const int HH = HD * HD;
  const int Etot = E0 + E1 + E2 + E3;
  const int Ntot = NG + ND + NG + NC;
  const int NB = (Ntot + 1023) >> 10;  // 1024-node buckets

  // ---- workspace carve (all 16B-aligned by construction) ----
  char* w = (char*)d_ws;
  unsigned short* wprep = (unsigned short*)w; w += (size_t)14 * 32768;
  unsigned short* xbf_g0 = (unsigned short*)w; w += (size_t)NG * HD * 2;
  unsigned short* xbf_d0 = (unsigned short*)w; w += (size_t)ND * HD * 2;
  unsigned short* xbf_c0 = (unsigned short*)w; w += (size_t)NC * HD * 2;
  unsigned short* xbf_g1 = (unsigned short*)w; w += (size_t)NG * HD * 2;
  unsigned short* xbf_d1 = (unsigned short*)w; w += (size_t)ND * HD * 2;
  unsigned short* xbf_c1 = (unsigned short*)w; w += (size_t)NC * HD * 2;
  unsigned short* mean_gg = (unsigned short*)w; w += (size_t)NG * HD * 2;
  unsigned short* mean_cd = (unsigned short*)w; w += (size_t)ND * HD * 2;
  unsigned short* mean_cg = (unsigned short*)w; w += (size_t)NG * HD * 2;
  unsigned short* mean_gc = (unsigned short*)w; w += (size_t)NC * HD * 2;
  unsigned char* x8_g0 = (unsigned char*)w; w += (size_t)NG * HD;
  unsigned char* x8_d0 = (unsigned char*)w; w += (size_t)ND * HD;
  unsigned char* x8_c0 = (unsigned char*)w; w += (size_t)NC * HD;
  unsigned char* x8_g1 = (unsigned char*)w; w += (size_t)NG * HD;
  unsigned char* x8_c1 = (unsigned char*)w; w += (size_t)NC * HD;
  int* ss = (int*)w;        w += (size_t)Etot * 4;
  int* ptr = (int*)w;       w += (size_t)Ntot * 4;
  int* cnt = (int*)w;       w += (size_t)Ntot * 4;
  unsigned* binned = (unsigned*)w; w += (size_t)NB * BSTRIDE * 4;
  int* bucketCur = (int*)w; w += (size_t)NBMAX * 4;  // zeroed

  hipMemsetAsync(bucketCur, 0, (size_t)NBMAX * 4, stream);

  // bf16 + fp8 feature tables for layer 0
  {
    long long n0 = (long long)NG * HD, n1 = (long long)ND * HD, n2 = (long long)NC * HD;
    long long tot8 = (n0 + n1 + n2) / 8;
    k_convert<<<(int)((tot8 + 255) / 256), 256, 0, stream>>>(
        emb_g, emb_d, emb_c, xbf_g0, xbf_d0, xbf_c0, x8_g0, x8_d0, x8_c0, n0, n1, n2);
  }

  // CSR build over concatenated spaces (two-pass binned sort)
  GArgs ga;
  ga.esrc[0] = (const int*)d_in[6];  ga.edst[0] = (const int*)d_in[7];
  ga.esrc[1] = (const int*)d_in[8];  ga.edst[1] = (const int*)d_in[9];
  ga.esrc[2] = (const int*)d_in[10]; ga.edst[2] = (const int*)d_in[11];
  ga.esrc[3] = (const int*)d_in[12]; ga.edst[3] = (const int*)d_in[13];
  ga.ebase[0] = 0; ga.ebase[1] = E0; ga.ebase[2] = E0 + E1;
  ga.ebase[3] = E0 + E1 + E2; ga.ebase[4] = Etot;
  ga.nbase[0] = 0; ga.nbase[1] = NG; ga.nbase[2] = NG + ND; ga.nbase[3] = NG + ND + NG;

  k_binA<<<(Etot + 4095) / 4096, 256, 0, stream>>>(ga, Etot, NB, bucketCur, binned);
  k_binB<<<NB, 256, 0, stream>>>(bucketCur, binned, ptr, cnt, ss, Ntot);

  // W preprocessing: 7 slabs/layer: 0:Wl0 1:Wl2 2:Wr0+Wr2 3:Wl1 4:Wr1 5:Wl3 6:Wr3
  PrepArgs pa;
  for (int L = 0; L < 2; ++L) {
    int b = L * 7;
    pa.a[b + 0] = Wl + (size_t)(L * 4 + 0) * HH; pa.b[b + 0] = nullptr;
    pa.a[b + 1] = Wl + (size_t)(L * 4 + 2) * HH; pa.b[b + 1] = nullptr;
    pa.a[b + 2] = Wr + (size_t)(L * 4 + 0) * HH; pa.b[b + 2] = Wr + (size_t)(L * 4 + 2) * HH;
    pa.a[b + 3] = Wl + (size_t)(L * 4 + 1) * HH; pa.b[b + 3] = nullptr;
    pa.a[b + 4] = Wr + (size_t)(L * 4 + 1) * HH; pa.b[b + 4] = nullptr;
    pa.a[b + 5] = Wl + (size_t)(L * 4 + 3) * HH; pa.b[b + 5] = nullptr;
    pa.a[b + 6] = Wr + (size_t)(L * 4 + 3) * HH; pa.b[b + 6] = nullptr;
  }
  k_prepw<<<dim3(14, 16), 256, 0, stream>>>(pa, wprep);

  float* out = (float*)d_out;
  float* xg_out = out;
  float* xd_out = out + (size_t)NG * HD;
  float* xc_out = out + (size_t)(NG + ND) * HD;

  for (int L = 0; L < 2; ++L) {
    const unsigned short* xg = L ? xbf_g1 : xbf_g0;
    const unsigned short* xd = L ? xbf_d1 : xbf_d0;
    const unsigned short* xc = L ? xbf_c1 : xbf_c0;
    const unsigned char* x8g = L ? x8_g1 : x8_g0;
    const unsigned char* x8c = L ? x8_c1 : x8_c0;

    // fused aggregates (reln order: gg(src xg), cd(src xc), cg(src xc), gc(src xg))
    AArgs aa;
    aa.xs[0] = x8g; aa.xs[1] = x8c; aa.xs[2] = x8c; aa.xs[3] = x8g;
    aa.mean[0] = mean_gg; aa.mean[1] = mean_cd; aa.mean[2] = mean_cg; aa.mean[3] = mean_gc;
    aa.nbase[0] = 0; aa.nbase[1] = NG; aa.nbase[2] = NG + ND; aa.nbase[3] = NG + ND + NG;
    aa.n[0] = NG; aa.n[1] = ND; aa.n[2] = NG; aa.n[3] = NC;
    int bb = 0;
    for (int r = 0; r < 4; ++r) { aa.bbase[r] = bb; bb += (aa.n[r] + 15) / 16; }
    aa.bbase[4] = bb;
    k_aggregate_all<<<bb, 256, 0, stream>>>(aa, ptr, cnt, ss);

    const float* bl_L = bl + (size_t)L * 4 * HD;
    const unsigned short* wp = wprep + (size_t)L * 7 * 16384;

    GemmArgs gm;
    // genes: mean_gg@Wl0 + mean_cg@Wl2 + xg@(Wr0+Wr2) + bl0 + bl2
    gm.x[0][0] = mean_gg; gm.x[0][1] = mean_cg; gm.x[0][2] = xg;
    gm.wp[0][0] = wp + 0 * 16384; gm.wp[0][1] = wp + 1 * 16384; gm.wp[0][2] = wp + 2 * 16384;
    gm.b0[0] = bl_L + 0 * HD; gm.b1[0] = bl_L + 2 * HD;
    gm.M[0] = NG; gm.nslab[0] = 3;
    // disease: mean_cd@Wl1 + xd@Wr1 + bl1
    gm.x[1][0] = mean_cd; gm.x[1][1] = xd; gm.x[1][2] = nullptr;
    gm.wp[1][0] = wp + 3 * 16384; gm.wp[1][1] = wp + 4 * 16384; gm.wp[1][2] = nullptr;
    gm.b0[1] = bl_L + 1 * HD; gm.b1[1] = nullptr;
    gm.M[1] = ND; gm.nslab[1] = 2;
    // compound: mean_gc@Wl3 + xc@Wr3 + bl3
    gm.x[2][0] = mean_gc; gm.x[2][1] = xc; gm.x[2][2] = nullptr;
    gm.wp[2][0] = wp + 5 * 16384; gm.wp[2][1] = wp + 6 * 16384; gm.wp[2][2] = nullptr;
    gm.b0[2] = bl_L + 3 * HD; gm.b1[2] = nullptr;
    gm.M[2] = NC; gm.nslab[2] = 2;
    if (L) {
      gm.outf[0] = xg_out; gm.outf[1] = xd_out; gm.outf[2] = xc_out;
      gm.outb[0] = gm.outb[1] = gm.outb[2] = nullptr;
      gm.out8[0] = gm.out8[1] = gm.out8[2] = nullptr;
    } else {
      gm.outf[0] = gm.outf[1] = gm.outf[2] = nullptr;
      gm.outb[0] = xbf_g1; gm.outb[1] = xbf_d1; gm.outb[2] = xbf_c1;
      gm.out8[0] = x8_g1; gm.out8[1] = nullptr; gm.out8[2] = x8_c1;  // disease never gathered
    }
    gm.relu = (L == 0) ? 1 : 0;
    int gb = 0;
    for (int t = 0; t < 3; ++t) { gm.gbase[t] = gb; gb += (gm.M[t] + 127) / 128; }
    gm.gbase[3] = gb;
    k_gemm_all<<<gb, 256, 0, stream>>>(gm);
  }
}

// Round 9
// 355.340 us; speedup vs baseline: 3.9119x; 1.0525x over previous
//
#include <hip/hip_runtime.h>

// HeteroGNN: 2-layer hetero SAGE (gene/disease/compound), H=128.
// R9 (bit-identical math vs R8):
//  - k_aggregate_all: 8-lane row-groups, uint4 (16B)/lane -> one gather instr
//    serves 8 edges (was 4); per-edge shfl count also halves. Same ss edge
//    order per output element -> bit-identical.
//  - k_convert: disease fp8 table skipped (never gathered).
// Pipeline unchanged: memset, convert, binA, binB, prepw, L0{agg,gemm},
// L1{agg,gemm} = 9 launches.

constexpr int HD = 128;
constexpr int NBMAX = 512;     // max buckets (Ntot/1024 = 293 here)
constexpr int BSTRIDE = 32768; // per-bucket record capacity (expected max ~13K)

typedef __attribute__((ext_vector_type(8))) short bf16x8;
typedef __attribute__((ext_vector_type(16))) float f32x16;
typedef __attribute__((ext_vector_type(2))) float f32x2;

__device__ __forceinline__ unsigned short f2bf(float x) {
  unsigned u = __builtin_bit_cast(unsigned, x);
  u += 0x7FFF + ((u >> 16) & 1);  // RNE
  return (unsigned short)(u >> 16);
}
__device__ __forceinline__ float bf2f(unsigned short h) {
  return __builtin_bit_cast(float, (unsigned)h << 16);
}

// pack 8 f32 (x16 scale) -> 8 fp8 bytes (uint2)
__device__ __forceinline__ uint2 pack_fp8x8(const float* v) {
  uint2 o;
  unsigned t;
  t = (unsigned)__builtin_amdgcn_cvt_pk_fp8_f32(v[0] * 16.f, v[1] * 16.f, 0, false);
  t = (unsigned)__builtin_amdgcn_cvt_pk_fp8_f32(v[2] * 16.f, v[3] * 16.f, (int)t, true);
  o.x = t;
  t = (unsigned)__builtin_amdgcn_cvt_pk_fp8_f32(v[4] * 16.f, v[5] * 16.f, 0, false);
  t = (unsigned)__builtin_amdgcn_cvt_pk_fp8_f32(v[6] * 16.f, v[7] * 16.f, (int)t, true);
  o.y = t;
  return o;
}

// ---------------- f32 -> bf16 + fp8 table convert (3 tables, fused) ----------------
__global__ __launch_bounds__(256) void k_convert(const float* __restrict__ s0,
                                                 const float* __restrict__ s1,
                                                 const float* __restrict__ s2,
                                                 unsigned short* __restrict__ d0,
                                                 unsigned short* __restrict__ d1,
                                                 unsigned short* __restrict__ d2,
                                                 unsigned char* __restrict__ e0,
                                                 unsigned char* __restrict__ e2,
                                                 long long n0, long long n1, long long n2) {
  long long i = ((long long)blockIdx.x * 256 + threadIdx.x) * 8;
  const float* s;
  unsigned short* d;
  unsigned char* e;
  if (i < n0) { s = s0 + i; d = d0 + i; e = e0 + i; }
  else if (i < n0 + n1) { s = s1 + (i - n0); d = d1 + (i - n0); e = nullptr; }  // disease: no fp8
  else if (i < n0 + n1 + n2) { s = s2 + (i - n0 - n1); d = d2 + (i - n0 - n1); e = e2 + (i - n0 - n1); }
  else return;
  float4 a = *(const float4*)s;
  float4 b = *(const float4*)(s + 4);
  float v[8] = {a.x, a.y, a.z, a.w, b.x, b.y, b.z, b.w};
  uint4 o;
  o.x = (unsigned)f2bf(v[0]) | ((unsigned)f2bf(v[1]) << 16);
  o.y = (unsigned)f2bf(v[2]) | ((unsigned)f2bf(v[3]) << 16);
  o.z = (unsigned)f2bf(v[4]) | ((unsigned)f2bf(v[5]) << 16);
  o.w = (unsigned)f2bf(v[6]) | ((unsigned)f2bf(v[7]) << 16);
  *(uint4*)d = o;
  if (e) *(uint2*)e = pack_fp8x8(v);
}

// ---------------- CSR build: two-pass binned sort ----------------
struct GArgs {
  const int* esrc[4];
  const int* edst[4];
  int ebase[5];  // edge prefix over concatenated edge space
  int nbase[4];  // dst-node prefix per relation (concat node space)
};

// Pass A: bin edges into 1024-node buckets; packed rec = (g&1023)<<20 | src.
__global__ __launch_bounds__(256) void k_binA(GArgs ga, int Etot, int NB,
                                              int* __restrict__ bucketCur,
                                              unsigned* __restrict__ binned) {
  __shared__ int hist[NBMAX];
  __shared__ int base[NBMAX];
  const int tid = threadIdx.x;
  for (int b = tid; b < NB; b += 256) hist[b] = 0;
  __syncthreads();
  const int e0 = blockIdx.x * 4096;
  for (int i = tid; i < 4096; i += 256) {
    int e = e0 + i;
    if (e < Etot) {
      int r = (e >= ga.ebase[1]) + (e >= ga.ebase[2]) + (e >= ga.ebase[3]);
      int g = ga.nbase[r] + ga.edst[r][e - ga.ebase[r]];
      atomicAdd(&hist[g >> 10], 1);
    }
  }
  __syncthreads();
  for (int b = tid; b < NB; b += 256) {
    int h = hist[b];
    base[b] = h ? atomicAdd(&bucketCur[b], h) : 0;
    hist[b] = 0;  // same thread owns b in both statements -> ordered
  }
  __syncthreads();
  for (int i = tid; i < 4096; i += 256) {
    int e = e0 + i;
    if (e < Etot) {
      int r = (e >= ga.ebase[1]) + (e >= ga.ebase[2]) + (e >= ga.ebase[3]);
      int el = e - ga.ebase[r];
      int g = ga.nbase[r] + ga.edst[r][el];
      int b = g >> 10;
      int pos = base[b] + atomicAdd(&hist[b], 1);
      binned[(size_t)b * BSTRIDE + pos] =
          ((unsigned)(g & 1023) << 20) | (unsigned)ga.esrc[r][el];
    }
  }
}

// Pass B: one block per bucket; per-node LDS hist + scan -> ptr/cnt; LDS-cursor
// scatter -> ss (bucket output contiguous, single-CU -> L2-friendly).
__global__ __launch_bounds__(256) void k_binB(const int* __restrict__ bucketCur,
                                              const unsigned* __restrict__ binned,
                                              int* __restrict__ ptr, int* __restrict__ cnt,
                                              int* __restrict__ ss, int Ntot) {
  const int b = blockIdx.x;
  const int tid = threadIdx.x;
  __shared__ int ncnt[1024];
  __shared__ int noff[1024];
  __shared__ int red[256];
  __shared__ int sbase_s;
  __shared__ int wsum[4], wbase[4];

  int part = 0;
  for (int i = tid; i < b; i += 256) part += bucketCur[i];
  red[tid] = part;
  __syncthreads();
  for (int s = 128; s > 0; s >>= 1) {
    if (tid < s) red[tid] += red[tid + s];
    __syncthreads();
  }
  if (tid == 0) sbase_s = red[0];

  for (int j = tid; j < 1024; j += 256) ncnt[j] = 0;
  __syncthreads();

  const int ecount = bucketCur[b];
  const unsigned* bp = binned + (size_t)b * BSTRIDE;
  for (int i = tid; i < ecount; i += 256) atomicAdd(&ncnt[bp[i] >> 20], 1);
  __syncthreads();

  const int j0 = tid * 4;
  int c0 = ncnt[j0], c1 = ncnt[j0 + 1], c2 = ncnt[j0 + 2], c3 = ncnt[j0 + 3];
  int s4 = c0 + c1 + c2 + c3;
  int lane = tid & 63, wid = tid >> 6;
  int incl = s4;
#pragma unroll
  for (int off = 1; off < 64; off <<= 1) {
    int t = __shfl_up(incl, off);
    if (lane >= off) incl += t;
  }
  if (lane == 63) wsum[wid] = incl;
  __syncthreads();
  if (tid == 0) {
    int acc = 0;
#pragma unroll
    for (int w2 = 0; w2 < 4; ++w2) { wbase[w2] = acc; acc += wsum[w2]; }
  }
  __syncthreads();
  int excl = wbase[wid] + incl - s4;
  const int sbase = sbase_s;
  int o0 = excl, o1 = excl + c0, o2 = o1 + c1, o3 = o2 + c2;
  noff[j0] = o0; noff[j0 + 1] = o1; noff[j0 + 2] = o2; noff[j0 + 3] = o3;
  int g0 = b * 1024 + j0;
  if (g0 + 0 < Ntot) { ptr[g0 + 0] = sbase + o0; cnt[g0 + 0] = c0; }
  if (g0 + 1 < Ntot) { ptr[g0 + 1] = sbase + o1; cnt[g0 + 1] = c1; }
  if (g0 + 2 < Ntot) { ptr[g0 + 2] = sbase + o2; cnt[g0 + 2] = c2; }
  if (g0 + 3 < Ntot) { ptr[g0 + 3] = sbase + o3; cnt[g0 + 3] = c3; }
  __syncthreads();

  for (int i = tid; i < ecount; i += 256) {
    unsigned rec = bp[i];
    int j = rec >> 20;
    int p = sbase + atomicAdd(&noff[j], 1);
    ss[p] = (int)(rec & 0xFFFFF);
  }
}

// ---------------- fused neighbor mean (4 relations, fp8 gather) ----------------
// 8-lane groups: lane covers 16 cols (uint4); one wave = 8 dst nodes; one
// gather instr = 8 edges x 128B. Per-element edge order identical to R8.
struct AArgs {
  const unsigned char* xs[4];   // fp8 tables (x16 scale)
  unsigned short* mean[4];      // bf16 out
  int nbase[4];
  int bbase[5];  // block prefix
  int n[4];
};

__global__ __launch_bounds__(256) void k_aggregate_all(AArgs A, const int* __restrict__ ptr,
                                                       const int* __restrict__ cnt,
                                                       const int* __restrict__ ss) {
  int b = blockIdx.x;
  int r = (b >= A.bbase[1]) + (b >= A.bbase[2]) + (b >= A.bbase[3]);
  int d = (b - A.bbase[r]) * 32 + (threadIdx.x >> 3);
  if (d >= A.n[r]) return;
  const unsigned char* xs = A.xs[r];
  int l = threadIdx.x & 7;
  int g = A.nbase[r] + d;
  int p = ptr[g];
  int deg = cnt[g];
  float a0 = 0.f, a1 = 0.f, a2 = 0.f, a3 = 0.f, a4 = 0.f, a5 = 0.f, a6 = 0.f, a7 = 0.f;
  float a8 = 0.f, a9 = 0.f, aA = 0.f, aB = 0.f, aC = 0.f, aD = 0.f, aE = 0.f, aF = 0.f;
  for (int j0 = 0; j0 < deg; j0 += 8) {
    int m = deg - j0;
    if (m > 8) m = 8;
    int idx = ss[p + j0 + (l < m ? l : m - 1)];
    uint4 uu[8];
#pragma unroll
    for (int k = 0; k < 8; ++k) {
      if (k < m) {
        int s = __shfl(idx, k, 8);
        uu[k] = *(const uint4*)(xs + (size_t)s * HD + l * 16);
      }
    }
#pragma unroll
    for (int k = 0; k < 8; ++k) {
      if (k < m) {
        f32x2 q;
        q = __builtin_amdgcn_cvt_pk_f32_fp8(uu[k].x, false); a0 += q.x; a1 += q.y;
        q = __builtin_amdgcn_cvt_pk_f32_fp8(uu[k].x, true);  a2 += q.x; a3 += q.y;
        q = __builtin_amdgcn_cvt_pk_f32_fp8(uu[k].y, false); a4 += q.x; a5 += q.y;
        q = __builtin_amdgcn_cvt_pk_f32_fp8(uu[k].y, true);  a6 += q.x; a7 += q.y;
        q = __builtin_amdgcn_cvt_pk_f32_fp8(uu[k].z, false); a8 += q.x; a9 += q.y;
        q = __builtin_amdgcn_cvt_pk_f32_fp8(uu[k].z, true);  aA += q.x; aB += q.y;
        q = __builtin_amdgcn_cvt_pk_f32_fp8(uu[k].w, false); aC += q.x; aD += q.y;
        q = __builtin_amdgcn_cvt_pk_f32_fp8(uu[k].w, true);  aE += q.x; aF += q.y;
      }
    }
  }
  float inv = 1.0f / (16.0f * (float)(deg > 0 ? deg : 1));  // fold out x16 scale
  uint4 o;
  unsigned short* mp = A.mean[r] + (size_t)d * HD + l * 16;
  o.x = (unsigned)f2bf(a0 * inv) | ((unsigned)f2bf(a1 * inv) << 16);
  o.y = (unsigned)f2bf(a2 * inv) | ((unsigned)f2bf(a3 * inv) << 16);
  o.z = (unsigned)f2bf(a4 * inv) | ((unsigned)f2bf(a5 * inv) << 16);
  o.w = (unsigned)f2bf(a6 * inv) | ((unsigned)f2bf(a7 * inv) << 16);
  *(uint4*)mp = o;
  o.x = (unsigned)f2bf(a8 * inv) | ((unsigned)f2bf(a9 * inv) << 16);
  o.y = (unsigned)f2bf(aA * inv) | ((unsigned)f2bf(aB * inv) << 16);
  o.z = (unsigned)f2bf(aC * inv) | ((unsigned)f2bf(aD * inv) << 16);
  o.w = (unsigned)f2bf(aE * inv) | ((unsigned)f2bf(aF * inv) << 16);
  *(uint4*)(mp + 8) = o;
}

// ---------------- W preprocessing ----------------
// W (or Wa+Wb) [k][n] f32 -> transposed [n][k] bf16, k swizzled:
// idx = n*128 + (k ^ ((n&15)<<3))  -> conflict-free ds_read_b128 in GEMM.
struct PrepArgs {
  const float* a[14];
  const float* b[14];
};

__global__ __launch_bounds__(256) void k_prepw(PrepArgs pa, unsigned short* __restrict__ out) {
  int s = blockIdx.x;
  const float* A = pa.a[s];
  const float* B = pa.b[s];
  unsigned short* oh = out + (size_t)s * 16384;
  int e0 = blockIdx.y * 1024 + threadIdx.x * 4;
#pragma unroll
  for (int j = 0; j < 4; ++j) {
    int e = e0 + j;
    int k = e >> 7, n = e & 127;
    float v = A[e] + (B ? B[e] : 0.f);
    oh[n * 128 + (k ^ ((n & 15) << 3))] = f2bf(v);
  }
}

// ---------------- merged MFMA GEMM (3 node types, one dispatch) ----------------
// M-tile 128, 4 waves, wave owns 32 rows (acc[4]). L0 epilogue also emits the
// fp8 gather table from the bf16-ROUNDED value.
struct GemmArgs {
  const unsigned short* x[3][3];   // [type][slab]
  const unsigned short* wp[3][3];
  const float* b0[3];
  const float* b1[3];
  float* outf[3];                  // layer-1: d_out segment; layer-0: null
  unsigned short* outb[3];         // layer-0: bf16 hidden table
  unsigned char* out8[3];          // layer-0: fp8 hidden table (null = skip)
  int M[3];
  int nslab[3];
  int gbase[4];                    // block prefix per type
  int relu;
};

__global__ __launch_bounds__(256, 4) void k_gemm_all(GemmArgs ga) {
  __shared__ unsigned short ldsb[16384];  // 32KB
  const int t = (blockIdx.x >= ga.gbase[1]) + (blockIdx.x >= ga.gbase[2]);
  const int blk = blockIdx.x - ga.gbase[t];
  const int M = ga.M[t];
  const int nslab = ga.nslab[t];
  const int tid = threadIdx.x;
  const int wave = tid >> 6;
  const int lane = tid & 63;
  const int l31 = lane & 31;
  const int lhalf = lane >> 5;

  const int mbase = blk * 128 + wave * 32;
  int r0 = mbase + l31;
  if (r0 > M - 1) r0 = M - 1;

  f32x16 acc[4];
#pragma unroll
  for (int n = 0; n < 4; ++n)
#pragma unroll
    for (int q = 0; q < 16; ++q) acc[n][q] = 0.f;

#pragma unroll
  for (int s = 0; s < 3; ++s) {
    if (s < nslab) {
      const unsigned short* xp = ga.x[t][s];
      __syncthreads();  // protect LDS from previous slab's readers
      {
        const float4* src = (const float4*)ga.wp[t][s];
        float4* dst = (float4*)ldsb;
#pragma unroll
        for (int j = 0; j < 8; ++j) dst[tid + j * 256] = src[tid + j * 256];
      }
      __syncthreads();

#pragma unroll
      for (int ks = 0; ks < 8; ++ks) {
        const int k0 = ks * 16 + lhalf * 8;
        bf16x8 a0 = *(const bf16x8*)(xp + (size_t)r0 * HD + k0);
#pragma unroll
        for (int nt = 0; nt < 4; ++nt) {
          const int rown = nt * 32 + l31;
          const int kidx = k0 ^ ((rown & 15) << 3);
          const bf16x8 bb = *(const bf16x8*)&ldsb[rown * HD + kidx];
          acc[nt] = __builtin_amdgcn_mfma_f32_32x32x16_bf16(a0, bb, acc[nt], 0, 0, 0);
        }
      }
    }
  }

  const float* b0 = ga.b0[t];
  const float* b1 = ga.b1[t];
  float* outf = ga.outf[t];
  unsigned short* outb = ga.outb[t];
  unsigned char* out8 = ga.out8[t];
#pragma unroll
  for (int nt = 0; nt < 4; ++nt) {
    const int col = nt * 32 + l31;
    float bias = b0[col] + (b1 ? b1[col] : 0.f);
#pragma unroll
    for (int rg = 0; rg < 16; ++rg) {
      int row = mbase + (rg & 3) + 8 * (rg >> 2) + 4 * lhalf;
      float v = acc[nt][rg] + bias;
      if (ga.relu) v = fmaxf(v, 0.f);
      if (row < M) {
        if (outf) {
          outf[(size_t)row * HD + col] = v;
        } else {
          unsigned short h = f2bf(v);
          outb[(size_t)row * HD + col] = h;
          if (out8) {
            float vb = bf2f(h);  // bf16-rounded value (matches table semantics)
            unsigned pk = (unsigned)__builtin_amdgcn_cvt_pk_fp8_f32(vb * 16.f, vb * 16.f, 0, false);
            out8[(size_t)row * HD + col] = (unsigned char)(pk & 0xFF);
          }
        }
      }
    }
  }
}

extern "C" void kernel_launch(void* const* d_in, const int* in_sizes, int n_in,
                              void* d_out, int out_size, void* d_ws, size_t ws_size,
                              hipStream_t stream) {
  const float* emb_g = (const float*)d_in[0];
  const float* emb_d = (const float*)d_in[1];
  const float* emb_c = (const float*)d_in[2];
  const float* Wl = (const float*)d_in[3];   // [2,4,128,128]
  const float* bl = (const float*)d_in[4];   // [2,4,128]
  const float* Wr = (const float*)d_in[5];   // [2,4,128,128]

  const int NG = in_sizes[0] / HD;
  const int ND = in_sizes[1] / HD;
  const int NC = in_sizes[2] / HD;
  const int E0 = in_sizes[6];   // g->g
  const int E1 = in_sizes[8];   // c->d
  const int E2 = in_sizes[10];  // c->g
  const int E3 = in_sizes[12];  // g->c
  const int HH = HD * HD;
  const int Etot = E0 + E1 + E2 + E3;
  const int Ntot = NG + ND + NG + NC;
  const int NB = (Ntot + 1023) >> 10;  // 1024-node buckets

  // ---- workspace carve (all 16B-aligned by construction) ----
  char* w = (char*)d_ws;
  unsigned short* wprep = (unsigned short*)w; w += (size_t)14 * 32768;
  unsigned short* xbf_g0 = (unsigned short*)w; w += (size_t)NG * HD * 2;
  unsigned short* xbf_d0 = (unsigned short*)w; w += (size_t)ND * HD * 2;
  unsigned short* xbf_c0 = (unsigned short*)w; w += (size_t)NC * HD * 2;
  unsigned short* xbf_g1 = (unsigned short*)w; w += (size_t)NG * HD * 2;
  unsigned short* xbf_d1 = (unsigned short*)w; w += (size_t)ND * HD * 2;
  unsigned short* xbf_c1 = (unsigned short*)w; w += (size_t)NC * HD * 2;
  unsigned short* mean_gg = (unsigned short*)w; w += (size_t)NG * HD * 2;
  unsigned short* mean_cd = (unsigned short*)w; w += (size_t)ND * HD * 2;
  unsigned short* mean_cg = (unsigned short*)w; w += (size_t)NG * HD * 2;
  unsigned short* mean_gc = (unsigned short*)w; w += (size_t)NC * HD * 2;
  unsigned char* x8_g0 = (unsigned char*)w; w += (size_t)NG * HD;
  unsigned char* x8_c0 = (unsigned char*)w; w += (size_t)NC * HD;
  unsigned char* x8_g1 = (unsigned char*)w; w += (size_t)NG * HD;
  unsigned char* x8_c1 = (unsigned char*)w; w += (size_t)NC * HD;
  int* ss = (int*)w;        w += (size_t)Etot * 4;
  int* ptr = (int*)w;       w += (size_t)Ntot * 4;
  int* cnt = (int*)w;       w += (size_t)Ntot * 4;
  unsigned* binned = (unsigned*)w; w += (size_t)NB * BSTRIDE * 4;
  int* bucketCur = (int*)w; w += (size_t)NBMAX * 4;  // zeroed

  hipMemsetAsync(bucketCur, 0, (size_t)NBMAX * 4, stream);

  // bf16 (+fp8 for gene/compound) feature tables for layer 0
  {
    long long n0 = (long long)NG * HD, n1 = (long long)ND * HD, n2 = (long long)NC * HD;
    long long tot8 = (n0 + n1 + n2) / 8;
    k_convert<<<(int)((tot8 + 255) / 256), 256, 0, stream>>>(
        emb_g, emb_d, emb_c, xbf_g0, xbf_d0, xbf_c0, x8_g0, x8_c0, n0, n1, n2);
  }

  // CSR build over concatenated spaces (two-pass binned sort)
  GArgs ga;
  ga.esrc[0] = (const int*)d_in[6];  ga.edst[0] = (const int*)d_in[7];
  ga.esrc[1] = (const int*)d_in[8];  ga.edst[1] = (const int*)d_in[9];
  ga.esrc[2] = (const int*)d_in[10]; ga.edst[2] = (const int*)d_in[11];
  ga.esrc[3] = (const int*)d_in[12]; ga.edst[3] = (const int*)d_in[13];
  ga.ebase[0] = 0; ga.ebase[1] = E0; ga.ebase[2] = E0 + E1;
  ga.ebase[3] = E0 + E1 + E2; ga.ebase[4] = Etot;
  ga.nbase[0] = 0; ga.nbase[1] = NG; ga.nbase[2] = NG + ND; ga.nbase[3] = NG + ND + NG;

  k_binA<<<(Etot + 4095) / 4096, 256, 0, stream>>>(ga, Etot, NB, bucketCur, binned);
  k_binB<<<NB, 256, 0, stream>>>(bucketCur, binned, ptr, cnt, ss, Ntot);

  // W preprocessing: 7 slabs/layer: 0:Wl0 1:Wl2 2:Wr0+Wr2 3:Wl1 4:Wr1 5:Wl3 6:Wr3
  PrepArgs pa;
  for (int L = 0; L < 2; ++L) {
    int b = L * 7;
    pa.a[b + 0] = Wl + (size_t)(L * 4 + 0) * HH; pa.b[b + 0] = nullptr;
    pa.a[b + 1] = Wl + (size_t)(L * 4 + 2) * HH; pa.b[b + 1] = nullptr;
    pa.a[b + 2] = Wr + (size_t)(L * 4 + 0) * HH; pa.b[b + 2] = Wr + (size_t)(L * 4 + 2) * HH;
    pa.a[b + 3] = Wl + (size_t)(L * 4 + 1) * HH; pa.b[b + 3] = nullptr;
    pa.a[b + 4] = Wr + (size_t)(L * 4 + 1) * HH; pa.b[b + 4] = nullptr;
    pa.a[b + 5] = Wl + (size_t)(L * 4 + 3) * HH; pa.b[b + 5] = nullptr;
    pa.a[b + 6] = Wr + (size_t)(L * 4 + 3) * HH; pa.b[b + 6] = nullptr;
  }
  k_prepw<<<dim3(14, 16), 256, 0, stream>>>(pa, wprep);

  float* out = (float*)d_out;
  float* xg_out = out;
  float* xd_out = out + (size_t)NG * HD;
  float* xc_out = out + (size_t)(NG + ND) * HD;

  for (int L = 0; L < 2; ++L) {
    const unsigned short* xg = L ? xbf_g1 : xbf_g0;
    const unsigned short* xd = L ? xbf_d1 : xbf_d0;
    const unsigned short* xc = L ? xbf_c1 : xbf_c0;
    const unsigned char* x8g = L ? x8_g1 : x8_g0;
    const unsigned char* x8c = L ? x8_c1 : x8_c0;

    // fused aggregates (reln order: gg(src xg), cd(src xc), cg(src xc), gc(src xg))
    AArgs aa;
    aa.xs[0] = x8g; aa.xs[1] = x8c; aa.xs[2] = x8c; aa.xs[3] = x8g;
    aa.mean[0] = mean_gg; aa.mean[1] = mean_cd; aa.mean[2] = mean_cg; aa.mean[3] = mean_gc;
    aa.nbase[0] = 0; aa.nbase[1] = NG; aa.nbase[2] = NG + ND; aa.nbase[3] = NG + ND + NG;
    aa.n[0] = NG; aa.n[1] = ND; aa.n[2] = NG; aa.n[3] = NC;
    int bb = 0;
    for (int r = 0; r < 4; ++r) { aa.bbase[r] = bb; bb += (aa.n[r] + 31) / 32; }
    aa.bbase[4] = bb;
    k_aggregate_all<<<bb, 256, 0, stream>>>(aa, ptr, cnt, ss);

    const float* bl_L = bl + (size_t)L * 4 * HD;
    const unsigned short* wp = wprep + (size_t)L * 7 * 16384;

    GemmArgs gm;
    // genes: mean_gg@Wl0 + mean_cg@Wl2 + xg@(Wr0+Wr2) + bl0 + bl2
    gm.x[0][0] = mean_gg; gm.x[0][1] = mean_cg; gm.x[0][2] = xg;
    gm.wp[0][0] = wp + 0 * 16384; gm.wp[0][1] = wp + 1 * 16384; gm.wp[0][2] = wp + 2 * 16384;
    gm.b0[0] = bl_L + 0 * HD; gm.b1[0] = bl_L + 2 * HD;
    gm.M[0] = NG; gm.nslab[0] = 3;
    // disease: mean_cd@Wl1 + xd@Wr1 + bl1
    gm.x[1][0] = mean_cd; gm.x[1][1] = xd; gm.x[1][2] = nullptr;
    gm.wp[1][0] = wp + 3 * 16384; gm.wp[1][1] = wp + 4 * 16384; gm.wp[1][2] = nullptr;
    gm.b0[1] = bl_L + 1 * HD; gm.b1[1] = nullptr;
    gm.M[1] = ND; gm.nslab[1] = 2;
    // compound: mean_gc@Wl3 + xc@Wr3 + bl3
    gm.x[2][0] = mean_gc; gm.x[2][1] = xc; gm.x[2][2] = nullptr;
    gm.wp[2][0] = wp + 5 * 16384; gm.wp[2][1] = wp + 6 * 16384; gm.wp[2][2] = nullptr;
    gm.b0[2] = bl_L + 3 * HD; gm.b1[2] = nullptr;
    gm.M[2] = NC; gm.nslab[2] = 2;
    if (L) {
      gm.outf[0] = xg_out; gm.outf[1] = xd_out; gm.outf[2] = xc_out;
      gm.outb[0] = gm.outb[1] = gm.outb[2] = nullptr;
      gm.out8[0] = gm.out8[1] = gm.out8[2] = nullptr;
    } else {
      gm.outf[0] = gm.outf[1] = gm.outf[2] = nullptr;
      gm.outb[0] = xbf_g1; gm.outb[1] = xbf_d1; gm.outb[2] = xbf_c1;
      gm.out8[0] = x8_g1; gm.out8[1] = nullptr; gm.out8[2] = x8_c1;  // disease never gathered
    }
    gm.relu = (L == 0) ? 1 : 0;
    int gb = 0;
    for (int t = 0; t < 3; ++t) { gm.gbase[t] = gb; gb += (gm.M[t] + 127) / 128; }
    gm.gbase[3] = gb;
    k_gemm_all<<<gb, 256, 0, stream>>>(gm);
  }
}

// Round 10
// 334.061 us; speedup vs baseline: 4.1611x; 1.0637x over previous
//
#include <hip/hip_runtime.h>

// HeteroGNN: 2-layer hetero SAGE (gene/disease/compound), H=128.
// R10 (bit-identical math vs R9):
//  - k_gemm_all: per-slab A row prefetched in full (8 independent 16B loads
//    issued before the staging barrier) -> MLP 1->8, loads overlap staging.
//  - k_aggregate_all: f32x2 accumulators -> v_pk_add_f32 (half the VALU adds);
//    per-element add chain/order unchanged.
// Pipeline unchanged: memset, convert, binA, binB, prepw, L0{agg,gemm},
// L1{agg,gemm} = 9 launches.

constexpr int HD = 128;
constexpr int NBMAX = 512;     // max buckets (Ntot/1024 = 293 here)
constexpr int BSTRIDE = 32768; // per-bucket record capacity (expected max ~13K)

typedef __attribute__((ext_vector_type(8))) short bf16x8;
typedef __attribute__((ext_vector_type(16))) float f32x16;
typedef __attribute__((ext_vector_type(2))) float f32x2;

__device__ __forceinline__ unsigned short f2bf(float x) {
  unsigned u = __builtin_bit_cast(unsigned, x);
  u += 0x7FFF + ((u >> 16) & 1);  // RNE
  return (unsigned short)(u >> 16);
}
__device__ __forceinline__ float bf2f(unsigned short h) {
  return __builtin_bit_cast(float, (unsigned)h << 16);
}

// pack 8 f32 (x16 scale) -> 8 fp8 bytes (uint2)
__device__ __forceinline__ uint2 pack_fp8x8(const float* v) {
  uint2 o;
  unsigned t;
  t = (unsigned)__builtin_amdgcn_cvt_pk_fp8_f32(v[0] * 16.f, v[1] * 16.f, 0, false);
  t = (unsigned)__builtin_amdgcn_cvt_pk_fp8_f32(v[2] * 16.f, v[3] * 16.f, (int)t, true);
  o.x = t;
  t = (unsigned)__builtin_amdgcn_cvt_pk_fp8_f32(v[4] * 16.f, v[5] * 16.f, 0, false);
  t = (unsigned)__builtin_amdgcn_cvt_pk_fp8_f32(v[6] * 16.f, v[7] * 16.f, (int)t, true);
  o.y = t;
  return o;
}

// ---------------- f32 -> bf16 + fp8 table convert (3 tables, fused) ----------------
__global__ __launch_bounds__(256) void k_convert(const float* __restrict__ s0,
                                                 const float* __restrict__ s1,
                                                 const float* __restrict__ s2,
                                                 unsigned short* __restrict__ d0,
                                                 unsigned short* __restrict__ d1,
                                                 unsigned short* __restrict__ d2,
                                                 unsigned char* __restrict__ e0,
                                                 unsigned char* __restrict__ e2,
                                                 long long n0, long long n1, long long n2) {
  long long i = ((long long)blockIdx.x * 256 + threadIdx.x) * 8;
  const float* s;
  unsigned short* d;
  unsigned char* e;
  if (i < n0) { s = s0 + i; d = d0 + i; e = e0 + i; }
  else if (i < n0 + n1) { s = s1 + (i - n0); d = d1 + (i - n0); e = nullptr; }  // disease: no fp8
  else if (i < n0 + n1 + n2) { s = s2 + (i - n0 - n1); d = d2 + (i - n0 - n1); e = e2 + (i - n0 - n1); }
  else return;
  float4 a = *(const float4*)s;
  float4 b = *(const float4*)(s + 4);
  float v[8] = {a.x, a.y, a.z, a.w, b.x, b.y, b.z, b.w};
  uint4 o;
  o.x = (unsigned)f2bf(v[0]) | ((unsigned)f2bf(v[1]) << 16);
  o.y = (unsigned)f2bf(v[2]) | ((unsigned)f2bf(v[3]) << 16);
  o.z = (unsigned)f2bf(v[4]) | ((unsigned)f2bf(v[5]) << 16);
  o.w = (unsigned)f2bf(v[6]) | ((unsigned)f2bf(v[7]) << 16);
  *(uint4*)d = o;
  if (e) *(uint2*)e = pack_fp8x8(v);
}

// ---------------- CSR build: two-pass binned sort ----------------
struct GArgs {
  const int* esrc[4];
  const int* edst[4];
  int ebase[5];  // edge prefix over concatenated edge space
  int nbase[4];  // dst-node prefix per relation (concat node space)
};

// Pass A: bin edges into 1024-node buckets; packed rec = (g&1023)<<20 | src.
__global__ __launch_bounds__(256) void k_binA(GArgs ga, int Etot, int NB,
                                              int* __restrict__ bucketCur,
                                              unsigned* __restrict__ binned) {
  __shared__ int hist[NBMAX];
  __shared__ int base[NBMAX];
  const int tid = threadIdx.x;
  for (int b = tid; b < NB; b += 256) hist[b] = 0;
  __syncthreads();
  const int e0 = blockIdx.x * 4096;
  for (int i = tid; i < 4096; i += 256) {
    int e = e0 + i;
    if (e < Etot) {
      int r = (e >= ga.ebase[1]) + (e >= ga.ebase[2]) + (e >= ga.ebase[3]);
      int g = ga.nbase[r] + ga.edst[r][e - ga.ebase[r]];
      atomicAdd(&hist[g >> 10], 1);
    }
  }
  __syncthreads();
  for (int b = tid; b < NB; b += 256) {
    int h = hist[b];
    base[b] = h ? atomicAdd(&bucketCur[b], h) : 0;
    hist[b] = 0;  // same thread owns b in both statements -> ordered
  }
  __syncthreads();
  for (int i = tid; i < 4096; i += 256) {
    int e = e0 + i;
    if (e < Etot) {
      int r = (e >= ga.ebase[1]) + (e >= ga.ebase[2]) + (e >= ga.ebase[3]);
      int el = e - ga.ebase[r];
      int g = ga.nbase[r] + ga.edst[r][el];
      int b = g >> 10;
      int pos = base[b] + atomicAdd(&hist[b], 1);
      binned[(size_t)b * BSTRIDE + pos] =
          ((unsigned)(g & 1023) << 20) | (unsigned)ga.esrc[r][el];
    }
  }
}

// Pass B: one block per bucket; per-node LDS hist + scan -> ptr/cnt; LDS-cursor
// scatter -> ss (bucket output contiguous, single-CU -> L2-friendly).
__global__ __launch_bounds__(256) void k_binB(const int* __restrict__ bucketCur,
                                              const unsigned* __restrict__ binned,
                                              int* __restrict__ ptr, int* __restrict__ cnt,
                                              int* __restrict__ ss, int Ntot) {
  const int b = blockIdx.x;
  const int tid = threadIdx.x;
  __shared__ int ncnt[1024];
  __shared__ int noff[1024];
  __shared__ int red[256];
  __shared__ int sbase_s;
  __shared__ int wsum[4], wbase[4];

  int part = 0;
  for (int i = tid; i < b; i += 256) part += bucketCur[i];
  red[tid] = part;
  __syncthreads();
  for (int s = 128; s > 0; s >>= 1) {
    if (tid < s) red[tid] += red[tid + s];
    __syncthreads();
  }
  if (tid == 0) sbase_s = red[0];

  for (int j = tid; j < 1024; j += 256) ncnt[j] = 0;
  __syncthreads();

  const int ecount = bucketCur[b];
  const unsigned* bp = binned + (size_t)b * BSTRIDE;
  for (int i = tid; i < ecount; i += 256) atomicAdd(&ncnt[bp[i] >> 20], 1);
  __syncthreads();

  const int j0 = tid * 4;
  int c0 = ncnt[j0], c1 = ncnt[j0 + 1], c2 = ncnt[j0 + 2], c3 = ncnt[j0 + 3];
  int s4 = c0 + c1 + c2 + c3;
  int lane = tid & 63, wid = tid >> 6;
  int incl = s4;
#pragma unroll
  for (int off = 1; off < 64; off <<= 1) {
    int t = __shfl_up(incl, off);
    if (lane >= off) incl += t;
  }
  if (lane == 63) wsum[wid] = incl;
  __syncthreads();
  if (tid == 0) {
    int acc = 0;
#pragma unroll
    for (int w2 = 0; w2 < 4; ++w2) { wbase[w2] = acc; acc += wsum[w2]; }
  }
  __syncthreads();
  int excl = wbase[wid] + incl - s4;
  const int sbase = sbase_s;
  int o0 = excl, o1 = excl + c0, o2 = o1 + c1, o3 = o2 + c2;
  noff[j0] = o0; noff[j0 + 1] = o1; noff[j0 + 2] = o2; noff[j0 + 3] = o3;
  int g0 = b * 1024 + j0;
  if (g0 + 0 < Ntot) { ptr[g0 + 0] = sbase + o0; cnt[g0 + 0] = c0; }
  if (g0 + 1 < Ntot) { ptr[g0 + 1] = sbase + o1; cnt[g0 + 1] = c1; }
  if (g0 + 2 < Ntot) { ptr[g0 + 2] = sbase + o2; cnt[g0 + 2] = c2; }
  if (g0 + 3 < Ntot) { ptr[g0 + 3] = sbase + o3; cnt[g0 + 3] = c3; }
  __syncthreads();

  for (int i = tid; i < ecount; i += 256) {
    unsigned rec = bp[i];
    int j = rec >> 20;
    int p = sbase + atomicAdd(&noff[j], 1);
    ss[p] = (int)(rec & 0xFFFFF);
  }
}

// ---------------- fused neighbor mean (4 relations, fp8 gather) ----------------
// 8-lane groups: lane covers 16 cols (uint4); one wave = 8 dst nodes; one
// gather instr = 8 edges x 128B. f32x2 accs -> v_pk_add_f32.
struct AArgs {
  const unsigned char* xs[4];   // fp8 tables (x16 scale)
  unsigned short* mean[4];      // bf16 out
  int nbase[4];
  int bbase[5];  // block prefix
  int n[4];
};

__global__ __launch_bounds__(256) void k_aggregate_all(AArgs A, const int* __restrict__ ptr,
                                                       const int* __restrict__ cnt,
                                                       const int* __restrict__ ss) {
  int b = blockIdx.x;
  int r = (b >= A.bbase[1]) + (b >= A.bbase[2]) + (b >= A.bbase[3]);
  int d = (b - A.bbase[r]) * 32 + (threadIdx.x >> 3);
  if (d >= A.n[r]) return;
  const unsigned char* xs = A.xs[r];
  int l = threadIdx.x & 7;
  int g = A.nbase[r] + d;
  int p = ptr[g];
  int deg = cnt[g];
  f32x2 b0 = {0.f, 0.f}, b1 = {0.f, 0.f}, b2 = {0.f, 0.f}, b3 = {0.f, 0.f};
  f32x2 b4 = {0.f, 0.f}, b5 = {0.f, 0.f}, b6 = {0.f, 0.f}, b7 = {0.f, 0.f};
  for (int j0 = 0; j0 < deg; j0 += 8) {
    int m = deg - j0;
    if (m > 8) m = 8;
    int idx = ss[p + j0 + (l < m ? l : m - 1)];
    uint4 uu[8];
#pragma unroll
    for (int k = 0; k < 8; ++k) {
      if (k < m) {
        int s = __shfl(idx, k, 8);
        uu[k] = *(const uint4*)(xs + (size_t)s * HD + l * 16);
      }
    }
#pragma unroll
    for (int k = 0; k < 8; ++k) {
      if (k < m) {
        b0 += __builtin_amdgcn_cvt_pk_f32_fp8(uu[k].x, false);
        b1 += __builtin_amdgcn_cvt_pk_f32_fp8(uu[k].x, true);
        b2 += __builtin_amdgcn_cvt_pk_f32_fp8(uu[k].y, false);
        b3 += __builtin_amdgcn_cvt_pk_f32_fp8(uu[k].y, true);
        b4 += __builtin_amdgcn_cvt_pk_f32_fp8(uu[k].z, false);
        b5 += __builtin_amdgcn_cvt_pk_f32_fp8(uu[k].z, true);
        b6 += __builtin_amdgcn_cvt_pk_f32_fp8(uu[k].w, false);
        b7 += __builtin_amdgcn_cvt_pk_f32_fp8(uu[k].w, true);
      }
    }
  }
  float inv = 1.0f / (16.0f * (float)(deg > 0 ? deg : 1));  // fold out x16 scale
  uint4 o;
  unsigned short* mp = A.mean[r] + (size_t)d * HD + l * 16;
  o.x = (unsigned)f2bf(b0.x * inv) | ((unsigned)f2bf(b0.y * inv) << 16);
  o.y = (unsigned)f2bf(b1.x * inv) | ((unsigned)f2bf(b1.y * inv) << 16);
  o.z = (unsigned)f2bf(b2.x * inv) | ((unsigned)f2bf(b2.y * inv) << 16);
  o.w = (unsigned)f2bf(b3.x * inv) | ((unsigned)f2bf(b3.y * inv) << 16);
  *(uint4*)mp = o;
  o.x = (unsigned)f2bf(b4.x * inv) | ((unsigned)f2bf(b4.y * inv) << 16);
  o.y = (unsigned)f2bf(b5.x * inv) | ((unsigned)f2bf(b5.y * inv) << 16);
  o.z = (unsigned)f2bf(b6.x * inv) | ((unsigned)f2bf(b6.y * inv) << 16);
  o.w = (unsigned)f2bf(b7.x * inv) | ((unsigned)f2bf(b7.y * inv) << 16);
  *(uint4*)(mp + 8) = o;
}

// ---------------- W preprocessing ----------------
// W (or Wa+Wb) [k][n] f32 -> transposed [n][k] bf16, k swizzled:
// idx = n*128 + (k ^ ((n&15)<<3))  -> conflict-free ds_read_b128 in GEMM.
struct PrepArgs {
  const float* a[14];
  const float* b[14];
};

__global__ __launch_bounds__(256) void k_prepw(PrepArgs pa, unsigned short* __restrict__ out) {
  int s = blockIdx.x;
  const float* A = pa.a[s];
  const float* B = pa.b[s];
  unsigned short* oh = out + (size_t)s * 16384;
  int e0 = blockIdx.y * 1024 + threadIdx.x * 4;
#pragma unroll
  for (int j = 0; j < 4; ++j) {
    int e = e0 + j;
    int k = e >> 7, n = e & 127;
    float v = A[e] + (B ? B[e] : 0.f);
    oh[n * 128 + (k ^ ((n & 15) << 3))] = f2bf(v);
  }
}

// ---------------- merged MFMA GEMM (3 node types, one dispatch) ----------------
// M-tile 128, 4 waves, wave owns 32 rows (acc[4]). Per slab: full A row (8x16B)
// prefetched before the staging barrier (MLP 8, overlaps LDS staging).
struct GemmArgs {
  const unsigned short* x[3][3];   // [type][slab]
  const unsigned short* wp[3][3];
  const float* b0[3];
  const float* b1[3];
  float* outf[3];                  // layer-1: d_out segment; layer-0: null
  unsigned short* outb[3];         // layer-0: bf16 hidden table
  unsigned char* out8[3];          // layer-0: fp8 hidden table (null = skip)
  int M[3];
  int nslab[3];
  int gbase[4];                    // block prefix per type
  int relu;
};

__global__ __launch_bounds__(256, 4) void k_gemm_all(GemmArgs ga) {
  __shared__ unsigned short ldsb[16384];  // 32KB
  const int t = (blockIdx.x >= ga.gbase[1]) + (blockIdx.x >= ga.gbase[2]);
  const int blk = blockIdx.x - ga.gbase[t];
  const int M = ga.M[t];
  const int nslab = ga.nslab[t];
  const int tid = threadIdx.x;
  const int wave = tid >> 6;
  const int lane = tid & 63;
  const int l31 = lane & 31;
  const int lhalf = lane >> 5;

  const int mbase = blk * 128 + wave * 32;
  int r0 = mbase + l31;
  if (r0 > M - 1) r0 = M - 1;

  f32x16 acc[4];
#pragma unroll
  for (int n = 0; n < 4; ++n)
#pragma unroll
    for (int q = 0; q < 16; ++q) acc[n][q] = 0.f;

#pragma unroll
  for (int s = 0; s < 3; ++s) {
    if (s < nslab) {
      const unsigned short* xp = ga.x[t][s] + (size_t)r0 * HD + lhalf * 8;
      // prefetch the wave's full A row for this slab: 8 independent 16B loads
      bf16x8 areg[8];
#pragma unroll
      for (int ks = 0; ks < 8; ++ks) areg[ks] = *(const bf16x8*)(xp + ks * 16);

      __syncthreads();  // protect LDS from previous slab's readers
      {
        const float4* src = (const float4*)ga.wp[t][s];
        float4* dst = (float4*)ldsb;
#pragma unroll
        for (int j = 0; j < 8; ++j) dst[tid + j * 256] = src[tid + j * 256];
      }
      __syncthreads();

#pragma unroll
      for (int ks = 0; ks < 8; ++ks) {
        const int k0 = ks * 16 + lhalf * 8;
#pragma unroll
        for (int nt = 0; nt < 4; ++nt) {
          const int rown = nt * 32 + l31;
          const int kidx = k0 ^ ((rown & 15) << 3);
          const bf16x8 bb = *(const bf16x8*)&ldsb[rown * HD + kidx];
          acc[nt] = __builtin_amdgcn_mfma_f32_32x32x16_bf16(areg[ks], bb, acc[nt], 0, 0, 0);
        }
      }
    }
  }

  const float* b0 = ga.b0[t];
  const float* b1 = ga.b1[t];
  float* outf = ga.outf[t];
  unsigned short* outb = ga.outb[t];
  unsigned char* out8 = ga.out8[t];
#pragma unroll
  for (int nt = 0; nt < 4; ++nt) {
    const int col = nt * 32 + l31;
    float bias = b0[col] + (b1 ? b1[col] : 0.f);
#pragma unroll
    for (int rg = 0; rg < 16; ++rg) {
      int row = mbase + (rg & 3) + 8 * (rg >> 2) + 4 * lhalf;
      float v = acc[nt][rg] + bias;
      if (ga.relu) v = fmaxf(v, 0.f);
      if (row < M) {
        if (outf) {
          outf[(size_t)row * HD + col] = v;
        } else {
          unsigned short h = f2bf(v);
          outb[(size_t)row * HD + col] = h;
          if (out8) {
            float vb = bf2f(h);  // bf16-rounded value (matches table semantics)
            unsigned pk = (unsigned)__builtin_amdgcn_cvt_pk_fp8_f32(vb * 16.f, vb * 16.f, 0, false);
            out8[(size_t)row * HD + col] = (unsigned char)(pk & 0xFF);
          }
        }
      }
    }
  }
}

extern "C" void kernel_launch(void* const* d_in, const int* in_sizes, int n_in,
                              void* d_out, int out_size, void* d_ws, size_t ws_size,
                              hipStream_t stream) {
  const float* emb_g = (const float*)d_in[0];
  const float* emb_d = (const float*)d_in[1];
  const float* emb_c = (const float*)d_in[2];
  const float* Wl = (const float*)d_in[3];   // [2,4,128,128]
  const float* bl = (const float*)d_in[4];   // [2,4,128]
  const float* Wr = (const float*)d_in[5];   // [2,4,128,128]

  const int NG = in_sizes[0] / HD;
  const int ND = in_sizes[1] / HD;
  const int NC = in_sizes[2] / HD;
  const int E0 = in_sizes[6];   // g->g
  const int E1 = in_sizes[8];   // c->d
  const int E2 = in_sizes[10];  // c->g
  const int E3 = in_sizes[12];  // g->c
  const int HH = HD * HD;
  const int Etot = E0 + E1 + E2 + E3;
  const int Ntot = NG + ND + NG + NC;
  const int NB = (Ntot + 1023) >> 10;  // 1024-node buckets

  // ---- workspace carve (all 16B-aligned by construction) ----
  char* w = (char*)d_ws;
  unsigned short* wprep = (unsigned short*)w; w += (size_t)14 * 32768;
  unsigned short* xbf_g0 = (unsigned short*)w; w += (size_t)NG * HD * 2;
  unsigned short* xbf_d0 = (unsigned short*)w; w += (size_t)ND * HD * 2;
  unsigned short* xbf_c0 = (unsigned short*)w; w += (size_t)NC * HD * 2;
  unsigned short* xbf_g1 = (unsigned short*)w; w += (size_t)NG * HD * 2;
  unsigned short* xbf_d1 = (unsigned short*)w; w += (size_t)ND * HD * 2;
  unsigned short* xbf_c1 = (unsigned short*)w; w += (size_t)NC * HD * 2;
  unsigned short* mean_gg = (unsigned short*)w; w += (size_t)NG * HD * 2;
  unsigned short* mean_cd = (unsigned short*)w; w += (size_t)ND * HD * 2;
  unsigned short* mean_cg = (unsigned short*)w; w += (size_t)NG * HD * 2;
  unsigned short* mean_gc = (unsigned short*)w; w += (size_t)NC * HD * 2;
  unsigned char* x8_g0 = (unsigned char*)w; w += (size_t)NG * HD;
  unsigned char* x8_c0 = (unsigned char*)w; w += (size_t)NC * HD;
  unsigned char* x8_g1 = (unsigned char*)w; w += (size_t)NG * HD;
  unsigned char* x8_c1 = (unsigned char*)w; w += (size_t)NC * HD;
  int* ss = (int*)w;        w += (size_t)Etot * 4;
  int* ptr = (int*)w;       w += (size_t)Ntot * 4;
  int* cnt = (int*)w;       w += (size_t)Ntot * 4;
  unsigned* binned = (unsigned*)w; w += (size_t)NB * BSTRIDE * 4;
  int* bucketCur = (int*)w; w += (size_t)NBMAX * 4;  // zeroed

  hipMemsetAsync(bucketCur, 0, (size_t)NBMAX * 4, stream);

  // bf16 (+fp8 for gene/compound) feature tables for layer 0
  {
    long long n0 = (long long)NG * HD, n1 = (long long)ND * HD, n2 = (long long)NC * HD;
    long long tot8 = (n0 + n1 + n2) / 8;
    k_convert<<<(int)((tot8 + 255) / 256), 256, 0, stream>>>(
        emb_g, emb_d, emb_c, xbf_g0, xbf_d0, xbf_c0, x8_g0, x8_c0, n0, n1, n2);
  }

  // CSR build over concatenated spaces (two-pass binned sort)
  GArgs ga;
  ga.esrc[0] = (const int*)d_in[6];  ga.edst[0] = (const int*)d_in[7];
  ga.esrc[1] = (const int*)d_in[8];  ga.edst[1] = (const int*)d_in[9];
  ga.esrc[2] = (const int*)d_in[10]; ga.edst[2] = (const int*)d_in[11];
  ga.esrc[3] = (const int*)d_in[12]; ga.edst[3] = (const int*)d_in[13];
  ga.ebase[0] = 0; ga.ebase[1] = E0; ga.ebase[2] = E0 + E1;
  ga.ebase[3] = E0 + E1 + E2; ga.ebase[4] = Etot;
  ga.nbase[0] = 0; ga.nbase[1] = NG; ga.nbase[2] = NG + ND; ga.nbase[3] = NG + ND + NG;

  k_binA<<<(Etot + 4095) / 4096, 256, 0, stream>>>(ga, Etot, NB, bucketCur, binned);
  k_binB<<<NB, 256, 0, stream>>>(bucketCur, binned, ptr, cnt, ss, Ntot);

  // W preprocessing: 7 slabs/layer: 0:Wl0 1:Wl2 2:Wr0+Wr2 3:Wl1 4:Wr1 5:Wl3 6:Wr3
  PrepArgs pa;
  for (int L = 0; L < 2; ++L) {
    int b = L * 7;
    pa.a[b + 0] = Wl + (size_t)(L * 4 + 0) * HH; pa.b[b + 0] = nullptr;
    pa.a[b + 1] = Wl + (size_t)(L * 4 + 2) * HH; pa.b[b + 1] = nullptr;
    pa.a[b + 2] = Wr + (size_t)(L * 4 + 0) * HH; pa.b[b + 2] = Wr + (size_t)(L * 4 + 2) * HH;
    pa.a[b + 3] = Wl + (size_t)(L * 4 + 1) * HH; pa.b[b + 3] = nullptr;
    pa.a[b + 4] = Wr + (size_t)(L * 4 + 1) * HH; pa.b[b + 4] = nullptr;
    pa.a[b + 5] = Wl + (size_t)(L * 4 + 3) * HH; pa.b[b + 5] = nullptr;
    pa.a[b + 6] = Wr + (size_t)(L * 4 + 3) * HH; pa.b[b + 6] = nullptr;
  }
  k_prepw<<<dim3(14, 16), 256, 0, stream>>>(pa, wprep);

  float* out = (float*)d_out;
  float* xg_out = out;
  float* xd_out = out + (size_t)NG * HD;
  float* xc_out = out + (size_t)(NG + ND) * HD;

  for (int L = 0; L < 2; ++L) {
    const unsigned short* xg = L ? xbf_g1 : xbf_g0;
    const unsigned short* xd = L ? xbf_d1 : xbf_d0;
    const unsigned short* xc = L ? xbf_c1 : xbf_c0;
    const unsigned char* x8g = L ? x8_g1 : x8_g0;
    const unsigned char* x8c = L ? x8_c1 : x8_c0;

    // fused aggregates (reln order: gg(src xg), cd(src xc), cg(src xc), gc(src xg))
    AArgs aa;
    aa.xs[0] = x8g; aa.xs[1] = x8c; aa.xs[2] = x8c; aa.xs[3] = x8g;
    aa.mean[0] = mean_gg; aa.mean[1] = mean_cd; aa.mean[2] = mean_cg; aa.mean[3] = mean_gc;
    aa.nbase[0] = 0; aa.nbase[1] = NG; aa.nbase[2] = NG + ND; aa.nbase[3] = NG + ND + NG;
    aa.n[0] = NG; aa.n[1] = ND; aa.n[2] = NG; aa.n[3] = NC;
    int bb = 0;
    for (int r = 0; r < 4; ++r) { aa.bbase[r] = bb; bb += (aa.n[r] + 31) / 32; }
    aa.bbase[4] = bb;
    k_aggregate_all<<<bb, 256, 0, stream>>>(aa, ptr, cnt, ss);

    const float* bl_L = bl + (size_t)L * 4 * HD;
    const unsigned short* wp = wprep + (size_t)L * 7 * 16384;

    GemmArgs gm;
    // genes: mean_gg@Wl0 + mean_cg@Wl2 + xg@(Wr0+Wr2) + bl0 + bl2
    gm.x[0][0] = mean_gg; gm.x[0][1] = mean_cg; gm.x[0][2] = xg;
    gm.wp[0][0] = wp + 0 * 16384; gm.wp[0][1] = wp + 1 * 16384; gm.wp[0][2] = wp + 2 * 16384;
    gm.b0[0] = bl_L + 0 * HD; gm.b1[0] = bl_L + 2 * HD;
    gm.M[0] = NG; gm.nslab[0] = 3;
    // disease: mean_cd@Wl1 + xd@Wr1 + bl1
    gm.x[1][0] = mean_cd; gm.x[1][1] = xd; gm.x[1][2] = nullptr;
    gm.wp[1][0] = wp + 3 * 16384; gm.wp[1][1] = wp + 4 * 16384; gm.wp[1][2] = nullptr;
    gm.b0[1] = bl_L + 1 * HD; gm.b1[1] = nullptr;
    gm.M[1] = ND; gm.nslab[1] = 2;
    // compound: mean_gc@Wl3 + xc@Wr3 + bl3
    gm.x[2][0] = mean_gc; gm.x[2][1] = xc; gm.x[2][2] = nullptr;
    gm.wp[2][0] = wp + 5 * 16384; gm.wp[2][1] = wp + 6 * 16384; gm.wp[2][2] = nullptr;
    gm.b0[2] = bl_L + 3 * HD; gm.b1[2] = nullptr;
    gm.M[2] = NC; gm.nslab[2] = 2;
    if (L) {
      gm.outf[0] = xg_out; gm.outf[1] = xd_out; gm.outf[2] = xc_out;
      gm.outb[0] = gm.outb[1] = gm.outb[2] = nullptr;
      gm.out8[0] = gm.out8[1] = gm.out8[2] = nullptr;
    } else {
      gm.outf[0] = gm.outf[1] = gm.outf[2] = nullptr;
      gm.outb[0] = xbf_g1; gm.outb[1] = xbf_d1; gm.outb[2] = xbf_c1;
      gm.out8[0] = x8_g1; gm.out8[1] = nullptr; gm.out8[2] = x8_c1;  // disease never gathered
    }
    gm.relu = (L == 0) ? 1 : 0;
    int gb = 0;
    for (int t = 0; t < 3; ++t) { gm.gbase[t] = gb; gb += (gm.M[t] + 127) / 128; }
    gm.gbase[3] = gb;
    k_gemm_all<<<gb, 256, 0, stream>>>(gm);
  }
}

// Round 12
// 331.808 us; speedup vs baseline: 4.1894x; 1.0068x over previous
//
#include <hip/hip_runtime.h>

// HeteroGNN: 2-layer hetero SAGE (gene/disease/compound), H=128.
// R11b (bit-identical math vs R10; fixes nontemporal-store type):
//  - k_aggregate_all: nontemporal mean stores (stop evicting fp8 tables from
//    L3 -> FETCH was 104MB vs 19MB unique table); 8-aligned CSR segments ->
//    edge indices loaded as 2 broadcast uint4 (no ds_bpermute chain).
//  - k_binB: pads each node segment to a multiple of 8 (bucket base reserve
//    PADRES, 8-aligned); edge order per node unchanged.
//  - k_front: convert + binA + prepw fused into one dispatch (independent).
// Pipeline: memset, front, binB, L0{agg,gemm}, L1{agg,gemm} = 7 launches.

constexpr int HD = 128;
constexpr int NBMAX = 512;     // max buckets (Ntot/1024 = 293 here)
constexpr int BSTRIDE = 32768; // per-bucket record capacity (expected max ~13K)
constexpr int PADRES = 7176;   // per-bucket pad reserve (1024*7 rounded up +8)

typedef __attribute__((ext_vector_type(8))) short bf16x8;
typedef __attribute__((ext_vector_type(16))) float f32x16;
typedef __attribute__((ext_vector_type(2))) float f32x2;
typedef __attribute__((ext_vector_type(4))) unsigned int u32x4;  // nontemporal-compatible

__device__ __forceinline__ unsigned short f2bf(float x) {
  unsigned u = __builtin_bit_cast(unsigned, x);
  u += 0x7FFF + ((u >> 16) & 1);  // RNE
  return (unsigned short)(u >> 16);
}
__device__ __forceinline__ float bf2f(unsigned short h) {
  return __builtin_bit_cast(float, (unsigned)h << 16);
}

// pack 8 f32 (x16 scale) -> 8 fp8 bytes (uint2)
__device__ __forceinline__ uint2 pack_fp8x8(const float* v) {
  uint2 o;
  unsigned t;
  t = (unsigned)__builtin_amdgcn_cvt_pk_fp8_f32(v[0] * 16.f, v[1] * 16.f, 0, false);
  t = (unsigned)__builtin_amdgcn_cvt_pk_fp8_f32(v[2] * 16.f, v[3] * 16.f, (int)t, true);
  o.x = t;
  t = (unsigned)__builtin_amdgcn_cvt_pk_fp8_f32(v[4] * 16.f, v[5] * 16.f, 0, false);
  t = (unsigned)__builtin_amdgcn_cvt_pk_fp8_f32(v[6] * 16.f, v[7] * 16.f, (int)t, true);
  o.y = t;
  return o;
}

struct GArgs {
  const int* esrc[4];
  const int* edst[4];
  int ebase[5];  // edge prefix over concatenated edge space
  int nbase[4];  // dst-node prefix per relation (concat node space)
};

struct PrepArgs {
  const float* a[14];
  const float* b[14];
};

// ---------------- fused front kernel: convert | binA | prepw ----------------
struct FrontArgs {
  // convert (f32 -> bf16 + fp8[gene/compound])
  const float *cs0, *cs1, *cs2;
  unsigned short *cd0, *cd1, *cd2;
  unsigned char *ce0, *ce2;
  long long n0, n1, n2;
  // binA
  GArgs ga;
  int Etot, NB;
  int* bucketCur;
  unsigned* binned;
  // prepw
  PrepArgs pa;
  unsigned short* wprep;
  int cb, ab;  // block counts of convert / binA parts
};

__global__ __launch_bounds__(256) void k_front(FrontArgs f) {
  __shared__ int hist[NBMAX];
  __shared__ int base[NBMAX];
  const int tid = threadIdx.x;
  int b = blockIdx.x;

  if (b < f.cb) {
    // ---- convert ----
    long long i = ((long long)b * 256 + tid) * 8;
    const float* s;
    unsigned short* d;
    unsigned char* e;
    if (i < f.n0) { s = f.cs0 + i; d = f.cd0 + i; e = f.ce0 + i; }
    else if (i < f.n0 + f.n1) { s = f.cs1 + (i - f.n0); d = f.cd1 + (i - f.n0); e = nullptr; }
    else if (i < f.n0 + f.n1 + f.n2) {
      long long o2 = i - f.n0 - f.n1;
      s = f.cs2 + o2; d = f.cd2 + o2; e = f.ce2 + o2;
    } else return;
    float4 a = *(const float4*)s;
    float4 bb = *(const float4*)(s + 4);
    float v[8] = {a.x, a.y, a.z, a.w, bb.x, bb.y, bb.z, bb.w};
    uint4 o;
    o.x = (unsigned)f2bf(v[0]) | ((unsigned)f2bf(v[1]) << 16);
    o.y = (unsigned)f2bf(v[2]) | ((unsigned)f2bf(v[3]) << 16);
    o.z = (unsigned)f2bf(v[4]) | ((unsigned)f2bf(v[5]) << 16);
    o.w = (unsigned)f2bf(v[6]) | ((unsigned)f2bf(v[7]) << 16);
    *(uint4*)d = o;
    if (e) *(uint2*)e = pack_fp8x8(v);
    return;
  }
  b -= f.cb;

  if (b < f.ab) {
    // ---- binA: bin edges into 1024-node buckets; rec = (g&1023)<<20 | src ----
    for (int j = tid; j < f.NB; j += 256) hist[j] = 0;
    __syncthreads();
    const int e0 = b * 4096;
    for (int i = tid; i < 4096; i += 256) {
      int e = e0 + i;
      if (e < f.Etot) {
        int r = (e >= f.ga.ebase[1]) + (e >= f.ga.ebase[2]) + (e >= f.ga.ebase[3]);
        int g = f.ga.nbase[r] + f.ga.edst[r][e - f.ga.ebase[r]];
        atomicAdd(&hist[g >> 10], 1);
      }
    }
    __syncthreads();
    for (int j = tid; j < f.NB; j += 256) {
      int h = hist[j];
      base[j] = h ? atomicAdd(&f.bucketCur[j], h) : 0;
      hist[j] = 0;  // same thread owns j in both statements -> ordered
    }
    __syncthreads();
    for (int i = tid; i < 4096; i += 256) {
      int e = e0 + i;
      if (e < f.Etot) {
        int r = (e >= f.ga.ebase[1]) + (e >= f.ga.ebase[2]) + (e >= f.ga.ebase[3]);
        int el = e - f.ga.ebase[r];
        int g = f.ga.nbase[r] + f.ga.edst[r][el];
        int bk = g >> 10;
        int pos = base[bk] + atomicAdd(&hist[bk], 1);
        f.binned[(size_t)bk * BSTRIDE + pos] =
            ((unsigned)(g & 1023) << 20) | (unsigned)f.ga.esrc[r][el];
      }
    }
    return;
  }
  b -= f.ab;

  // ---- prepw: W (or Wa+Wb) [k][n] f32 -> [n][k] bf16, k XOR-swizzled ----
  int s = b >> 4, y = b & 15;
  const float* A = f.pa.a[s];
  const float* B = f.pa.b[s];
  unsigned short* oh = f.wprep + (size_t)s * 16384;
  int e0 = y * 1024 + tid * 4;
#pragma unroll
  for (int j = 0; j < 4; ++j) {
    int e = e0 + j;
    int k = e >> 7, n = e & 127;
    float v = A[e] + (B ? B[e] : 0.f);
    oh[n * 128 + (k ^ ((n & 15) << 3))] = f2bf(v);
  }
}

// ---------------- binB: per-bucket CSR finalize, 8-aligned segments ----------
__global__ __launch_bounds__(256) void k_binB(const int* __restrict__ bucketCur,
                                              const unsigned* __restrict__ binned,
                                              int* __restrict__ ptr, int* __restrict__ cnt,
                                              int* __restrict__ ss, int Ntot) {
  const int b = blockIdx.x;
  const int tid = threadIdx.x;
  __shared__ int ncnt[1024];
  __shared__ int noff[1024];
  __shared__ int red[256];
  __shared__ int sbase_s;
  __shared__ int wsum[4], wbase[4];

  int part = 0;
  for (int i = tid; i < b; i += 256) part += bucketCur[i];
  red[tid] = part;
  __syncthreads();
  for (int s = 128; s > 0; s >>= 1) {
    if (tid < s) red[tid] += red[tid + s];
    __syncthreads();
  }
  if (tid == 0) sbase_s = ((red[0] + 7) & ~7) + b * PADRES;  // 8-aligned base

  for (int j = tid; j < 1024; j += 256) ncnt[j] = 0;
  __syncthreads();

  const int ecount = bucketCur[b];
  const unsigned* bp = binned + (size_t)b * BSTRIDE;
  for (int i = tid; i < ecount; i += 256) atomicAdd(&ncnt[bp[i] >> 20], 1);
  __syncthreads();

  // exclusive scan over PADDED counts (each node's slot rounded up to 8)
  const int j0 = tid * 4;
  int c0 = ncnt[j0], c1 = ncnt[j0 + 1], c2 = ncnt[j0 + 2], c3 = ncnt[j0 + 3];
  int p0 = (c0 + 7) & ~7, p1 = (c1 + 7) & ~7, p2 = (c2 + 7) & ~7, p3 = (c3 + 7) & ~7;
  int s4 = p0 + p1 + p2 + p3;
  int lane = tid & 63, wid = tid >> 6;
  int incl = s4;
#pragma unroll
  for (int off = 1; off < 64; off <<= 1) {
    int t = __shfl_up(incl, off);
    if (lane >= off) incl += t;
  }
  if (lane == 63) wsum[wid] = incl;
  __syncthreads();
  if (tid == 0) {
    int acc = 0;
#pragma unroll
    for (int w2 = 0; w2 < 4; ++w2) { wbase[w2] = acc; acc += wsum[w2]; }
  }
  __syncthreads();
  int excl = wbase[wid] + incl - s4;
  const int sbase = sbase_s;
  int o0 = excl, o1 = o0 + p0, o2 = o1 + p1, o3 = o2 + p2;
  noff[j0] = o0; noff[j0 + 1] = o1; noff[j0 + 2] = o2; noff[j0 + 3] = o3;
  int g0 = b * 1024 + j0;
  if (g0 + 0 < Ntot) { ptr[g0 + 0] = sbase + o0; cnt[g0 + 0] = c0; }
  if (g0 + 1 < Ntot) { ptr[g0 + 1] = sbase + o1; cnt[g0 + 1] = c1; }
  if (g0 + 2 < Ntot) { ptr[g0 + 2] = sbase + o2; cnt[g0 + 2] = c2; }
  if (g0 + 3 < Ntot) { ptr[g0 + 3] = sbase + o3; cnt[g0 + 3] = c3; }
  __syncthreads();

  for (int i = tid; i < ecount; i += 256) {
    unsigned rec = bp[i];
    int j = rec >> 20;
    int p = sbase + atomicAdd(&noff[j], 1);
    ss[p] = (int)(rec & 0xFFFFF);
  }
}

// ---------------- fused neighbor mean (4 relations, fp8 gather) ----------------
// 8-lane groups, uint4/lane. Segments 8-aligned -> indices via 2 broadcast
// uint4 loads (no shfl). Nontemporal mean stores (keep fp8 tables cached).
struct AArgs {
  const unsigned char* xs[4];   // fp8 tables (x16 scale)
  unsigned short* mean[4];      // bf16 out
  int nbase[4];
  int bbase[5];  // block prefix
  int n[4];
};

__global__ __launch_bounds__(256) void k_aggregate_all(AArgs A, const int* __restrict__ ptr,
                                                       const int* __restrict__ cnt,
                                                       const int* __restrict__ ss) {
  int b = blockIdx.x;
  int r = (b >= A.bbase[1]) + (b >= A.bbase[2]) + (b >= A.bbase[3]);
  int d = (b - A.bbase[r]) * 32 + (threadIdx.x >> 3);
  if (d >= A.n[r]) return;
  const unsigned char* xs = A.xs[r];
  int l = threadIdx.x & 7;
  int g = A.nbase[r] + d;
  int p = ptr[g];   // multiple of 8 -> 16B-aligned index loads
  int deg = cnt[g];
  f32x2 b0 = {0.f, 0.f}, b1 = {0.f, 0.f}, b2 = {0.f, 0.f}, b3 = {0.f, 0.f};
  f32x2 b4 = {0.f, 0.f}, b5 = {0.f, 0.f}, b6 = {0.f, 0.f}, b7 = {0.f, 0.f};
  for (int j0 = 0; j0 < deg; j0 += 8) {
    int m = deg - j0;
    if (m > 8) m = 8;
    const uint4* ip = (const uint4*)(ss + p + j0);
    uint4 ia = ip[0];          // same addr across lanes -> broadcast
    uint4 ib = ip[1];          // pad slots may hold garbage; guarded below
    uint4 uu[8];
    if (m > 0) uu[0] = *(const uint4*)(xs + (size_t)ia.x * HD + l * 16);
    if (m > 1) uu[1] = *(const uint4*)(xs + (size_t)ia.y * HD + l * 16);
    if (m > 2) uu[2] = *(const uint4*)(xs + (size_t)ia.z * HD + l * 16);
    if (m > 3) uu[3] = *(const uint4*)(xs + (size_t)ia.w * HD + l * 16);
    if (m > 4) uu[4] = *(const uint4*)(xs + (size_t)ib.x * HD + l * 16);
    if (m > 5) uu[5] = *(const uint4*)(xs + (size_t)ib.y * HD + l * 16);
    if (m > 6) uu[6] = *(const uint4*)(xs + (size_t)ib.z * HD + l * 16);
    if (m > 7) uu[7] = *(const uint4*)(xs + (size_t)ib.w * HD + l * 16);
#pragma unroll
    for (int k = 0; k < 8; ++k) {
      if (k < m) {
        b0 += __builtin_amdgcn_cvt_pk_f32_fp8(uu[k].x, false);
        b1 += __builtin_amdgcn_cvt_pk_f32_fp8(uu[k].x, true);
        b2 += __builtin_amdgcn_cvt_pk_f32_fp8(uu[k].y, false);
        b3 += __builtin_amdgcn_cvt_pk_f32_fp8(uu[k].y, true);
        b4 += __builtin_amdgcn_cvt_pk_f32_fp8(uu[k].z, false);
        b5 += __builtin_amdgcn_cvt_pk_f32_fp8(uu[k].z, true);
        b6 += __builtin_amdgcn_cvt_pk_f32_fp8(uu[k].w, false);
        b7 += __builtin_amdgcn_cvt_pk_f32_fp8(uu[k].w, true);
      }
    }
  }
  float inv = 1.0f / (16.0f * (float)(deg > 0 ? deg : 1));  // fold out x16 scale
  u32x4 o;
  unsigned short* mp = A.mean[r] + (size_t)d * HD + l * 16;
  o.x = (unsigned)f2bf(b0.x * inv) | ((unsigned)f2bf(b0.y * inv) << 16);
  o.y = (unsigned)f2bf(b1.x * inv) | ((unsigned)f2bf(b1.y * inv) << 16);
  o.z = (unsigned)f2bf(b2.x * inv) | ((unsigned)f2bf(b2.y * inv) << 16);
  o.w = (unsigned)f2bf(b3.x * inv) | ((unsigned)f2bf(b3.y * inv) << 16);
  __builtin_nontemporal_store(o, (u32x4*)mp);
  o.x = (unsigned)f2bf(b4.x * inv) | ((unsigned)f2bf(b4.y * inv) << 16);
  o.y = (unsigned)f2bf(b5.x * inv) | ((unsigned)f2bf(b5.y * inv) << 16);
  o.z = (unsigned)f2bf(b6.x * inv) | ((unsigned)f2bf(b6.y * inv) << 16);
  o.w = (unsigned)f2bf(b7.x * inv) | ((unsigned)f2bf(b7.y * inv) << 16);
  __builtin_nontemporal_store(o, (u32x4*)(mp + 8));
}

// ---------------- merged MFMA GEMM (3 node types, one dispatch) ----------------
struct GemmArgs {
  const unsigned short* x[3][3];   // [type][slab]
  const unsigned short* wp[3][3];
  const float* b0[3];
  const float* b1[3];
  float* outf[3];                  // layer-1: d_out segment; layer-0: null
  unsigned short* outb[3];         // layer-0: bf16 hidden table
  unsigned char* out8[3];          // layer-0: fp8 hidden table (null = skip)
  int M[3];
  int nslab[3];
  int gbase[4];                    // block prefix per type
  int relu;
};

__global__ __launch_bounds__(256, 4) void k_gemm_all(GemmArgs ga) {
  __shared__ unsigned short ldsb[16384];  // 32KB
  const int t = (blockIdx.x >= ga.gbase[1]) + (blockIdx.x >= ga.gbase[2]);
  const int blk = blockIdx.x - ga.gbase[t];
  const int M = ga.M[t];
  const int nslab = ga.nslab[t];
  const int tid = threadIdx.x;
  const int wave = tid >> 6;
  const int lane = tid & 63;
  const int l31 = lane & 31;
  const int lhalf = lane >> 5;

  const int mbase = blk * 128 + wave * 32;
  int r0 = mbase + l31;
  if (r0 > M - 1) r0 = M - 1;

  f32x16 acc[4];
#pragma unroll
  for (int n = 0; n < 4; ++n)
#pragma unroll
    for (int q = 0; q < 16; ++q) acc[n][q] = 0.f;

#pragma unroll
  for (int s = 0; s < 3; ++s) {
    if (s < nslab) {
      const unsigned short* xp = ga.x[t][s] + (size_t)r0 * HD + lhalf * 8;
      // prefetch the wave's full A row for this slab: 8 independent 16B loads
      bf16x8 areg[8];
#pragma unroll
      for (int ks = 0; ks < 8; ++ks) areg[ks] = *(const bf16x8*)(xp + ks * 16);

      __syncthreads();  // protect LDS from previous slab's readers
      {
        const float4* src = (const float4*)ga.wp[t][s];
        float4* dst = (float4*)ldsb;
#pragma unroll
        for (int j = 0; j < 8; ++j) dst[tid + j * 256] = src[tid + j * 256];
      }
      __syncthreads();

#pragma unroll
      for (int ks = 0; ks < 8; ++ks) {
        const int k0 = ks * 16 + lhalf * 8;
#pragma unroll
        for (int nt = 0; nt < 4; ++nt) {
          const int rown = nt * 32 + l31;
          const int kidx = k0 ^ ((rown & 15) << 3);
          const bf16x8 bb = *(const bf16x8*)&ldsb[rown * HD + kidx];
          acc[nt] = __builtin_amdgcn_mfma_f32_32x32x16_bf16(areg[ks], bb, acc[nt], 0, 0, 0);
        }
      }
    }
  }

  const float* b0 = ga.b0[t];
  const float* b1 = ga.b1[t];
  float* outf = ga.outf[t];
  unsigned short* outb = ga.outb[t];
  unsigned char* out8 = ga.out8[t];
#pragma unroll
  for (int nt = 0; nt < 4; ++nt) {
    const int col = nt * 32 + l31;
    float bias = b0[col] + (b1 ? b1[col] : 0.f);
#pragma unroll
    for (int rg = 0; rg < 16; ++rg) {
      int row = mbase + (rg & 3) + 8 * (rg >> 2) + 4 * lhalf;
      float v = acc[nt][rg] + bias;
      if (ga.relu) v = fmaxf(v, 0.f);
      if (row < M) {
        if (outf) {
          outf[(size_t)row * HD + col] = v;
        } else {
          unsigned short h = f2bf(v);
          outb[(size_t)row * HD + col] = h;
          if (out8) {
            float vb = bf2f(h);  // bf16-rounded value (matches table semantics)
            unsigned pk = (unsigned)__builtin_amdgcn_cvt_pk_fp8_f32(vb * 16.f, vb * 16.f, 0, false);
            out8[(size_t)row * HD + col] = (unsigned char)(pk & 0xFF);
          }
        }
      }
    }
  }
}

extern "C" void kernel_launch(void* const* d_in, const int* in_sizes, int n_in,
                              void* d_out, int out_size, void* d_ws, size_t ws_size,
                              hipStream_t stream) {
  const float* emb_g = (const float*)d_in[0];
  const float* emb_d = (const float*)d_in[1];
  const float* emb_c = (const float*)d_in[2];
  const float* Wl = (const float*)d_in[3];   // [2,4,128,128]
  const float* bl = (const float*)d_in[4];   // [2,4,128]
  const float* Wr = (const float*)d_in[5];   // [2,4,128,128]

  const int NG = in_sizes[0] / HD;
  const int ND = in_sizes[1] / HD;
  const int NC = in_sizes[2] / HD;
  const int E0 = in_sizes[6];   // g->g
  const int E1 = in_sizes[8];   // c->d
  const int E2 = in_sizes[10];  // c->g
  const int E3 = in_sizes[12];  // g->c
  const int HH = HD * HD;
  const int Etot = E0 + E1 + E2 + E3;
  const int Ntot = NG + ND + NG + NC;
  const int NB = (Ntot + 1023) >> 10;  // 1024-node buckets

  // ---- workspace carve (all 16B-aligned by construction) ----
  char* w = (char*)d_ws;
  unsigned short* wprep = (unsigned short*)w; w += (size_t)14 * 32768;
  unsigned short* xbf_g0 = (unsigned short*)w; w += (size_t)NG * HD * 2;
  unsigned short* xbf_d0 = (unsigned short*)w; w += (size_t)ND * HD * 2;
  unsigned short* xbf_c0 = (unsigned short*)w; w += (size_t)NC * HD * 2;
  unsigned short* xbf_g1 = (unsigned short*)w; w += (size_t)NG * HD * 2;
  unsigned short* xbf_d1 = (unsigned short*)w; w += (size_t)ND * HD * 2;
  unsigned short* xbf_c1 = (unsigned short*)w; w += (size_t)NC * HD * 2;
  unsigned short* mean_gg = (unsigned short*)w; w += (size_t)NG * HD * 2;
  unsigned short* mean_cd = (unsigned short*)w; w += (size_t)ND * HD * 2;
  unsigned short* mean_cg = (unsigned short*)w; w += (size_t)NG * HD * 2;
  unsigned short* mean_gc = (unsigned short*)w; w += (size_t)NC * HD * 2;
  unsigned char* x8_g0 = (unsigned char*)w; w += (size_t)NG * HD;
  unsigned char* x8_c0 = (unsigned char*)w; w += (size_t)NC * HD;
  unsigned char* x8_g1 = (unsigned char*)w; w += (size_t)NG * HD;
  unsigned char* x8_c1 = (unsigned char*)w; w += (size_t)NC * HD;
  int* ss = (int*)w;        w += ((size_t)Etot + (size_t)NB * PADRES + 64) * 4;
  int* ptr = (int*)w;       w += (size_t)Ntot * 4;
  int* cnt = (int*)w;       w += (size_t)Ntot * 4;
  unsigned* binned = (unsigned*)w; w += (size_t)NB * BSTRIDE * 4;
  int* bucketCur = (int*)w; w += (size_t)NBMAX * 4;  // zeroed

  hipMemsetAsync(bucketCur, 0, (size_t)NBMAX * 4, stream);

  // ---- fused front: convert | binA | prepw ----
  FrontArgs fa;
  fa.cs0 = emb_g; fa.cs1 = emb_d; fa.cs2 = emb_c;
  fa.cd0 = xbf_g0; fa.cd1 = xbf_d0; fa.cd2 = xbf_c0;
  fa.ce0 = x8_g0; fa.ce2 = x8_c0;
  fa.n0 = (long long)NG * HD; fa.n1 = (long long)ND * HD; fa.n2 = (long long)NC * HD;
  fa.ga.esrc[0] = (const int*)d_in[6];  fa.ga.edst[0] = (const int*)d_in[7];
  fa.ga.esrc[1] = (const int*)d_in[8];  fa.ga.edst[1] = (const int*)d_in[9];
  fa.ga.esrc[2] = (const int*)d_in[10]; fa.ga.edst[2] = (const int*)d_in[11];
  fa.ga.esrc[3] = (const int*)d_in[12]; fa.ga.edst[3] = (const int*)d_in[13];
  fa.ga.ebase[0] = 0; fa.ga.ebase[1] = E0; fa.ga.ebase[2] = E0 + E1;
  fa.ga.ebase[3] = E0 + E1 + E2; fa.ga.ebase[4] = Etot;
  fa.ga.nbase[0] = 0; fa.ga.nbase[1] = NG; fa.ga.nbase[2] = NG + ND; fa.ga.nbase[3] = NG + ND + NG;
  fa.Etot = Etot; fa.NB = NB;
  fa.bucketCur = bucketCur; fa.binned = binned;
  for (int L = 0; L < 2; ++L) {
    int b = L * 7;
    fa.pa.a[b + 0] = Wl + (size_t)(L * 4 + 0) * HH; fa.pa.b[b + 0] = nullptr;
    fa.pa.a[b + 1] = Wl + (size_t)(L * 4 + 2) * HH; fa.pa.b[b + 1] = nullptr;
    fa.pa.a[b + 2] = Wr + (size_t)(L * 4 + 0) * HH; fa.pa.b[b + 2] = Wr + (size_t)(L * 4 + 2) * HH;
    fa.pa.a[b + 3] = Wl + (size_t)(L * 4 + 1) * HH; fa.pa.b[b + 3] = nullptr;
    fa.pa.a[b + 4] = Wr + (size_t)(L * 4 + 1) * HH; fa.pa.b[b + 4] = nullptr;
    fa.pa.a[b + 5] = Wl + (size_t)(L * 4 + 3) * HH; fa.pa.b[b + 5] = nullptr;
    fa.pa.a[b + 6] = Wr + (size_t)(L * 4 + 3) * HH; fa.pa.b[b + 6] = nullptr;
  }
  fa.wprep = wprep;
  long long tot8 = (fa.n0 + fa.n1 + fa.n2) / 8;
  fa.cb = (int)((tot8 + 255) / 256);
  fa.ab = (Etot + 4095) / 4096;
  k_front<<<fa.cb + fa.ab + 14 * 16, 256, 0, stream>>>(fa);

  k_binB<<<NB, 256, 0, stream>>>(bucketCur, binned, ptr, cnt, ss, Ntot);

  float* out = (float*)d_out;
  float* xg_out = out;
  float* xd_out = out + (size_t)NG * HD;
  float* xc_out = out + (size_t)(NG + ND) * HD;

  for (int L = 0; L < 2; ++L) {
    const unsigned short* xg = L ? xbf_g1 : xbf_g0;
    const unsigned short* xd = L ? xbf_d1 : xbf_d0;
    const unsigned short* xc = L ? xbf_c1 : xbf_c0;
    const unsigned char* x8g = L ? x8_g1 : x8_g0;
    const unsigned char* x8c = L ? x8_c1 : x8_c0;

    // fused aggregates (reln order: gg(src xg), cd(src xc), cg(src xc), gc(src xg))
    AArgs aa;
    aa.xs[0] = x8g; aa.xs[1] = x8c; aa.xs[2] = x8c; aa.xs[3] = x8g;
    aa.mean[0] = mean_gg; aa.mean[1] = mean_cd; aa.mean[2] = mean_cg; aa.mean[3] = mean_gc;
    aa.nbase[0] = 0; aa.nbase[1] = NG; aa.nbase[2] = NG + ND; aa.nbase[3] = NG + ND + NG;
    aa.n[0] = NG; aa.n[1] = ND; aa.n[2] = NG; aa.n[3] = NC;
    int bb = 0;
    for (int r = 0; r < 4; ++r) { aa.bbase[r] = bb; bb += (aa.n[r] + 31) / 32; }
    aa.bbase[4] = bb;
    k_aggregate_all<<<bb, 256, 0, stream>>>(aa, ptr, cnt, ss);

    const float* bl_L = bl + (size_t)L * 4 * HD;
    const unsigned short* wp = wprep + (size_t)L * 7 * 16384;

    GemmArgs gm;
    // genes: mean_gg@Wl0 + mean_cg@Wl2 + xg@(Wr0+Wr2) + bl0 + bl2
    gm.x[0][0] = mean_gg; gm.x[0][1] = mean_cg; gm.x[0][2] = xg;
    gm.wp[0][0] = wp + 0 * 16384; gm.wp[0][1] = wp + 1 * 16384; gm.wp[0][2] = wp + 2 * 16384;
    gm.b0[0] = bl_L + 0 * HD; gm.b1[0] = bl_L + 2 * HD;
    gm.M[0] = NG; gm.nslab[0] = 3;
    // disease: mean_cd@Wl1 + xd@Wr1 + bl1
    gm.x[1][0] = mean_cd; gm.x[1][1] = xd; gm.x[1][2] = nullptr;
    gm.wp[1][0] = wp + 3 * 16384; gm.wp[1][1] = wp + 4 * 16384; gm.wp[1][2] = nullptr;
    gm.b0[1] = bl_L + 1 * HD; gm.b1[1] = nullptr;
    gm.M[1] = ND; gm.nslab[1] = 2;
    // compound: mean_gc@Wl3 + xc@Wr3 + bl3
    gm.x[2][0] = mean_gc; gm.x[2][1] = xc; gm.x[2][2] = nullptr;
    gm.wp[2][0] = wp + 5 * 16384; gm.wp[2][1] = wp + 6 * 16384; gm.wp[2][2] = nullptr;
    gm.b0[2] = bl_L + 3 * HD; gm.b1[2] = nullptr;
    gm.M[2] = NC; gm.nslab[2] = 2;
    if (L) {
      gm.outf[0] = xg_out; gm.outf[1] = xd_out; gm.outf[2] = xc_out;
      gm.outb[0] = gm.outb[1] = gm.outb[2] = nullptr;
      gm.out8[0] = gm.out8[1] = gm.out8[2] = nullptr;
    } else {
      gm.outf[0] = gm.outf[1] = gm.outf[2] = nullptr;
      gm.outb[0] = xbf_g1; gm.outb[1] = xbf_d1; gm.outb[2] = xbf_c1;
      gm.out8[0] = x8_g1; gm.out8[1] = nullptr; gm.out8[2] = x8_c1;  // disease never gathered
    }
    gm.relu = (L == 0) ? 1 : 0;
    int gb = 0;
    for (int t = 0; t < 3; ++t) { gm.gbase[t] = gb; gb += (gm.M[t] + 127) / 128; }
    gm.gbase[3] = gb;
    k_gemm_all<<<gb, 256, 0, stream>>>(gm);
  }
}